// Round 7
// baseline (592.530 us; speedup 1.0000x reference)
//
#include <hip/hip_runtime.h>
#include <hip/hip_bf16.h>
#include <stdint.h>

#define NTOK 3136
#define MTOT 100352
#define RPW  14          // rows per LN wave
#define WPB  224         // LN waves per batch (NTOK/RPW)

typedef __attribute__((ext_vector_type(8))) short bf16x8;
typedef __attribute__((ext_vector_type(4))) float f32x4;
typedef __attribute__((ext_vector_type(2))) float f32x2;

static __device__ __forceinline__ ushort f2bf(float x) {
  union { float f; uint32_t u; } c; c.f = x;
  uint32_t r = (c.u + 0x7FFFu + ((c.u >> 16) & 1u)) >> 16;   // RNE
  return (ushort)r;
}
static __device__ __forceinline__ float bf2f(ushort h) {
  union { uint32_t u; float f; } c; c.u = ((uint32_t)h) << 16;
  return c.f;
}

// ---------------------------------------------------------------------------
// LayerNorm + fp32 column partial sums. Lanes own channel PAIRS (float2 in,
// packed-uint bf16-pair out). One wave per RPW=14 rows -> 7168 waves (28/CU).
// part layout: [b][c][WPB] so the reducer reads contiguous float4s.
// ---------------------------------------------------------------------------
template<int DIN, bool WLO>
__global__ __launch_bounds__(256)
void ln_colsum_k(const float* __restrict__ in, const float* __restrict__ gma,
                 const float* __restrict__ bta, ushort* __restrict__ oh,
                 ushort* __restrict__ ol, float* __restrict__ part)
{
  constexpr int P2 = DIN / 2;
  constexpr int T2 = (P2 + 63) / 64;
  const int wid  = (blockIdx.x * 256 + threadIdx.x) >> 6;
  const int lane = threadIdx.x & 63;
  const int b = wid / WPB;
  const int w = wid - b * WPB;

  f32x2 gv[T2], bv[T2], acc[T2];
#pragma unroll
  for (int t = 0; t < T2; ++t) {
    int c2 = lane + 64 * t;
    if (c2 < P2) {
      gv[t] = *(const f32x2*)(gma + 2 * c2);
      bv[t] = *(const f32x2*)(bta + 2 * c2);
    } else { gv[t] = {0.f, 0.f}; bv[t] = {0.f, 0.f}; }
    acc[t] = {0.f, 0.f};
  }

  const size_t rbase = ((size_t)b * NTOK + (size_t)w * RPW) * DIN;
  const float* ip = in + rbase;
  ushort* oph = oh + rbase;
  ushort* opl = ol + rbase;

  for (int j = 0; j < RPW; ++j) {
    f32x2 v[T2];
    float s = 0.f, sq = 0.f;
#pragma unroll
    for (int t = 0; t < T2; ++t) {
      int c2 = lane + 64 * t;
      f32x2 xv = {0.f, 0.f};
      if (c2 < P2) xv = *(const f32x2*)(ip + (size_t)j * DIN + 2 * c2);
      v[t] = xv;
      s  += xv[0] + xv[1];
      sq += xv[0] * xv[0] + xv[1] * xv[1];
    }
#pragma unroll
    for (int off = 1; off < 64; off <<= 1) {
      s  += __shfl_xor(s, off);
      sq += __shfl_xor(sq, off);
    }
    float m   = s / (float)DIN;
    float var = sq / (float)DIN - m * m;
    float r   = 1.f / sqrtf(var + 1e-5f);
#pragma unroll
    for (int t = 0; t < T2; ++t) {
      int c2 = lane + 64 * t;
      if (c2 < P2) {
        float xn0 = (v[t][0] - m) * r * gv[t][0] + bv[t][0];
        float xn1 = (v[t][1] - m) * r * gv[t][1] + bv[t][1];
        ushort h0 = f2bf(xn0), h1 = f2bf(xn1);
        ((uint32_t*)(oph + (size_t)j * DIN))[c2] =
            (uint32_t)h0 | ((uint32_t)h1 << 16);
        if (WLO) {
          ushort l0 = f2bf(xn0 - bf2f(h0)), l1 = f2bf(xn1 - bf2f(h1));
          ((uint32_t*)(opl + (size_t)j * DIN))[c2] =
              (uint32_t)l0 | ((uint32_t)l1 << 16);
        }
        acc[t][0] += xn0;
        acc[t][1] += xn1;
      }
    }
  }
#pragma unroll
  for (int t = 0; t < T2; ++t) {
    int c2 = lane + 64 * t;
    if (c2 < P2) {
      int c = 2 * c2;
      part[((size_t)b * DIN + c) * WPB + w]     = acc[t][0];
      part[((size_t)b * DIN + c + 1) * WPB + w] = acc[t][1];
    }
  }
}

// ---------------------------------------------------------------------------
// st_k: per (batch, col-chunk): xm = mean_tokens (from [b][c][WPB] part),
// st[chunk cols] = xm @ W + bias -> global. 8 k-slices x float4-cols.
// ---------------------------------------------------------------------------
template<int DIN, int DOUT, int CHUNKS, int BLK>
__global__ __launch_bounds__(BLK)
void st_k(const float* __restrict__ part, const float* __restrict__ Wt,
          const float* __restrict__ bias, float* __restrict__ st_g)
{
  constexpr int C4 = DOUT / 4 / CHUNKS;   // float4 cols per chunk
  constexpr int CW = C4 * 4;
  constexpr int SL = 8;
  constexpr int RPS = DIN / SL;
  static_assert(BLK == C4 * SL, "block size");
  constexpr int CG = BLK / 4;             // col-groups in phase A
  static_assert(DIN % CG == 0, "phase A tiling");
  constexpr int QW = WPB / 4;             // 56 floats = 14 f32x4 per quarter

  __shared__ float xm[DIN];
  __shared__ float redA[4][DIN];
  __shared__ float redB[SL][CW];

  const int b = blockIdx.x, ch = blockIdx.y, tid = threadIdx.x;

  // phase A: xm (4 threads per column, 14 independent float4 each)
  {
    const int cg = tid >> 2, wq = tid & 3;
#pragma unroll
    for (int i = 0; i < DIN / CG; ++i) {
      int c = cg + i * CG;
      const float* p = part + ((size_t)b * DIN + c) * WPB + wq * QW;
      f32x4 a = {0.f, 0.f, 0.f, 0.f};
#pragma unroll
      for (int u = 0; u < QW / 4; ++u) {
        f32x4 t0 = *(const f32x4*)(p + u * 4);
        a[0] += t0[0]; a[1] += t0[1]; a[2] += t0[2]; a[3] += t0[3];
      }
      redA[wq][c] = (a[0] + a[1]) + (a[2] + a[3]);
    }
  }
  __syncthreads();
  for (int c = tid; c < DIN; c += BLK)
    xm[c] = ((redA[0][c]+redA[1][c]) + (redA[2][c]+redA[3][c])) * (1.f/(float)NTOK);
  __syncthreads();

  // phase B: st chunk = xm @ W + bias
  {
    const int j4 = tid % C4, sl = tid / C4;
    const float* wp = Wt + (size_t)(sl * RPS) * DOUT + ch * CW + j4 * 4;
    f32x4 acc = {0.f, 0.f, 0.f, 0.f};
#pragma unroll
    for (int r = 0; r < RPS; ++r) {
      f32x4 wv = *(const f32x4*)(wp + (size_t)r * DOUT);
      float xv = xm[sl * RPS + r];
      acc[0] = fmaf(xv, wv[0], acc[0]);
      acc[1] = fmaf(xv, wv[1], acc[1]);
      acc[2] = fmaf(xv, wv[2], acc[2]);
      acc[3] = fmaf(xv, wv[3], acc[3]);
    }
    *(f32x4*)&redB[sl][j4 * 4] = acc;
  }
  __syncthreads();
  if (tid < CW) {
    int c = ch * CW + tid;
    float t0 = (redB[0][tid]+redB[1][tid]) + (redB[2][tid]+redB[3][tid]);
    float t1 = (redB[4][tid]+redB[5][tid]) + (redB[6][tid]+redB[7][tid]);
    st_g[(size_t)b * DOUT + c] = bias[c] + t0 + t1;
  }
}

// ---------------------------------------------------------------------------
// hscrank_k: per batch: h = relu(st@W1+b1), sc = h@W2+b2, stable rank -> mask.
// ---------------------------------------------------------------------------
template<int DOUT>
__global__ __launch_bounds__(1024)
void hscrank_k(const float* __restrict__ st_g,
               const float* __restrict__ W1, const float* __restrict__ b1,
               const float* __restrict__ W2, const float* __restrict__ b2,
               float* __restrict__ mask, int k)
{
  constexpr int DH  = DOUT / 4;
  constexpr int DH4 = DH / 4;
  constexpr int NSLC = (1024 / DH4 < 64) ? 1024 / DH4 : 64;
  constexpr int RPSC = (DOUT + NSLC - 1) / NSLC;
  constexpr int C4  = DOUT / 4;
  constexpr int NSLD = (1024 / C4 < 64) ? 1024 / C4 : 64;
  constexpr int RPSD = (DH + NSLD - 1) / NSLD;

  __shared__ float st[DOUT];
  __shared__ float h[DH];
  __shared__ float sc[DOUT];
  __shared__ float red[4096];

  const int b = blockIdx.x, tid = threadIdx.x;

  for (int c = tid; c < DOUT; c += 1024) st[c] = st_g[(size_t)b * DOUT + c];
  __syncthreads();

  {
    const int j4 = tid % DH4, sl = tid / DH4;
    if (sl < NSLC) {
      f32x4 acc = {0.f, 0.f, 0.f, 0.f};
#pragma unroll
      for (int rr = 0; rr < RPSC; ++rr) {
        int r = sl * RPSC + rr;
        if (r < DOUT) {
          f32x4 wv = *(const f32x4*)(W1 + (size_t)r * DH + j4 * 4);
          float sv = st[r];
          acc[0] = fmaf(sv, wv[0], acc[0]);
          acc[1] = fmaf(sv, wv[1], acc[1]);
          acc[2] = fmaf(sv, wv[2], acc[2]);
          acc[3] = fmaf(sv, wv[3], acc[3]);
        }
      }
      *(f32x4*)&red[(size_t)sl * DH + j4 * 4] = acc;
    }
  }
  __syncthreads();
  if (tid < DH) {
    float a = 0.f;
#pragma unroll 4
    for (int sl = 0; sl < NSLC; ++sl) a += red[(size_t)sl * DH + tid];
    h[tid] = fmaxf(b1[tid] + a, 0.f);
  }
  __syncthreads();

  {
    const int c4 = tid % C4, sl = tid / C4;
    if (sl < NSLD) {
      f32x4 acc = {0.f, 0.f, 0.f, 0.f};
#pragma unroll
      for (int rr = 0; rr < RPSD; ++rr) {
        int r = sl * RPSD + rr;
        if (r < DH) {
          f32x4 wv = *(const f32x4*)(W2 + (size_t)r * DOUT + c4 * 4);
          float hv = h[r];
          acc[0] = fmaf(hv, wv[0], acc[0]);
          acc[1] = fmaf(hv, wv[1], acc[1]);
          acc[2] = fmaf(hv, wv[2], acc[2]);
          acc[3] = fmaf(hv, wv[3], acc[3]);
        }
      }
      *(f32x4*)&red[(size_t)sl * DOUT + c4 * 4] = acc;
    }
  }
  __syncthreads();
  for (int c = tid; c < DOUT; c += 1024) {
    float a = 0.f;
#pragma unroll 4
    for (int sl = 0; sl < NSLD; ++sl) a += red[(size_t)sl * DOUT + c];
    sc[c] = b2[c] + a;
  }
  __syncthreads();

  for (int c = tid; c < DOUT; c += 1024) {
    float v = sc[c];
    int rank = 0;
#pragma unroll 8
    for (int j = 0; j < DOUT; ++j) {
      float u = sc[j];
      rank += (u > v) || (u == v && j < c);
    }
    mask[(size_t)b * DOUT + c] = (rank < k) ? 1.f : 0.f;
  }
}

// ---------------------------------------------------------------------------
// All 4 stages' W [K][N] fp32 -> hi/lo bf16 [Npad][K], hoisted to the start.
// ---------------------------------------------------------------------------
__global__ __launch_bounds__(256)
void convW_all_k(const float* __restrict__ W0, const float* __restrict__ W1,
                 const float* __restrict__ W2, const float* __restrict__ W3,
                 ushort* __restrict__ hi, ushort* __restrict__ lo)
{
  const int Kd[4]   = { 96, 96, 192, 384 };
  const int Nd[4]   = { 96, 192, 384, 768 };
  const int off[5]  = { 0, 12288, 36864, 110592, 405504 };
  const float* Wp[4] = { W0, W1, W2, W3 };

  int idx = blockIdx.x * 256 + threadIdx.x;
  if (idx >= 405504) return;
  int s = (idx >= off[1]) + (idx >= off[2]) + (idx >= off[3]);
  int local = idx - off[s];
  int K = Kd[s], N = Nd[s];
  int n = local / K, kk = local - n * K;
  float v = (n < N) ? Wp[s][(size_t)kk * N + n] : 0.f;
  ushort h = f2bf(v);
  hi[idx] = h;
  lo[idx] = f2bf(v - bf2f(h));
}

// ---------------------------------------------------------------------------
// MFMA GEMM: 128xBN tile (BN in {128,192,256}), BK=32, 4 waves (2x2; wave =
// 64 x BN/2). Source-pre-swizzled linear LDS + global_load_lds(16B).
// Triple-buffered, counted s_waitcnt vmcnt(IS) (IS = 2+BN/64 issues/step),
// raw s_barrier; STAGE(t+2) issued after the barrier (race-free). Epilogue:
// batch via boundary compare, mask/bias hoisted.
// ---------------------------------------------------------------------------
#define ASYNC16(GP, LP) __builtin_amdgcn_global_load_lds( \
    (const __attribute__((address_space(1))) void*)(GP),  \
    (__attribute__((address_space(3))) void*)(LP), 16, 0, 0)

template<int K, int NSEG, int BN>
__global__ __launch_bounds__(256)
void gemm_mfma_k(const ushort* __restrict__ a0, const ushort* __restrict__ a1,
                 const ushort* __restrict__ a2,
                 const ushort* __restrict__ b0, const ushort* __restrict__ b1,
                 const ushort* __restrict__ b2,
                 const float* __restrict__ bias, const float* __restrict__ msk,
                 float* __restrict__ C, int N)
{
  constexpr int KSTEPS = K / 32;
  constexpr int NT  = NSEG * KSTEPS;
  constexpr int WN  = BN / 2;       // wave n-width
  constexpr int NFR = WN / 16;      // B frags per wave (4/6/8)
  constexpr int BR  = BN / 64;      // B stage row-groups (2/3/4)
  __shared__ __align__(16) ushort ldsA[3][128 * 32];
  __shared__ __align__(16) ushort ldsB[3][BN * 32];

  const int tid  = threadIdx.x;
  const int lane = tid & 63;
  const int wid  = tid >> 6;
  const int wm = wid >> 1, wn = wid & 1;

  // XCD-chunked bijective remap (gridDim.x % 8 == 0), n-tile innermost.
  const int NBN = (N + BN - 1) / BN;
  const int q8  = gridDim.x >> 3;
  const int bid = blockIdx.x;
  const int wg  = (bid & 7) * q8 + (bid >> 3);
  const int mt  = wg / NBN;
  const int nt  = wg - mt * NBN;
  const size_t row0 = (size_t)mt * 128;
  const int n0 = nt * BN;

  const ushort* Aseg[3] = { a0, a1, a2 };
  const ushort* Bseg[3] = { b0, b1, b2 };

  f32x4 acc[4][NFR];
#pragma unroll
  for (int i = 0; i < 4; ++i)
#pragma unroll
    for (int j = 0; j < NFR; ++j) acc[i][j] = { 0.f, 0.f, 0.f, 0.f };

  const int c_row  = tid >> 2;
  const int c_phys = tid & 3;

#define STAGE(BUF, T)                                                          \
  {                                                                            \
    const int seg_ = (T) / KSTEPS;                                             \
    const int k0_  = ((T) % KSTEPS) * 32;                                      \
    const ushort* ap_ = Aseg[seg_];                                            \
    const ushort* bp_ = Bseg[seg_];                                            \
    _Pragma("unroll")                                                          \
    for (int r_ = 0; r_ < 2; ++r_) {                                           \
      int row_  = c_row + r_ * 64;                                             \
      int slot_ = c_phys ^ ((row_ >> 1) & 3);                                  \
      ASYNC16(ap_ + (row0 + row_) * (size_t)K + (k0_ + slot_ * 8),             \
              &ldsA[BUF][(row_ * 4 + c_phys) * 8]);                            \
    }                                                                          \
    _Pragma("unroll")                                                          \
    for (int r_ = 0; r_ < BR; ++r_) {                                          \
      int row_  = c_row + r_ * 64;                                             \
      int slot_ = c_phys ^ ((row_ >> 1) & 3);                                  \
      ASYNC16(bp_ + (size_t)(n0 + row_) * K + (k0_ + slot_ * 8),               \
              &ldsB[BUF][(row_ * 4 + c_phys) * 8]);                            \
    }                                                                          \
  }

  STAGE(0, 0);
  STAGE(1, 1);
#pragma unroll
  for (int t = 0; t < NT; ++t) {
    // wait for buf t's loads (the next stage's loads may stay in flight)
    if (t == NT - 1)            { asm volatile("s_waitcnt vmcnt(0)" ::: "memory"); }
    else if constexpr (BN == 128) { asm volatile("s_waitcnt vmcnt(4)" ::: "memory"); }
    else if constexpr (BN == 192) { asm volatile("s_waitcnt vmcnt(5)" ::: "memory"); }
    else                          { asm volatile("s_waitcnt vmcnt(6)" ::: "memory"); }
    __builtin_amdgcn_s_barrier();
    if (t + 2 < NT) STAGE((t + 2) % 3, t + 2);
    const int buf = t % 3;
    const int slot = lane >> 4;
    const int r16  = lane & 15;
    bf16x8 af[4], bfr[NFR];
#pragma unroll
    for (int mi = 0; mi < 4; ++mi) {
      int r = wm * 64 + mi * 16 + r16;
      af[mi] = *(const bf16x8*)&ldsA[buf][(r * 4 + (slot ^ ((r >> 1) & 3))) * 8];
    }
#pragma unroll
    for (int ni = 0; ni < NFR; ++ni) {
      int r = wn * WN + ni * 16 + r16;
      bfr[ni] = *(const bf16x8*)&ldsB[buf][(r * 4 + (slot ^ ((r >> 1) & 3))) * 8];
    }
#pragma unroll
    for (int mi = 0; mi < 4; ++mi)
#pragma unroll
      for (int ni = 0; ni < NFR; ++ni)
        acc[mi][ni] = __builtin_amdgcn_mfma_f32_16x16x32_bf16(af[mi], bfr[ni],
                                                              acc[mi][ni], 0, 0, 0);
  }

  // epilogue: no divisions; mask/bias hoisted per output column
  const int b0i = (int)(row0 / NTOK);              // scalar, once
  const size_t rowB = (size_t)(b0i + 1) * NTOK;    // batch boundary row
  const bool straddle = (rowB < row0 + 128) && (b0i + 1 < 32);

#pragma unroll
  for (int ni = 0; ni < NFR; ++ni) {
    int n = n0 + wn * WN + ni * 16 + (lane & 15);
    if (n < N) {
      float bv  = bias[n];
      float mk0 = msk[(size_t)b0i * N + n];
      float mk1 = straddle ? msk[(size_t)(b0i + 1) * N + n] : mk0;
#pragma unroll
      for (int mi = 0; mi < 4; ++mi) {
#pragma unroll
        for (int q = 0; q < 4; ++q) {
          size_t m = row0 + (size_t)(wm * 64 + mi * 16 + (lane >> 4) * 4 + q);
          float mv = (m < rowB) ? mk0 : mk1;
          C[m * (size_t)N + n] = (acc[mi][ni][q] + bv) * mv;
        }
      }
    }
  }
}

// ---------------------------------------------------------------------------
extern "C" void kernel_launch(void* const* d_in, const int* in_sizes, int n_in,
                              void* d_out, int out_size, void* d_ws, size_t ws_size,
                              hipStream_t stream)
{
  (void)in_sizes; (void)n_in; (void)out_size; (void)ws_size;
  const float* x = (const float*)d_in[0];
  const float *sg[4], *sb[4], *sW[4], *sbias[4], *pW1[4], *pb1[4], *pW2[4], *pb2[4];
  for (int s = 0; s < 4; ++s) {
    int base = 1 + s * 8;
    sg[s]    = (const float*)d_in[base + 0];
    sb[s]    = (const float*)d_in[base + 1];
    sW[s]    = (const float*)d_in[base + 2];
    sbias[s] = (const float*)d_in[base + 3];
    pW1[s]   = (const float*)d_in[base + 4];
    pb1[s]   = (const float*)d_in[base + 5];
    pW2[s]   = (const float*)d_in[base + 6];
    pb2[s]   = (const float*)d_in[base + 7];
  }

  // workspace layout (bytes, all 16-aligned):
  char* ws = (char*)d_ws;
  ushort* a_hi = (ushort*)(ws);                 // 77,070,336  (M*384 bf16)
  ushort* a_lo = (ushort*)(ws + 77070336);      // 38,535,168  (M*192 bf16)
  float*  part = (float*) (ws + 115605504);     // 11,010,048  ([b][c][224])
  float*  mk   = (float*) (ws + 126615552);     //     98,304
  ushort* w_hi = (ushort*)(ws + 126713856);     //    811,008
  ushort* w_lo = (ushort*)(ws + 127524864);     //    811,008
  float*  st_g = (float*) (ws + 128335872);     //     98,304  -> end 128,434,176

  const int woff[4] = { 0, 12288, 36864, 110592 };

  // z1..z3 aliased into d_out (all dead before stage-4 GEMM overwrites):
  float* out = (float*)d_out;
  float* z3 = out;              // M*384
  float* z2 = out + 38535168;   // M*192
  float* z1 = out + 57802752;   // M*96

  convW_all_k<<<(405504 + 255) / 256, 256, 0, stream>>>(
      sW[0], sW[1], sW[2], sW[3], w_hi, w_lo);

  // LN grid: 32 batches * WPB waves / 4 waves-per-block = 1792 blocks
  const int LNG = 32 * WPB / 4;

  // ---- stage 1: K=96 -> N=96 (Npad=128), k = 86, BN=128, 1 n-tile
  ln_colsum_k<96, true><<<LNG, 256, 0, stream>>>(x, sg[0], sb[0], a_hi, a_lo, part);
  st_k<96, 96, 1, 192><<<dim3(32, 1), 192, 0, stream>>>(part, sW[0], sbias[0], st_g);
  hscrank_k<96><<<32, 1024, 0, stream>>>(st_g, pW1[0], pb1[0], pW2[0], pb2[0], mk, 86);
  gemm_mfma_k<96, 3, 128><<<784, 256, 0, stream>>>(
      a_hi, a_hi, a_lo, w_hi + woff[0], w_lo + woff[0], w_hi + woff[0],
      sbias[0], mk, z1, 96);

  // ---- stage 2: K=96 -> N=192 (Npad=256), k = 134, BN=192, 1 n-tile
  ln_colsum_k<96, true><<<LNG, 256, 0, stream>>>(z1, sg[1], sb[1], a_hi, a_lo, part);
  st_k<96, 192, 1, 384><<<dim3(32, 1), 384, 0, stream>>>(part, sW[1], sbias[1], st_g);
  hscrank_k<192><<<32, 1024, 0, stream>>>(st_g, pW1[1], pb1[1], pW2[1], pb2[1], mk, 134);
  gemm_mfma_k<96, 3, 192><<<784, 256, 0, stream>>>(
      a_hi, a_hi, a_lo, w_hi + woff[1], w_lo + woff[1], w_hi + woff[1],
      sbias[1], mk, z2, 192);

  // ---- stage 3: K=192 -> N=384, k = 192, BN=192, 2 n-tiles (exact)
  ln_colsum_k<192, true><<<LNG, 256, 0, stream>>>(z2, sg[2], sb[2], a_hi, a_lo, part);
  st_k<192, 384, 2, 384><<<dim3(32, 2), 384, 0, stream>>>(part, sW[2], sbias[2], st_g);
  hscrank_k<384><<<32, 1024, 0, stream>>>(st_g, pW1[2], pb1[2], pW2[2], pb2[2], mk, 192);
  gemm_mfma_k<192, 3, 192><<<784 * 2, 256, 0, stream>>>(
      a_hi, a_hi, a_lo, w_hi + woff[2], w_lo + woff[2], w_hi + woff[2],
      sbias[2], mk, z3, 384);

  // ---- stage 4: K=384 -> N=768, k = 230, BN=256, 3 n-tiles (exact)
  ln_colsum_k<384, false><<<LNG, 256, 0, stream>>>(z3, sg[3], sb[3], a_hi, a_hi, part);
  st_k<384, 768, 4, 384><<<dim3(32, 4), 384, 0, stream>>>(part, sW[3], sbias[3], st_g);
  hscrank_k<768><<<32, 1024, 0, stream>>>(st_g, pW1[3], pb1[3], pW2[3], pb2[3], mk, 230);
  gemm_mfma_k<384, 1, 256><<<784 * 3, 256, 0, stream>>>(
      a_hi, a_hi, a_hi, w_hi + woff[3], w_hi + woff[3], w_hi + woff[3],
      sbias[3], mk, out, 768);
}

// Round 8
// 558.974 us; speedup vs baseline: 1.0600x; 1.0600x over previous
//
#include <hip/hip_runtime.h>
#include <hip/hip_bf16.h>
#include <stdint.h>

#define NTOK 3136
#define MTOT 100352
#define RPW  14          // rows per LN wave (stage-1 LN only)
#define WPB  224         // LN waves per batch (NTOK/RPW)

typedef __attribute__((ext_vector_type(8))) short bf16x8;
typedef __attribute__((ext_vector_type(4))) float f32x4;
typedef __attribute__((ext_vector_type(2))) float f32x2;

static __device__ __forceinline__ ushort f2bf(float x) {
  union { float f; uint32_t u; } c; c.f = x;
  uint32_t r = (c.u + 0x7FFFu + ((c.u >> 16) & 1u)) >> 16;   // RNE
  return (ushort)r;
}
static __device__ __forceinline__ float bf2f(ushort h) {
  union { uint32_t u; float f; } c; c.u = ((uint32_t)h) << 16;
  return c.f;
}

// ---------------------------------------------------------------------------
// Stage-1 LayerNorm (reads fp32 x) + fp32 column partial sums.
// part layout: [b][c][WPB].
// ---------------------------------------------------------------------------
template<int DIN, bool WLO>
__global__ __launch_bounds__(256)
void ln_colsum_k(const float* __restrict__ in, const float* __restrict__ gma,
                 const float* __restrict__ bta, ushort* __restrict__ oh,
                 ushort* __restrict__ ol, float* __restrict__ part)
{
  constexpr int P2 = DIN / 2;
  constexpr int T2 = (P2 + 63) / 64;
  const int wid  = (blockIdx.x * 256 + threadIdx.x) >> 6;
  const int lane = threadIdx.x & 63;
  const int b = wid / WPB;
  const int w = wid - b * WPB;

  f32x2 gv[T2], bv[T2], acc[T2];
#pragma unroll
  for (int t = 0; t < T2; ++t) {
    int c2 = lane + 64 * t;
    if (c2 < P2) {
      gv[t] = *(const f32x2*)(gma + 2 * c2);
      bv[t] = *(const f32x2*)(bta + 2 * c2);
    } else { gv[t] = {0.f, 0.f}; bv[t] = {0.f, 0.f}; }
    acc[t] = {0.f, 0.f};
  }

  const size_t rbase = ((size_t)b * NTOK + (size_t)w * RPW) * DIN;
  const float* ip = in + rbase;
  ushort* oph = oh + rbase;
  ushort* opl = ol + rbase;

  for (int j = 0; j < RPW; ++j) {
    f32x2 v[T2];
    float s = 0.f, sq = 0.f;
#pragma unroll
    for (int t = 0; t < T2; ++t) {
      int c2 = lane + 64 * t;
      f32x2 xv = {0.f, 0.f};
      if (c2 < P2) xv = *(const f32x2*)(ip + (size_t)j * DIN + 2 * c2);
      v[t] = xv;
      s  += xv[0] + xv[1];
      sq += xv[0] * xv[0] + xv[1] * xv[1];
    }
#pragma unroll
    for (int off = 1; off < 64; off <<= 1) {
      s  += __shfl_xor(s, off);
      sq += __shfl_xor(sq, off);
    }
    float m   = s / (float)DIN;
    float var = sq / (float)DIN - m * m;
    float r   = 1.f / sqrtf(var + 1e-5f);
#pragma unroll
    for (int t = 0; t < T2; ++t) {
      int c2 = lane + 64 * t;
      if (c2 < P2) {
        float xn0 = (v[t][0] - m) * r * gv[t][0] + bv[t][0];
        float xn1 = (v[t][1] - m) * r * gv[t][1] + bv[t][1];
        ushort h0 = f2bf(xn0), h1 = f2bf(xn1);
        ((uint32_t*)(oph + (size_t)j * DIN))[c2] =
            (uint32_t)h0 | ((uint32_t)h1 << 16);
        if (WLO) {
          ushort l0 = f2bf(xn0 - bf2f(h0)), l1 = f2bf(xn1 - bf2f(h1));
          ((uint32_t*)(opl + (size_t)j * DIN))[c2] =
              (uint32_t)l0 | ((uint32_t)l1 << 16);
        }
        acc[t][0] += xn0;
        acc[t][1] += xn1;
      }
    }
  }
#pragma unroll
  for (int t = 0; t < T2; ++t) {
    int c2 = lane + 64 * t;
    if (c2 < P2) {
      int c = 2 * c2;
      part[((size_t)b * DIN + c) * WPB + w]     = acc[t][0];
      part[((size_t)b * DIN + c + 1) * WPB + w] = acc[t][1];
    }
  }
}

// ---------------------------------------------------------------------------
// st_k: xm = mean_tokens, st = xm @ W + bias -> global.
// SLOTS=224: part [b][c][224] (from ln_colsum). SLOTS=25: part [b][c][25]
// (from fused GEMM epilogue; 25 slots of 128-row block sums).
// ---------------------------------------------------------------------------
template<int DIN, int DOUT, int CHUNKS, int BLK, int SLOTS>
__global__ __launch_bounds__(BLK)
void st_k(const float* __restrict__ part, const float* __restrict__ Wt,
          const float* __restrict__ bias, float* __restrict__ st_g)
{
  constexpr int C4 = DOUT / 4 / CHUNKS;
  constexpr int CW = C4 * 4;
  constexpr int SL = 8;
  constexpr int RPS = DIN / SL;
  static_assert(BLK == C4 * SL, "block size");

  __shared__ float xm[DIN];
  __shared__ float redB[SL][CW];

  const int b = blockIdx.x, ch = blockIdx.y, tid = threadIdx.x;

  if constexpr (SLOTS == 25) {
    static_assert(BLK >= DIN, "one thread per col");
    if (tid < DIN) {
      const float* p = part + ((size_t)b * DIN + tid) * 25;
      float s = 0.f;
#pragma unroll
      for (int i = 0; i < 25; ++i) s += p[i];
      xm[tid] = s * (1.f / (float)NTOK);
    }
    __syncthreads();
  } else {
    constexpr int CG = BLK / 4;
    static_assert(DIN % CG == 0, "phase A tiling");
    constexpr int QW = WPB / 4;
    __shared__ float redA[4][DIN];
    {
      const int cg = tid >> 2, wq = tid & 3;
#pragma unroll
      for (int i = 0; i < DIN / CG; ++i) {
        int c = cg + i * CG;
        const float* p = part + ((size_t)b * DIN + c) * WPB + wq * QW;
        f32x4 a = {0.f, 0.f, 0.f, 0.f};
#pragma unroll
        for (int u = 0; u < QW / 4; ++u) {
          f32x4 t0 = *(const f32x4*)(p + u * 4);
          a[0] += t0[0]; a[1] += t0[1]; a[2] += t0[2]; a[3] += t0[3];
        }
        redA[wq][c] = (a[0] + a[1]) + (a[2] + a[3]);
      }
    }
    __syncthreads();
    for (int c = tid; c < DIN; c += BLK)
      xm[c] = ((redA[0][c]+redA[1][c]) + (redA[2][c]+redA[3][c])) * (1.f/(float)NTOK);
    __syncthreads();
  }

  // phase B: st chunk = xm @ W + bias
  {
    const int j4 = tid % C4, sl = tid / C4;
    const float* wp = Wt + (size_t)(sl * RPS) * DOUT + ch * CW + j4 * 4;
    f32x4 acc = {0.f, 0.f, 0.f, 0.f};
#pragma unroll
    for (int r = 0; r < RPS; ++r) {
      f32x4 wv = *(const f32x4*)(wp + (size_t)r * DOUT);
      float xv = xm[sl * RPS + r];
      acc[0] = fmaf(xv, wv[0], acc[0]);
      acc[1] = fmaf(xv, wv[1], acc[1]);
      acc[2] = fmaf(xv, wv[2], acc[2]);
      acc[3] = fmaf(xv, wv[3], acc[3]);
    }
    *(f32x4*)&redB[sl][j4 * 4] = acc;
  }
  __syncthreads();
  if (tid < CW) {
    int c = ch * CW + tid;
    float t0 = (redB[0][tid]+redB[1][tid]) + (redB[2][tid]+redB[3][tid]);
    float t1 = (redB[4][tid]+redB[5][tid]) + (redB[6][tid]+redB[7][tid]);
    st_g[(size_t)b * DOUT + c] = bias[c] + t0 + t1;
  }
}

// ---------------------------------------------------------------------------
// hscrank_k: h = relu(st@W1+b1), sc = h@W2+b2, stable rank -> mask.
// ---------------------------------------------------------------------------
template<int DOUT>
__global__ __launch_bounds__(1024)
void hscrank_k(const float* __restrict__ st_g,
               const float* __restrict__ W1, const float* __restrict__ b1,
               const float* __restrict__ W2, const float* __restrict__ b2,
               float* __restrict__ mask, int k)
{
  constexpr int DH  = DOUT / 4;
  constexpr int DH4 = DH / 4;
  constexpr int NSLC = (1024 / DH4 < 64) ? 1024 / DH4 : 64;
  constexpr int RPSC = (DOUT + NSLC - 1) / NSLC;
  constexpr int C4  = DOUT / 4;
  constexpr int NSLD = (1024 / C4 < 64) ? 1024 / C4 : 64;
  constexpr int RPSD = (DH + NSLD - 1) / NSLD;

  __shared__ float st[DOUT];
  __shared__ float h[DH];
  __shared__ float sc[DOUT];
  __shared__ float red[4096];

  const int b = blockIdx.x, tid = threadIdx.x;

  for (int c = tid; c < DOUT; c += 1024) st[c] = st_g[(size_t)b * DOUT + c];
  __syncthreads();

  {
    const int j4 = tid % DH4, sl = tid / DH4;
    if (sl < NSLC) {
      f32x4 acc = {0.f, 0.f, 0.f, 0.f};
#pragma unroll
      for (int rr = 0; rr < RPSC; ++rr) {
        int r = sl * RPSC + rr;
        if (r < DOUT) {
          f32x4 wv = *(const f32x4*)(W1 + (size_t)r * DH + j4 * 4);
          float sv = st[r];
          acc[0] = fmaf(sv, wv[0], acc[0]);
          acc[1] = fmaf(sv, wv[1], acc[1]);
          acc[2] = fmaf(sv, wv[2], acc[2]);
          acc[3] = fmaf(sv, wv[3], acc[3]);
        }
      }
      *(f32x4*)&red[(size_t)sl * DH + j4 * 4] = acc;
    }
  }
  __syncthreads();
  if (tid < DH) {
    float a = 0.f;
#pragma unroll 4
    for (int sl = 0; sl < NSLC; ++sl) a += red[(size_t)sl * DH + tid];
    h[tid] = fmaxf(b1[tid] + a, 0.f);
  }
  __syncthreads();

  {
    const int c4 = tid % C4, sl = tid / C4;
    if (sl < NSLD) {
      f32x4 acc = {0.f, 0.f, 0.f, 0.f};
#pragma unroll
      for (int rr = 0; rr < RPSD; ++rr) {
        int r = sl * RPSD + rr;
        if (r < DH) {
          f32x4 wv = *(const f32x4*)(W2 + (size_t)r * DOUT + c4 * 4);
          float hv = h[r];
          acc[0] = fmaf(hv, wv[0], acc[0]);
          acc[1] = fmaf(hv, wv[1], acc[1]);
          acc[2] = fmaf(hv, wv[2], acc[2]);
          acc[3] = fmaf(hv, wv[3], acc[3]);
        }
      }
      *(f32x4*)&red[(size_t)sl * DOUT + c4 * 4] = acc;
    }
  }
  __syncthreads();
  for (int c = tid; c < DOUT; c += 1024) {
    float a = 0.f;
#pragma unroll 4
    for (int sl = 0; sl < NSLD; ++sl) a += red[(size_t)sl * DOUT + c];
    sc[c] = b2[c] + a;
  }
  __syncthreads();

  for (int c = tid; c < DOUT; c += 1024) {
    float v = sc[c];
    int rank = 0;
#pragma unroll 8
    for (int j = 0; j < DOUT; ++j) {
      float u = sc[j];
      rank += (u > v) || (u == v && j < c);
    }
    mask[(size_t)b * DOUT + c] = (rank < k) ? 1.f : 0.f;
  }
}

// ---------------------------------------------------------------------------
// All 4 stages' W [K][N] fp32 -> hi/lo bf16 [Npad][K].
// ---------------------------------------------------------------------------
__global__ __launch_bounds__(256)
void convW_all_k(const float* __restrict__ W0, const float* __restrict__ W1,
                 const float* __restrict__ W2, const float* __restrict__ W3,
                 ushort* __restrict__ hi, ushort* __restrict__ lo)
{
  const int Kd[4]   = { 96, 96, 192, 384 };
  const int Nd[4]   = { 96, 192, 384, 768 };
  const int off[5]  = { 0, 12288, 36864, 110592, 405504 };
  const float* Wp[4] = { W0, W1, W2, W3 };

  int idx = blockIdx.x * 256 + threadIdx.x;
  if (idx >= 405504) return;
  int s = (idx >= off[1]) + (idx >= off[2]) + (idx >= off[3]);
  int local = idx - off[s];
  int K = Kd[s], N = Nd[s];
  int n = local / K, kk = local - n * K;
  float v = (n < N) ? Wp[s][(size_t)kk * N + n] : 0.f;
  ushort h = f2bf(v);
  hi[idx] = h;
  lo[idx] = f2bf(v - bf2f(h));
}

#define ASYNC16(GP, LP) __builtin_amdgcn_global_load_lds( \
    (const __attribute__((address_space(1))) void*)(GP),  \
    (__attribute__((address_space(3))) void*)(LP), 16, 0, 0)

// ---------------------------------------------------------------------------
// FUSED GEMM + bias + mask + LayerNorm-for-next-stage + colsum epilogue.
// Block = 128 rows x ALL N cols (single n-tile). 2m x NWN waves.
// Triple-buffered counted-vmcnt K-loop (as before). Epilogue: row Σ/Σ² via
// 16-lane shuffles + cross-wave LDS, normalize with next stage's γ/β, write
// bf16 hi(/lo) x̃, per-block column sums -> part[b][c][25] (slot per m-tile).
// ---------------------------------------------------------------------------
template<int K, int NSEG, int BNL, int N, int NWN, bool WLO>
__global__ __launch_bounds__(128 * NWN)
void gemm_ln_k(const ushort* __restrict__ a0, const ushort* __restrict__ a1,
               const ushort* __restrict__ a2,
               const ushort* __restrict__ b0, const ushort* __restrict__ b1,
               const ushort* __restrict__ b2,
               const float* __restrict__ bias, const float* __restrict__ msk,
               const float* __restrict__ gnext, const float* __restrict__ bnext,
               ushort* __restrict__ oh, ushort* __restrict__ ol,
               float* __restrict__ part)
{
  constexpr int T   = 128 * NWN;
  constexpr int R   = T / 4;        // rows per staging issue
  constexpr int AI  = 128 / R;
  constexpr int BI  = BNL / R;
  constexpr int IS  = AI + BI;      // issues per K-step
  constexpr int WN  = N / NWN;
  constexpr int NFR = WN / 16;
  constexpr int KSTEPS = K / 32;
  constexpr int NT  = NSEG * KSTEPS;
  __shared__ __align__(16) ushort ldsA[3][128 * 32];
  __shared__ __align__(16) ushort ldsB[3][BNL * 32];

  const int tid  = threadIdx.x;
  const int lane = tid & 63;
  const int wid  = tid >> 6;
  const int wm = wid & 1, wn = wid >> 1;

  const int q8  = gridDim.x >> 3;
  const int bid = blockIdx.x;
  const int mt  = (bid & 7) * q8 + (bid >> 3);
  const size_t row0 = (size_t)mt * 128;

  const ushort* Aseg[3] = { a0, a1, a2 };
  const ushort* Bseg[3] = { b0, b1, b2 };

  f32x4 acc[4][NFR];
#pragma unroll
  for (int i = 0; i < 4; ++i)
#pragma unroll
    for (int j = 0; j < NFR; ++j) acc[i][j] = { 0.f, 0.f, 0.f, 0.f };

  const int c_row  = tid >> 2;
  const int c_phys = tid & 3;

#define STAGEF(BUF, TT)                                                        \
  {                                                                            \
    const int seg_ = (TT) / KSTEPS;                                            \
    const int k0_  = ((TT) % KSTEPS) * 32;                                     \
    const ushort* ap_ = Aseg[seg_];                                            \
    const ushort* bp_ = Bseg[seg_];                                            \
    _Pragma("unroll")                                                          \
    for (int r_ = 0; r_ < AI; ++r_) {                                          \
      int row_  = c_row + r_ * R;                                              \
      int slot_ = c_phys ^ ((row_ >> 1) & 3);                                  \
      ASYNC16(ap_ + (row0 + row_) * (size_t)K + (k0_ + slot_ * 8),             \
              &ldsA[BUF][(row_ * 4 + c_phys) * 8]);                            \
    }                                                                          \
    _Pragma("unroll")                                                          \
    for (int r_ = 0; r_ < BI; ++r_) {                                          \
      int row_  = c_row + r_ * R;                                              \
      int slot_ = c_phys ^ ((row_ >> 1) & 3);                                  \
      ASYNC16(bp_ + (size_t)row_ * K + (k0_ + slot_ * 8),                      \
              &ldsB[BUF][(row_ * 4 + c_phys) * 8]);                            \
    }                                                                          \
  }

  STAGEF(0, 0);
  STAGEF(1, 1);
#pragma unroll
  for (int t = 0; t < NT; ++t) {
    if (t == NT - 1)            { asm volatile("s_waitcnt vmcnt(0)" ::: "memory"); }
    else if constexpr (IS == 4) { asm volatile("s_waitcnt vmcnt(4)" ::: "memory"); }
    else                        { asm volatile("s_waitcnt vmcnt(5)" ::: "memory"); }
    __builtin_amdgcn_s_barrier();
    if (t + 2 < NT) STAGEF((t + 2) % 3, t + 2);
    const int buf = t % 3;
    const int slot = lane >> 4;
    const int r16  = lane & 15;
    bf16x8 af[4], bfr[NFR];
#pragma unroll
    for (int mi = 0; mi < 4; ++mi) {
      int r = wm * 64 + mi * 16 + r16;
      af[mi] = *(const bf16x8*)&ldsA[buf][(r * 4 + (slot ^ ((r >> 1) & 3))) * 8];
    }
#pragma unroll
    for (int ni = 0; ni < NFR; ++ni) {
      int r = wn * WN + ni * 16 + r16;
      bfr[ni] = *(const bf16x8*)&ldsB[buf][(r * 4 + (slot ^ ((r >> 1) & 3))) * 8];
    }
#pragma unroll
    for (int mi = 0; mi < 4; ++mi)
#pragma unroll
      for (int ni = 0; ni < NFR; ++ni)
        acc[mi][ni] = __builtin_amdgcn_mfma_f32_16x16x32_bf16(af[mi], bfr[ni],
                                                              acc[mi][ni], 0, 0, 0);
  }
#undef STAGEF

  // ---------------- fused epilogue ----------------
  __syncthreads();                       // all LDS reads done; reuse ldsA

  float* rowred = (float*)&ldsA[0][0];   // [NWN][128][2]
  float* colred = rowred + NWN * 256;    // [2 sets][2 wm][N]

  const int l15 = lane & 15, l4 = lane >> 4;
  const int b0i = (int)(row0 / NTOK);
  const size_t rowB = (size_t)(b0i + 1) * NTOK;
  const bool strad = rowB < row0 + 128;

  float biasv[NFR], mk0a[NFR], mk1a[NFR], gvn[NFR], bvn[NFR];
#pragma unroll
  for (int ni = 0; ni < NFR; ++ni) {
    int n = wn * WN + ni * 16 + l15;
    biasv[ni] = bias[n];
    mk0a[ni] = msk[(size_t)b0i * N + n];
    mk1a[ni] = strad ? msk[(size_t)(b0i + 1) * N + n] : mk0a[ni];
    gvn[ni] = gnext[n];
    bvn[ni] = bnext[n];
  }

  // v = (acc+bias)*mask, row partial sums
  float rs[16], rq[16];
#pragma unroll
  for (int i = 0; i < 16; ++i) { rs[i] = 0.f; rq[i] = 0.f; }
#pragma unroll
  for (int mi = 0; mi < 4; ++mi)
#pragma unroll
    for (int q = 0; q < 4; ++q) {
      size_t row = row0 + wm * 64 + mi * 16 + l4 * 4 + q;
      bool loB = row < rowB;
#pragma unroll
      for (int ni = 0; ni < NFR; ++ni) {
        float v = (acc[mi][ni][q] + biasv[ni]) * (loB ? mk0a[ni] : mk1a[ni]);
        acc[mi][ni][q] = v;
        rs[mi * 4 + q] += v;
        rq[mi * 4 + q] += v * v;
      }
    }
#pragma unroll
  for (int off = 1; off < 16; off <<= 1)
#pragma unroll
    for (int i = 0; i < 16; ++i) {
      rs[i] += __shfl_xor(rs[i], off);
      rq[i] += __shfl_xor(rq[i], off);
    }
  if (l15 == 0) {
#pragma unroll
    for (int mi = 0; mi < 4; ++mi)
#pragma unroll
      for (int q = 0; q < 4; ++q) {
        int r = wm * 64 + mi * 16 + l4 * 4 + q;
        rowred[(wn * 128 + r) * 2 + 0] = rs[mi * 4 + q];
        rowred[(wn * 128 + r) * 2 + 1] = rq[mi * 4 + q];
      }
  }
  __syncthreads();

  float mean[16], rstd[16];
#pragma unroll
  for (int mi = 0; mi < 4; ++mi)
#pragma unroll
    for (int q = 0; q < 4; ++q) {
      int r = wm * 64 + mi * 16 + l4 * 4 + q;
      float S = 0.f, Q = 0.f;
#pragma unroll
      for (int w = 0; w < NWN; ++w) {
        S += rowred[(w * 128 + r) * 2 + 0];
        Q += rowred[(w * 128 + r) * 2 + 1];
      }
      float mn  = S / (float)N;
      float var = Q / (float)N - mn * mn;
      mean[mi * 4 + q] = mn;
      rstd[mi * 4 + q] = 1.f / sqrtf(var + 1e-5f);
    }

  // normalize, write bf16 x̃, column partials (split by batch if straddle)
  float cs0[NFR], cs1[NFR];
#pragma unroll
  for (int ni = 0; ni < NFR; ++ni) { cs0[ni] = 0.f; cs1[ni] = 0.f; }
#pragma unroll
  for (int mi = 0; mi < 4; ++mi)
#pragma unroll
    for (int q = 0; q < 4; ++q) {
      size_t row = row0 + wm * 64 + mi * 16 + l4 * 4 + q;
      bool loB = row < rowB;
      float mn = mean[mi * 4 + q], rv = rstd[mi * 4 + q];
#pragma unroll
      for (int ni = 0; ni < NFR; ++ni) {
        int n = wn * WN + ni * 16 + l15;
        float xn = (acc[mi][ni][q] - mn) * rv * gvn[ni] + bvn[ni];
        ushort hh = f2bf(xn);
        oh[row * N + n] = hh;
        if constexpr (WLO) ol[row * N + n] = f2bf(xn - bf2f(hh));
        if (loB) cs0[ni] += xn; else cs1[ni] += xn;
      }
    }
#pragma unroll
  for (int ni = 0; ni < NFR; ++ni) {
    cs0[ni] += __shfl_xor(cs0[ni], 16);
    cs0[ni] += __shfl_xor(cs0[ni], 32);
    cs1[ni] += __shfl_xor(cs1[ni], 16);
    cs1[ni] += __shfl_xor(cs1[ni], 32);
  }
  if (l4 == 0) {
#pragma unroll
    for (int ni = 0; ni < NFR; ++ni) {
      int n = wn * WN + ni * 16 + l15;
      colred[(0 * 2 + wm) * N + n] = cs0[ni];
      colred[(1 * 2 + wm) * N + n] = cs1[ni];
    }
  }
  __syncthreads();
  if (wm == 0 && l4 == 0) {
    const int mt_lo = (b0i * NTOK) >> 7;
    const int slot0 = mt - mt_lo;
#pragma unroll
    for (int ni = 0; ni < NFR; ++ni) {
      int n = wn * WN + ni * 16 + l15;
      float t0 = colred[0 * N + n] + colred[1 * N + n];
      part[((size_t)b0i * N + n) * 25 + slot0] = t0;
      if (strad) {
        float t1 = colred[2 * N + n] + colred[3 * N + n];
        part[((size_t)(b0i + 1) * N + n) * 25 + 0] = t1;
      }
    }
  }
}

// ---------------------------------------------------------------------------
// Stage-4 GEMM (no LN after): 128x256 tile, triple-buffer counted vmcnt.
// ---------------------------------------------------------------------------
template<int K, int NSEG, int BN>
__global__ __launch_bounds__(256)
void gemm_mfma_k(const ushort* __restrict__ a0, const ushort* __restrict__ a1,
                 const ushort* __restrict__ a2,
                 const ushort* __restrict__ b0, const ushort* __restrict__ b1,
                 const ushort* __restrict__ b2,
                 const float* __restrict__ bias, const float* __restrict__ msk,
                 float* __restrict__ C, int N)
{
  constexpr int KSTEPS = K / 32;
  constexpr int NT  = NSEG * KSTEPS;
  constexpr int WN  = BN / 2;
  constexpr int NFR = WN / 16;
  constexpr int BR  = BN / 64;
  __shared__ __align__(16) ushort ldsA[3][128 * 32];
  __shared__ __align__(16) ushort ldsB[3][BN * 32];

  const int tid  = threadIdx.x;
  const int lane = tid & 63;
  const int wid  = tid >> 6;
  const int wm = wid >> 1, wn = wid & 1;

  const int NBN = (N + BN - 1) / BN;
  const int q8  = gridDim.x >> 3;
  const int bid = blockIdx.x;
  const int wg  = (bid & 7) * q8 + (bid >> 3);
  const int mt  = wg / NBN;
  const int nt  = wg - mt * NBN;
  const size_t row0 = (size_t)mt * 128;
  const int n0 = nt * BN;

  const ushort* Aseg[3] = { a0, a1, a2 };
  const ushort* Bseg[3] = { b0, b1, b2 };

  f32x4 acc[4][NFR];
#pragma unroll
  for (int i = 0; i < 4; ++i)
#pragma unroll
    for (int j = 0; j < NFR; ++j) acc[i][j] = { 0.f, 0.f, 0.f, 0.f };

  const int c_row  = tid >> 2;
  const int c_phys = tid & 3;

#define STAGE4(BUF, TT)                                                        \
  {                                                                            \
    const int seg_ = (TT) / KSTEPS;                                            \
    const int k0_  = ((TT) % KSTEPS) * 32;                                     \
    const ushort* ap_ = Aseg[seg_];                                            \
    const ushort* bp_ = Bseg[seg_];                                            \
    _Pragma("unroll")                                                          \
    for (int r_ = 0; r_ < 2; ++r_) {                                           \
      int row_  = c_row + r_ * 64;                                             \
      int slot_ = c_phys ^ ((row_ >> 1) & 3);                                  \
      ASYNC16(ap_ + (row0 + row_) * (size_t)K + (k0_ + slot_ * 8),             \
              &ldsA[BUF][(row_ * 4 + c_phys) * 8]);                            \
    }                                                                          \
    _Pragma("unroll")                                                          \
    for (int r_ = 0; r_ < BR; ++r_) {                                          \
      int row_  = c_row + r_ * 64;                                             \
      int slot_ = c_phys ^ ((row_ >> 1) & 3);                                  \
      ASYNC16(bp_ + (size_t)(n0 + row_) * K + (k0_ + slot_ * 8),               \
              &ldsB[BUF][(row_ * 4 + c_phys) * 8]);                            \
    }                                                                          \
  }

  STAGE4(0, 0);
  STAGE4(1, 1);
#pragma unroll
  for (int t = 0; t < NT; ++t) {
    if (t == NT - 1)              { asm volatile("s_waitcnt vmcnt(0)" ::: "memory"); }
    else if constexpr (BN == 128) { asm volatile("s_waitcnt vmcnt(4)" ::: "memory"); }
    else if constexpr (BN == 192) { asm volatile("s_waitcnt vmcnt(5)" ::: "memory"); }
    else                          { asm volatile("s_waitcnt vmcnt(6)" ::: "memory"); }
    __builtin_amdgcn_s_barrier();
    if (t + 2 < NT) STAGE4((t + 2) % 3, t + 2);
    const int buf = t % 3;
    const int slot = lane >> 4;
    const int r16  = lane & 15;
    bf16x8 af[4], bfr[NFR];
#pragma unroll
    for (int mi = 0; mi < 4; ++mi) {
      int r = wm * 64 + mi * 16 + r16;
      af[mi] = *(const bf16x8*)&ldsA[buf][(r * 4 + (slot ^ ((r >> 1) & 3))) * 8];
    }
#pragma unroll
    for (int ni = 0; ni < NFR; ++ni) {
      int r = wn * WN + ni * 16 + r16;
      bfr[ni] = *(const bf16x8*)&ldsB[buf][(r * 4 + (slot ^ ((r >> 1) & 3))) * 8];
    }
#pragma unroll
    for (int mi = 0; mi < 4; ++mi)
#pragma unroll
      for (int ni = 0; ni < NFR; ++ni)
        acc[mi][ni] = __builtin_amdgcn_mfma_f32_16x16x32_bf16(af[mi], bfr[ni],
                                                              acc[mi][ni], 0, 0, 0);
  }
#undef STAGE4

  const int b0i = (int)(row0 / NTOK);
  const size_t rowB = (size_t)(b0i + 1) * NTOK;
  const bool straddle = (rowB < row0 + 128) && (b0i + 1 < 32);

#pragma unroll
  for (int ni = 0; ni < NFR; ++ni) {
    int n = n0 + wn * WN + ni * 16 + (lane & 15);
    if (n < N) {
      float bv  = bias[n];
      float mk0 = msk[(size_t)b0i * N + n];
      float mk1 = straddle ? msk[(size_t)(b0i + 1) * N + n] : mk0;
#pragma unroll
      for (int mi = 0; mi < 4; ++mi) {
#pragma unroll
        for (int q = 0; q < 4; ++q) {
          size_t m = row0 + (size_t)(wm * 64 + mi * 16 + (lane >> 4) * 4 + q);
          float mv = (m < rowB) ? mk0 : mk1;
          C[m * (size_t)N + n] = (acc[mi][ni][q] + bv) * mv;
        }
      }
    }
  }
}

// ---------------------------------------------------------------------------
extern "C" void kernel_launch(void* const* d_in, const int* in_sizes, int n_in,
                              void* d_out, int out_size, void* d_ws, size_t ws_size,
                              hipStream_t stream)
{
  (void)in_sizes; (void)n_in; (void)out_size; (void)ws_size;
  const float* x = (const float*)d_in[0];
  const float *sg[4], *sb[4], *sW[4], *sbias[4], *pW1[4], *pb1[4], *pW2[4], *pb2[4];
  for (int s = 0; s < 4; ++s) {
    int base = 1 + s * 8;
    sg[s]    = (const float*)d_in[base + 0];
    sb[s]    = (const float*)d_in[base + 1];
    sW[s]    = (const float*)d_in[base + 2];
    sbias[s] = (const float*)d_in[base + 3];
    pW1[s]   = (const float*)d_in[base + 4];
    pb1[s]   = (const float*)d_in[base + 5];
    pW2[s]   = (const float*)d_in[base + 6];
    pb2[s]   = (const float*)d_in[base + 7];
  }

  // x̃ ping-pong buffers. A-side in d_out (dead before gemm4 writes it),
  // B-side in d_ws (live during gemm4).
  float* out = (float*)d_out;
  ushort* hiA = (ushort*)out;                    // x̃1 (M*96) then x̃3 (M*384)
  ushort* loA = (ushort*)(out + 19267584);       // lo1 then lo3
  ushort* loB = (ushort*)(out + 38535168);       // lo2 (M*192)

  char* ws = (char*)d_ws;
  ushort* hiB  = (ushort*)(ws);                  // x̃2 (M*192) then x̃4 (M*384)
  float*  part = (float*) (ws + 77070336);       // max(32*96*224, 32*384*25)*4
  float*  mk   = (float*) (ws + 79822848);       //  98,304
  ushort* w_hi = (ushort*)(ws + 79921152);       // 811,008
  ushort* w_lo = (ushort*)(ws + 80732160);       // 811,008
  float*  st_g = (float*) (ws + 81543168);       //  98,304 -> end 81,641,472

  const int woff[4] = { 0, 12288, 36864, 110592 };

  convW_all_k<<<(405504 + 255) / 256, 256, 0, stream>>>(
      sW[0], sW[1], sW[2], sW[3], w_hi, w_lo);

  const int LNG = 32 * WPB / 4;

  // ---- stage 1: LN1 (standalone), scores1, fused gemm1+LN2
  ln_colsum_k<96, true><<<LNG, 256, 0, stream>>>(x, sg[0], sb[0], hiA, loA, part);
  st_k<96, 96, 1, 192, 224><<<dim3(32, 1), 192, 0, stream>>>(part, sW[0], sbias[0], st_g);
  hscrank_k<96><<<32, 1024, 0, stream>>>(st_g, pW1[0], pb1[0], pW2[0], pb2[0], mk, 86);
  gemm_ln_k<96, 3, 128, 96, 2, true><<<784, 256, 0, stream>>>(
      hiA, hiA, loA, w_hi + woff[0], w_lo + woff[0], w_hi + woff[0],
      sbias[0], mk, sg[1], sb[1], hiB, loB, part);

  // ---- stage 2: scores2, fused gemm2+LN3
  st_k<96, 192, 1, 384, 25><<<dim3(32, 1), 384, 0, stream>>>(part, sW[1], sbias[1], st_g);
  hscrank_k<192><<<32, 1024, 0, stream>>>(st_g, pW1[1], pb1[1], pW2[1], pb2[1], mk, 134);
  gemm_ln_k<96, 3, 192, 192, 2, true><<<784, 256, 0, stream>>>(
      hiB, hiB, loB, w_hi + woff[1], w_lo + woff[1], w_hi + woff[1],
      sbias[1], mk, sg[2], sb[2], hiA, loA, part);

  // ---- stage 3: scores3, fused gemm3+LN4 (512 threads, full N=384)
  st_k<192, 384, 2, 384, 25><<<dim3(32, 2), 384, 0, stream>>>(part, sW[2], sbias[2], st_g);
  hscrank_k<384><<<32, 1024, 0, stream>>>(st_g, pW1[2], pb1[2], pW2[2], pb2[2], mk, 192);
  gemm_ln_k<192, 3, 384, 384, 4, false><<<784, 512, 0, stream>>>(
      hiA, hiA, loA, w_hi + woff[2], w_lo + woff[2], w_hi + woff[2],
      sbias[2], mk, sg[3], sb[3], hiB, (ushort*)nullptr, part);

  // ---- stage 4: scores4, plain bf16 GEMM -> d_out
  st_k<384, 768, 4, 384, 25><<<dim3(32, 4), 384, 0, stream>>>(part, sW[3], sbias[3], st_g);
  hscrank_k<768><<<32, 1024, 0, stream>>>(st_g, pW1[3], pb1[3], pW2[3], pb2[3], mk, 230);
  gemm_mfma_k<384, 1, 256><<<784 * 3, 256, 0, stream>>>(
      hiB, hiB, hiB, w_hi + woff[3], w_hi + woff[3], w_hi + woff[3],
      sbias[3], mk, out, 768);
}

// Round 9
// 550.650 us; speedup vs baseline: 1.0761x; 1.0151x over previous
//
#include <hip/hip_runtime.h>
#include <hip/hip_bf16.h>
#include <stdint.h>

#define NTOK 3136
#define MTOT 100352
#define RPW  14          // rows per LN wave (stage-1 LN only)
#define WPB  224         // LN waves per batch (NTOK/RPW)

typedef __attribute__((ext_vector_type(8))) short bf16x8;
typedef __attribute__((ext_vector_type(4))) float f32x4;
typedef __attribute__((ext_vector_type(2))) float f32x2;

static __device__ __forceinline__ ushort f2bf(float x) {
  union { float f; uint32_t u; } c; c.f = x;
  uint32_t r = (c.u + 0x7FFFu + ((c.u >> 16) & 1u)) >> 16;   // RNE
  return (ushort)r;
}
static __device__ __forceinline__ float bf2f(ushort h) {
  union { uint32_t u; float f; } c; c.u = ((uint32_t)h) << 16;
  return c.f;
}

// ---------------------------------------------------------------------------
// Stage-1 LayerNorm (reads fp32 x) + fp32 column partial sums.
// part layout: [b][c][WPB].
// ---------------------------------------------------------------------------
template<int DIN, bool WLO>
__global__ __launch_bounds__(256)
void ln_colsum_k(const float* __restrict__ in, const float* __restrict__ gma,
                 const float* __restrict__ bta, ushort* __restrict__ oh,
                 ushort* __restrict__ ol, float* __restrict__ part)
{
  constexpr int P2 = DIN / 2;
  constexpr int T2 = (P2 + 63) / 64;
  const int wid  = (blockIdx.x * 256 + threadIdx.x) >> 6;
  const int lane = threadIdx.x & 63;
  const int b = wid / WPB;
  const int w = wid - b * WPB;

  f32x2 gv[T2], bv[T2], acc[T2];
#pragma unroll
  for (int t = 0; t < T2; ++t) {
    int c2 = lane + 64 * t;
    if (c2 < P2) {
      gv[t] = *(const f32x2*)(gma + 2 * c2);
      bv[t] = *(const f32x2*)(bta + 2 * c2);
    } else { gv[t] = {0.f, 0.f}; bv[t] = {0.f, 0.f}; }
    acc[t] = {0.f, 0.f};
  }

  const size_t rbase = ((size_t)b * NTOK + (size_t)w * RPW) * DIN;
  const float* ip = in + rbase;
  ushort* oph = oh + rbase;
  ushort* opl = ol + rbase;

  for (int j = 0; j < RPW; ++j) {
    f32x2 v[T2];
    float s = 0.f, sq = 0.f;
#pragma unroll
    for (int t = 0; t < T2; ++t) {
      int c2 = lane + 64 * t;
      f32x2 xv = {0.f, 0.f};
      if (c2 < P2) xv = *(const f32x2*)(ip + (size_t)j * DIN + 2 * c2);
      v[t] = xv;
      s  += xv[0] + xv[1];
      sq += xv[0] * xv[0] + xv[1] * xv[1];
    }
#pragma unroll
    for (int off = 1; off < 64; off <<= 1) {
      s  += __shfl_xor(s, off);
      sq += __shfl_xor(sq, off);
    }
    float m   = s / (float)DIN;
    float var = sq / (float)DIN - m * m;
    float r   = 1.f / sqrtf(var + 1e-5f);
#pragma unroll
    for (int t = 0; t < T2; ++t) {
      int c2 = lane + 64 * t;
      if (c2 < P2) {
        float xn0 = (v[t][0] - m) * r * gv[t][0] + bv[t][0];
        float xn1 = (v[t][1] - m) * r * gv[t][1] + bv[t][1];
        ushort h0 = f2bf(xn0), h1 = f2bf(xn1);
        ((uint32_t*)(oph + (size_t)j * DIN))[c2] =
            (uint32_t)h0 | ((uint32_t)h1 << 16);
        if (WLO) {
          ushort l0 = f2bf(xn0 - bf2f(h0)), l1 = f2bf(xn1 - bf2f(h1));
          ((uint32_t*)(opl + (size_t)j * DIN))[c2] =
              (uint32_t)l0 | ((uint32_t)l1 << 16);
        }
        acc[t][0] += xn0;
        acc[t][1] += xn1;
      }
    }
  }
#pragma unroll
  for (int t = 0; t < T2; ++t) {
    int c2 = lane + 64 * t;
    if (c2 < P2) {
      int c = 2 * c2;
      part[((size_t)b * DIN + c) * WPB + w]     = acc[t][0];
      part[((size_t)b * DIN + c + 1) * WPB + w] = acc[t][1];
    }
  }
}

// ---------------------------------------------------------------------------
// scores_k: FUSED per-batch score pipeline. One block (1024 thr) per batch:
//   xm (from part) -> st = xm@W+bias -> h = relu(st@W1+b1) -> sc = h@W2+b2
//   -> stable top-k rank -> mask.  All reductions fixed-order fp32.
// SLOTS=224: part [b][c][224] (ln_colsum). SLOTS=25: part [b][c][25] (fused
// GEMM epilogue block sums).
// ---------------------------------------------------------------------------
template<int DIN, int DOUT, int SLOTS>
__global__ __launch_bounds__(1024)
void scores_k(const float* __restrict__ part,
              const float* __restrict__ Wt, const float* __restrict__ bias,
              const float* __restrict__ W1, const float* __restrict__ b1,
              const float* __restrict__ W2, const float* __restrict__ b2,
              float* __restrict__ mask, int k)
{
  constexpr int DH  = DOUT / 4;
  constexpr int DH4 = DH / 4;
  constexpr int NSLC = (1024 / DH4 < 64) ? 1024 / DH4 : 64;
  constexpr int RPSC = (DOUT + NSLC - 1) / NSLC;
  constexpr int C4  = DOUT / 4;
  constexpr int NSLD = (1024 / C4 < 64) ? 1024 / C4 : 64;
  constexpr int RPSD = (DH + NSLD - 1) / NSLD;

  __shared__ float xm[DIN];
  __shared__ float st[DOUT];
  __shared__ float h[DH];
  __shared__ float sc[DOUT];
  __shared__ float red[4096];

  const int b = blockIdx.x, tid = threadIdx.x;

  // phase A: xm
  if constexpr (SLOTS == 25) {
    if (tid < DIN) {
      const float* p = part + ((size_t)b * DIN + tid) * 25;
      float s = 0.f;
#pragma unroll
      for (int i = 0; i < 25; ++i) s += p[i];
      xm[tid] = s * (1.f / (float)NTOK);
    }
  } else {
    const int cg = tid >> 2, wq = tid & 3;
    if (cg < DIN) {
      const float* p = part + ((size_t)b * DIN + cg) * WPB + wq * 56;
      f32x4 a = {0.f, 0.f, 0.f, 0.f};
#pragma unroll
      for (int u = 0; u < 14; ++u) {
        f32x4 t0 = *(const f32x4*)(p + u * 4);
        a[0] += t0[0]; a[1] += t0[1]; a[2] += t0[2]; a[3] += t0[3];
      }
      red[wq * DIN + cg] = (a[0] + a[1]) + (a[2] + a[3]);
    }
    __syncthreads();
    if (tid < DIN)
      xm[tid] = ((red[0 * DIN + tid] + red[1 * DIN + tid]) +
                 (red[2 * DIN + tid] + red[3 * DIN + tid])) * (1.f / (float)NTOK);
  }
  __syncthreads();

  // phase B: st = xm @ W + bias (4 reduction slices)
  {
    constexpr int RPS = DIN / 4;
    const int j4 = tid % C4, sl = tid / C4;
    if (sl < 4) {
      const float* wp = Wt + (size_t)(sl * RPS) * DOUT + j4 * 4;
      f32x4 acc = {0.f, 0.f, 0.f, 0.f};
#pragma unroll
      for (int r = 0; r < RPS; ++r) {
        f32x4 wv = *(const f32x4*)(wp + (size_t)r * DOUT);
        float xv = xm[sl * RPS + r];
        acc[0] = fmaf(xv, wv[0], acc[0]);
        acc[1] = fmaf(xv, wv[1], acc[1]);
        acc[2] = fmaf(xv, wv[2], acc[2]);
        acc[3] = fmaf(xv, wv[3], acc[3]);
      }
      *(f32x4*)&red[sl * DOUT + j4 * 4] = acc;
    }
  }
  __syncthreads();
  if (tid < DOUT)
    st[tid] = ((red[0 * DOUT + tid] + red[1 * DOUT + tid]) +
               (red[2 * DOUT + tid] + red[3 * DOUT + tid])) + bias[tid];
  __syncthreads();

  // phase C: h = relu(st @ W1 + b1)
  {
    const int j4 = tid % DH4, sl = tid / DH4;
    if (sl < NSLC) {
      f32x4 acc = {0.f, 0.f, 0.f, 0.f};
#pragma unroll
      for (int rr = 0; rr < RPSC; ++rr) {
        int r = sl * RPSC + rr;
        if (r < DOUT) {
          f32x4 wv = *(const f32x4*)(W1 + (size_t)r * DH + j4 * 4);
          float sv = st[r];
          acc[0] = fmaf(sv, wv[0], acc[0]);
          acc[1] = fmaf(sv, wv[1], acc[1]);
          acc[2] = fmaf(sv, wv[2], acc[2]);
          acc[3] = fmaf(sv, wv[3], acc[3]);
        }
      }
      *(f32x4*)&red[(size_t)sl * DH + j4 * 4] = acc;
    }
  }
  __syncthreads();
  if (tid < DH) {
    float a = 0.f;
#pragma unroll 4
    for (int sl = 0; sl < NSLC; ++sl) a += red[(size_t)sl * DH + tid];
    h[tid] = fmaxf(b1[tid] + a, 0.f);
  }
  __syncthreads();

  // phase D: sc = h @ W2 + b2
  {
    const int c4 = tid % C4, sl = tid / C4;
    if (sl < NSLD) {
      f32x4 acc = {0.f, 0.f, 0.f, 0.f};
#pragma unroll
      for (int rr = 0; rr < RPSD; ++rr) {
        int r = sl * RPSD + rr;
        if (r < DH) {
          f32x4 wv = *(const f32x4*)(W2 + (size_t)r * DOUT + c4 * 4);
          float hv = h[r];
          acc[0] = fmaf(hv, wv[0], acc[0]);
          acc[1] = fmaf(hv, wv[1], acc[1]);
          acc[2] = fmaf(hv, wv[2], acc[2]);
          acc[3] = fmaf(hv, wv[3], acc[3]);
        }
      }
      *(f32x4*)&red[(size_t)sl * DOUT + c4 * 4] = acc;
    }
  }
  __syncthreads();
  for (int c = tid; c < DOUT; c += 1024) {
    float a = 0.f;
#pragma unroll 4
    for (int sl = 0; sl < NSLD; ++sl) a += red[(size_t)sl * DOUT + c];
    sc[c] = b2[c] + a;
  }
  __syncthreads();

  // phase E: stable rank -> mask
  for (int c = tid; c < DOUT; c += 1024) {
    float v = sc[c];
    int rank = 0;
#pragma unroll 8
    for (int j = 0; j < DOUT; ++j) {
      float u = sc[j];
      rank += (u > v) || (u == v && j < c);
    }
    mask[(size_t)b * DOUT + c] = (rank < k) ? 1.f : 0.f;
  }
}

// ---------------------------------------------------------------------------
// All 4 stages' W [K][N] fp32 -> hi/lo bf16 [Npad][K].
// ---------------------------------------------------------------------------
__global__ __launch_bounds__(256)
void convW_all_k(const float* __restrict__ W0, const float* __restrict__ W1,
                 const float* __restrict__ W2, const float* __restrict__ W3,
                 ushort* __restrict__ hi, ushort* __restrict__ lo)
{
  const int Kd[4]   = { 96, 96, 192, 384 };
  const int Nd[4]   = { 96, 192, 384, 768 };
  const int off[5]  = { 0, 12288, 36864, 110592, 405504 };
  const float* Wp[4] = { W0, W1, W2, W3 };

  int idx = blockIdx.x * 256 + threadIdx.x;
  if (idx >= 405504) return;
  int s = (idx >= off[1]) + (idx >= off[2]) + (idx >= off[3]);
  int local = idx - off[s];
  int K = Kd[s], N = Nd[s];
  int n = local / K, kk = local - n * K;
  float v = (n < N) ? Wp[s][(size_t)kk * N + n] : 0.f;
  ushort h = f2bf(v);
  hi[idx] = h;
  lo[idx] = f2bf(v - bf2f(h));
}

#define ASYNC16(GP, LP) __builtin_amdgcn_global_load_lds( \
    (const __attribute__((address_space(1))) void*)(GP),  \
    (__attribute__((address_space(3))) void*)(LP), 16, 0, 0)

// ---------------------------------------------------------------------------
// FUSED GEMM + bias + mask + LayerNorm-for-next-stage + colsum epilogue.
// Block = 128 rows x ALL N cols. Triple-buffered counted-vmcnt K-loop.
// Epilogue: row stats via shuffles + cross-wave LDS; then per-16-row chunk
// normalize -> LDS staging (ldsB, dead after K-loop) -> COALESCED uint4
// stores of bf16 x̃; per-block column sums -> part[b][c][25].
// ---------------------------------------------------------------------------
template<int K, int NSEG, int BNL, int N, int NWN, bool WLO>
__global__ __launch_bounds__(128 * NWN)
void gemm_ln_k(const ushort* __restrict__ a0, const ushort* __restrict__ a1,
               const ushort* __restrict__ a2,
               const ushort* __restrict__ b0, const ushort* __restrict__ b1,
               const ushort* __restrict__ b2,
               const float* __restrict__ bias, const float* __restrict__ msk,
               const float* __restrict__ gnext, const float* __restrict__ bnext,
               ushort* __restrict__ oh, ushort* __restrict__ ol,
               float* __restrict__ part)
{
  constexpr int T   = 128 * NWN;
  constexpr int R   = T / 4;        // rows per staging issue
  constexpr int AI  = 128 / R;
  constexpr int BI  = BNL / R;
  constexpr int IS  = AI + BI;
  constexpr int WN  = N / NWN;
  constexpr int NFR = WN / 16;
  constexpr int KSTEPS = K / 32;
  constexpr int NT  = NSEG * KSTEPS;
  __shared__ __align__(16) ushort ldsA[3][128 * 32];
  __shared__ __align__(16) ushort ldsB[3][BNL * 32];

  const int tid  = threadIdx.x;
  const int lane = tid & 63;
  const int wid  = tid >> 6;
  const int wm = wid & 1, wn = wid >> 1;

  const int q8  = gridDim.x >> 3;
  const int bid = blockIdx.x;
  const int mt  = (bid & 7) * q8 + (bid >> 3);
  const size_t row0 = (size_t)mt * 128;

  const ushort* Aseg[3] = { a0, a1, a2 };
  const ushort* Bseg[3] = { b0, b1, b2 };

  f32x4 acc[4][NFR];
#pragma unroll
  for (int i = 0; i < 4; ++i)
#pragma unroll
    for (int j = 0; j < NFR; ++j) acc[i][j] = { 0.f, 0.f, 0.f, 0.f };

  const int c_row  = tid >> 2;
  const int c_phys = tid & 3;

#define STAGEF(BUF, TT)                                                        \
  {                                                                            \
    const int seg_ = (TT) / KSTEPS;                                            \
    const int k0_  = ((TT) % KSTEPS) * 32;                                     \
    const ushort* ap_ = Aseg[seg_];                                            \
    const ushort* bp_ = Bseg[seg_];                                            \
    _Pragma("unroll")                                                          \
    for (int r_ = 0; r_ < AI; ++r_) {                                          \
      int row_  = c_row + r_ * R;                                              \
      int slot_ = c_phys ^ ((row_ >> 1) & 3);                                  \
      ASYNC16(ap_ + (row0 + row_) * (size_t)K + (k0_ + slot_ * 8),             \
              &ldsA[BUF][(row_ * 4 + c_phys) * 8]);                            \
    }                                                                          \
    _Pragma("unroll")                                                          \
    for (int r_ = 0; r_ < BI; ++r_) {                                          \
      int row_  = c_row + r_ * R;                                              \
      int slot_ = c_phys ^ ((row_ >> 1) & 3);                                  \
      ASYNC16(bp_ + (size_t)row_ * K + (k0_ + slot_ * 8),                      \
              &ldsB[BUF][(row_ * 4 + c_phys) * 8]);                            \
    }                                                                          \
  }

  STAGEF(0, 0);
  STAGEF(1, 1);
#pragma unroll
  for (int t = 0; t < NT; ++t) {
    if (t == NT - 1)            { asm volatile("s_waitcnt vmcnt(0)" ::: "memory"); }
    else if constexpr (IS == 4) { asm volatile("s_waitcnt vmcnt(4)" ::: "memory"); }
    else                        { asm volatile("s_waitcnt vmcnt(5)" ::: "memory"); }
    __builtin_amdgcn_s_barrier();
    if (t + 2 < NT) STAGEF((t + 2) % 3, t + 2);
    const int buf = t % 3;
    const int slot = lane >> 4;
    const int r16  = lane & 15;
    bf16x8 af[4], bfr[NFR];
#pragma unroll
    for (int mi = 0; mi < 4; ++mi) {
      int r = wm * 64 + mi * 16 + r16;
      af[mi] = *(const bf16x8*)&ldsA[buf][(r * 4 + (slot ^ ((r >> 1) & 3))) * 8];
    }
#pragma unroll
    for (int ni = 0; ni < NFR; ++ni) {
      int r = wn * WN + ni * 16 + r16;
      bfr[ni] = *(const bf16x8*)&ldsB[buf][(r * 4 + (slot ^ ((r >> 1) & 3))) * 8];
    }
#pragma unroll
    for (int mi = 0; mi < 4; ++mi)
#pragma unroll
      for (int ni = 0; ni < NFR; ++ni)
        acc[mi][ni] = __builtin_amdgcn_mfma_f32_16x16x32_bf16(af[mi], bfr[ni],
                                                              acc[mi][ni], 0, 0, 0);
  }
#undef STAGEF

  // ---------------- fused epilogue ----------------
  __syncthreads();                       // all LDS reads done

  float* rowred = (float*)&ldsA[0][0];   // [NWN][128][2]
  float* colred = rowred + NWN * 256;    // [2 sets][2 wm][N]
  ushort* xsh = (ushort*)&ldsB[0][0];    // [32][N] hi staging
  ushort* xsl = xsh + 32 * N;            // [32][N] lo staging (WLO)

  const int l15 = lane & 15, l4 = lane >> 4;
  const int b0i = (int)(row0 / NTOK);
  const size_t rowB = (size_t)(b0i + 1) * NTOK;
  const bool strad = rowB < row0 + 128;

  float biasv[NFR], mk0a[NFR], mk1a[NFR], gvn[NFR], bvn[NFR];
#pragma unroll
  for (int ni = 0; ni < NFR; ++ni) {
    int n = wn * WN + ni * 16 + l15;
    biasv[ni] = bias[n];
    mk0a[ni] = msk[(size_t)b0i * N + n];
    mk1a[ni] = strad ? msk[(size_t)(b0i + 1) * N + n] : mk0a[ni];
    gvn[ni] = gnext[n];
    bvn[ni] = bnext[n];
  }

  // v = (acc+bias)*mask, row partial sums
  float rs[16], rq[16];
#pragma unroll
  for (int i = 0; i < 16; ++i) { rs[i] = 0.f; rq[i] = 0.f; }
#pragma unroll
  for (int mi = 0; mi < 4; ++mi)
#pragma unroll
    for (int q = 0; q < 4; ++q) {
      size_t row = row0 + wm * 64 + mi * 16 + l4 * 4 + q;
      bool loB = row < rowB;
#pragma unroll
      for (int ni = 0; ni < NFR; ++ni) {
        float v = (acc[mi][ni][q] + biasv[ni]) * (loB ? mk0a[ni] : mk1a[ni]);
        acc[mi][ni][q] = v;
        rs[mi * 4 + q] += v;
        rq[mi * 4 + q] += v * v;
      }
    }
#pragma unroll
  for (int off = 1; off < 16; off <<= 1)
#pragma unroll
    for (int i = 0; i < 16; ++i) {
      rs[i] += __shfl_xor(rs[i], off);
      rq[i] += __shfl_xor(rq[i], off);
    }
  if (l15 == 0) {
#pragma unroll
    for (int mi = 0; mi < 4; ++mi)
#pragma unroll
      for (int q = 0; q < 4; ++q) {
        int r = wm * 64 + mi * 16 + l4 * 4 + q;
        rowred[(wn * 128 + r) * 2 + 0] = rs[mi * 4 + q];
        rowred[(wn * 128 + r) * 2 + 1] = rq[mi * 4 + q];
      }
  }
  __syncthreads();

  float mean[16], rstd[16];
#pragma unroll
  for (int mi = 0; mi < 4; ++mi)
#pragma unroll
    for (int q = 0; q < 4; ++q) {
      int r = wm * 64 + mi * 16 + l4 * 4 + q;
      float S = 0.f, Q = 0.f;
#pragma unroll
      for (int w = 0; w < NWN; ++w) {
        S += rowred[(w * 128 + r) * 2 + 0];
        Q += rowred[(w * 128 + r) * 2 + 1];
      }
      float mn  = S / (float)N;
      float var = Q / (float)N - mn * mn;
      mean[mi * 4 + q] = mn;
      rstd[mi * 4 + q] = 1.f / sqrtf(var + 1e-5f);
    }

  // per-16-row chunk: normalize -> LDS staging -> coalesced uint4 stores
  float cs0[NFR], cs1[NFR];
#pragma unroll
  for (int ni = 0; ni < NFR; ++ni) { cs0[ni] = 0.f; cs1[ni] = 0.f; }
#pragma unroll
  for (int mi = 0; mi < 4; ++mi) {
    __syncthreads();                     // previous chunk's staging reads done
#pragma unroll
    for (int q = 0; q < 4; ++q) {
      const int rl = l4 * 4 + q;
      const size_t row = row0 + wm * 64 + mi * 16 + rl;
      const bool loB = row < rowB;
      const float mn = mean[mi * 4 + q], rv = rstd[mi * 4 + q];
#pragma unroll
      for (int ni = 0; ni < NFR; ++ni) {
        const int n = wn * WN + ni * 16 + l15;
        float xn = (acc[mi][ni][q] - mn) * rv * gvn[ni] + bvn[ni];
        ushort hh = f2bf(xn);
        xsh[(wm * 16 + rl) * N + n] = hh;
        if constexpr (WLO) xsl[(wm * 16 + rl) * N + n] = f2bf(xn - bf2f(hh));
        if (loB) cs0[ni] += xn; else cs1[ni] += xn;
      }
    }
    __syncthreads();
    constexpr int U4R = N / 8;           // uint4 per row
    for (int idx = tid; idx < 32 * U4R; idx += T) {
      const int grp = idx / U4R, c = idx - grp * U4R;
      const size_t row = row0 + (grp >> 4) * 64 + mi * 16 + (grp & 15);
      *(uint4*)(oh + row * (size_t)N + c * 8) =
          *(const uint4*)(xsh + grp * N + c * 8);
      if constexpr (WLO)
        *(uint4*)(ol + row * (size_t)N + c * 8) =
            *(const uint4*)(xsl + grp * N + c * 8);
    }
  }

  // column sums -> part[b][c][25]
#pragma unroll
  for (int ni = 0; ni < NFR; ++ni) {
    cs0[ni] += __shfl_xor(cs0[ni], 16);
    cs0[ni] += __shfl_xor(cs0[ni], 32);
    cs1[ni] += __shfl_xor(cs1[ni], 16);
    cs1[ni] += __shfl_xor(cs1[ni], 32);
  }
  __syncthreads();                       // staging reads done; colred safe
  if (l4 == 0) {
#pragma unroll
    for (int ni = 0; ni < NFR; ++ni) {
      int n = wn * WN + ni * 16 + l15;
      colred[(0 * 2 + wm) * N + n] = cs0[ni];
      colred[(1 * 2 + wm) * N + n] = cs1[ni];
    }
  }
  __syncthreads();
  if (wm == 0 && l4 == 0) {
    const int mt_lo = (b0i * NTOK) >> 7;
    const int slot0 = mt - mt_lo;
#pragma unroll
    for (int ni = 0; ni < NFR; ++ni) {
      int n = wn * WN + ni * 16 + l15;
      float t0 = colred[0 * N + n] + colred[1 * N + n];
      part[((size_t)b0i * N + n) * 25 + slot0] = t0;
      if (strad) {
        float t1 = colred[2 * N + n] + colred[3 * N + n];
        part[((size_t)(b0i + 1) * N + n) * 25 + 0] = t1;
      }
    }
  }
}

// ---------------------------------------------------------------------------
// Stage-4 GEMM: 128x256 tile, triple-buffer counted vmcnt, LDS-staged
// coalesced float4 C-write.
// ---------------------------------------------------------------------------
template<int K, int NSEG, int BN>
__global__ __launch_bounds__(256)
void gemm_mfma_k(const ushort* __restrict__ a0, const ushort* __restrict__ a1,
                 const ushort* __restrict__ a2,
                 const ushort* __restrict__ b0, const ushort* __restrict__ b1,
                 const ushort* __restrict__ b2,
                 const float* __restrict__ bias, const float* __restrict__ msk,
                 float* __restrict__ C, int N)
{
  constexpr int KSTEPS = K / 32;
  constexpr int NT  = NSEG * KSTEPS;
  constexpr int WN  = BN / 2;
  constexpr int NFR = WN / 16;
  constexpr int BR  = BN / 64;
  __shared__ __align__(16) ushort ldsA[3][128 * 32];
  __shared__ __align__(16) ushort ldsB[3][BN * 32];

  const int tid  = threadIdx.x;
  const int lane = tid & 63;
  const int wid  = tid >> 6;
  const int wm = wid >> 1, wn = wid & 1;

  const int NBN = (N + BN - 1) / BN;
  const int q8  = gridDim.x >> 3;
  const int bid = blockIdx.x;
  const int wg  = (bid & 7) * q8 + (bid >> 3);
  const int mt  = wg / NBN;
  const int nt  = wg - mt * NBN;
  const size_t row0 = (size_t)mt * 128;
  const int n0 = nt * BN;

  const ushort* Aseg[3] = { a0, a1, a2 };
  const ushort* Bseg[3] = { b0, b1, b2 };

  f32x4 acc[4][NFR];
#pragma unroll
  for (int i = 0; i < 4; ++i)
#pragma unroll
    for (int j = 0; j < NFR; ++j) acc[i][j] = { 0.f, 0.f, 0.f, 0.f };

  const int c_row  = tid >> 2;
  const int c_phys = tid & 3;

#define STAGE4(BUF, TT)                                                        \
  {                                                                            \
    const int seg_ = (TT) / KSTEPS;                                            \
    const int k0_  = ((TT) % KSTEPS) * 32;                                     \
    const ushort* ap_ = Aseg[seg_];                                            \
    const ushort* bp_ = Bseg[seg_];                                            \
    _Pragma("unroll")                                                          \
    for (int r_ = 0; r_ < 2; ++r_) {                                           \
      int row_  = c_row + r_ * 64;                                             \
      int slot_ = c_phys ^ ((row_ >> 1) & 3);                                  \
      ASYNC16(ap_ + (row0 + row_) * (size_t)K + (k0_ + slot_ * 8),             \
              &ldsA[BUF][(row_ * 4 + c_phys) * 8]);                            \
    }                                                                          \
    _Pragma("unroll")                                                          \
    for (int r_ = 0; r_ < BR; ++r_) {                                          \
      int row_  = c_row + r_ * 64;                                             \
      int slot_ = c_phys ^ ((row_ >> 1) & 3);                                  \
      ASYNC16(bp_ + (size_t)(n0 + row_) * K + (k0_ + slot_ * 8),               \
              &ldsB[BUF][(row_ * 4 + c_phys) * 8]);                            \
    }                                                                          \
  }

  STAGE4(0, 0);
  STAGE4(1, 1);
#pragma unroll
  for (int t = 0; t < NT; ++t) {
    if (t == NT - 1)              { asm volatile("s_waitcnt vmcnt(0)" ::: "memory"); }
    else if constexpr (BN == 128) { asm volatile("s_waitcnt vmcnt(4)" ::: "memory"); }
    else if constexpr (BN == 192) { asm volatile("s_waitcnt vmcnt(5)" ::: "memory"); }
    else                          { asm volatile("s_waitcnt vmcnt(6)" ::: "memory"); }
    __builtin_amdgcn_s_barrier();
    if (t + 2 < NT) STAGE4((t + 2) % 3, t + 2);
    const int buf = t % 3;
    const int slot = lane >> 4;
    const int r16  = lane & 15;
    bf16x8 af[4], bfr[NFR];
#pragma unroll
    for (int mi = 0; mi < 4; ++mi) {
      int r = wm * 64 + mi * 16 + r16;
      af[mi] = *(const bf16x8*)&ldsA[buf][(r * 4 + (slot ^ ((r >> 1) & 3))) * 8];
    }
#pragma unroll
    for (int ni = 0; ni < NFR; ++ni) {
      int r = wn * WN + ni * 16 + r16;
      bfr[ni] = *(const bf16x8*)&ldsB[buf][(r * 4 + (slot ^ ((r >> 1) & 3))) * 8];
    }
#pragma unroll
    for (int mi = 0; mi < 4; ++mi)
#pragma unroll
      for (int ni = 0; ni < NFR; ++ni)
        acc[mi][ni] = __builtin_amdgcn_mfma_f32_16x16x32_bf16(af[mi], bfr[ni],
                                                              acc[mi][ni], 0, 0, 0);
  }
#undef STAGE4

  // LDS-staged coalesced epilogue
  float* cst = (float*)&ldsB[0][0];      // [32][BN] fp32 chunk (32 KB)

  const int l15 = lane & 15, l4 = lane >> 4;
  const int b0i = (int)(row0 / NTOK);
  const size_t rowB = (size_t)(b0i + 1) * NTOK;
  const bool straddle = (rowB < row0 + 128) && (b0i + 1 < 32);

  float biasv[NFR], mk0a[NFR], mk1a[NFR];
#pragma unroll
  for (int ni = 0; ni < NFR; ++ni) {
    int n = n0 + wn * WN + ni * 16 + l15;
    biasv[ni] = bias[n];
    mk0a[ni] = msk[(size_t)b0i * N + n];
    mk1a[ni] = straddle ? msk[(size_t)(b0i + 1) * N + n] : mk0a[ni];
  }

#pragma unroll
  for (int mi = 0; mi < 4; ++mi) {
    __syncthreads();                     // K-loop reads / prior chunk reads done
#pragma unroll
    for (int q = 0; q < 4; ++q) {
      const int rl = l4 * 4 + q;
      const size_t m = row0 + wm * 64 + mi * 16 + rl;
      const bool loB = m < rowB;
#pragma unroll
      for (int ni = 0; ni < NFR; ++ni) {
        const int nn = wn * WN + ni * 16 + l15;
        cst[(wm * 16 + rl) * BN + nn] =
            (acc[mi][ni][q] + biasv[ni]) * (loB ? mk0a[ni] : mk1a[ni]);
      }
    }
    __syncthreads();
    constexpr int F4R = BN / 4;          // float4 per row
    for (int idx = tid; idx < 32 * F4R; idx += 256) {
      const int grp = idx / F4R, c = idx - grp * F4R;
      const size_t row = row0 + (grp >> 4) * 64 + mi * 16 + (grp & 15);
      *(f32x4*)(C + row * (size_t)N + n0 + c * 4) =
          *(const f32x4*)(cst + grp * BN + c * 4);
    }
  }
}

// ---------------------------------------------------------------------------
extern "C" void kernel_launch(void* const* d_in, const int* in_sizes, int n_in,
                              void* d_out, int out_size, void* d_ws, size_t ws_size,
                              hipStream_t stream)
{
  (void)in_sizes; (void)n_in; (void)out_size; (void)ws_size;
  const float* x = (const float*)d_in[0];
  const float *sg[4], *sb[4], *sW[4], *sbias[4], *pW1[4], *pb1[4], *pW2[4], *pb2[4];
  for (int s = 0; s < 4; ++s) {
    int base = 1 + s * 8;
    sg[s]    = (const float*)d_in[base + 0];
    sb[s]    = (const float*)d_in[base + 1];
    sW[s]    = (const float*)d_in[base + 2];
    sbias[s] = (const float*)d_in[base + 3];
    pW1[s]   = (const float*)d_in[base + 4];
    pb1[s]   = (const float*)d_in[base + 5];
    pW2[s]   = (const float*)d_in[base + 6];
    pb2[s]   = (const float*)d_in[base + 7];
  }

  // x̃ ping-pong buffers. A-side in d_out (dead before gemm4 writes it),
  // B-side in d_ws (live during gemm4).
  float* out = (float*)d_out;
  ushort* hiA = (ushort*)out;                    // x̃1 (M*96) then x̃3 (M*384)
  ushort* loA = (ushort*)(out + 19267584);       // lo1 then lo3
  ushort* loB = (ushort*)(out + 38535168);       // lo2 (M*192)

  char* ws = (char*)d_ws;
  ushort* hiB  = (ushort*)(ws);                  // x̃2 (M*192) then x̃4 (M*384)
  float*  part = (float*) (ws + 77070336);       // max(32*96*224, 32*384*25)*4
  float*  mk   = (float*) (ws + 79822848);       //  98,304
  ushort* w_hi = (ushort*)(ws + 79921152);       // 811,008
  ushort* w_lo = (ushort*)(ws + 80732160);       // 811,008 -> end 81,543,168

  const int woff[4] = { 0, 12288, 36864, 110592 };

  convW_all_k<<<(405504 + 255) / 256, 256, 0, stream>>>(
      sW[0], sW[1], sW[2], sW[3], w_hi, w_lo);

  const int LNG = 32 * WPB / 4;

  // ---- stage 1: LN1 (standalone), scores1, fused gemm1+LN2
  ln_colsum_k<96, true><<<LNG, 256, 0, stream>>>(x, sg[0], sb[0], hiA, loA, part);
  scores_k<96, 96, 224><<<32, 1024, 0, stream>>>(part, sW[0], sbias[0],
      pW1[0], pb1[0], pW2[0], pb2[0], mk, 86);
  gemm_ln_k<96, 3, 128, 96, 2, true><<<784, 256, 0, stream>>>(
      hiA, hiA, loA, w_hi + woff[0], w_lo + woff[0], w_hi + woff[0],
      sbias[0], mk, sg[1], sb[1], hiB, loB, part);

  // ---- stage 2: scores2, fused gemm2+LN3
  scores_k<96, 192, 25><<<32, 1024, 0, stream>>>(part, sW[1], sbias[1],
      pW1[1], pb1[1], pW2[1], pb2[1], mk, 134);
  gemm_ln_k<96, 3, 192, 192, 2, true><<<784, 256, 0, stream>>>(
      hiB, hiB, loB, w_hi + woff[1], w_lo + woff[1], w_hi + woff[1],
      sbias[1], mk, sg[2], sb[2], hiA, loA, part);

  // ---- stage 3: scores3, fused gemm3+LN4 (512 threads, full N=384)
  scores_k<192, 384, 25><<<32, 1024, 0, stream>>>(part, sW[2], sbias[2],
      pW1[2], pb1[2], pW2[2], pb2[2], mk, 192);
  gemm_ln_k<192, 3, 384, 384, 4, false><<<784, 512, 0, stream>>>(
      hiA, hiA, loA, w_hi + woff[2], w_lo + woff[2], w_hi + woff[2],
      sbias[2], mk, sg[3], sb[3], hiB, (ushort*)nullptr, part);

  // ---- stage 4: scores4, plain bf16 GEMM -> d_out (coalesced epilogue)
  scores_k<384, 768, 25><<<32, 1024, 0, stream>>>(part, sW[3], sbias[3],
      pW1[3], pb1[3], pW2[3], pb2[3], mk, 230);
  gemm_mfma_k<384, 1, 256><<<784 * 3, 256, 0, stream>>>(
      hiB, hiB, hiB, w_hi + woff[3], w_hi + woff[3], w_hi + woff[3],
      sbias[3], mk, out, 768);
}

// Round 13
// 490.348 us; speedup vs baseline: 1.2084x; 1.1230x over previous
//
#include <hip/hip_runtime.h>
#include <hip/hip_bf16.h>
#include <stdint.h>

#define NTOK 3136
#define MTOT 100352
#define RPW  14          // rows per LN wave (stage-1 LN only)
#define WPB  224         // LN waves per batch (NTOK/RPW)

typedef __attribute__((ext_vector_type(8))) short bf16x8;
typedef __attribute__((ext_vector_type(4))) float f32x4;
typedef __attribute__((ext_vector_type(2))) float f32x2;

static __device__ __forceinline__ ushort f2bf(float x) {
  union { float f; uint32_t u; } c; c.f = x;
  uint32_t r = (c.u + 0x7FFFu + ((c.u >> 16) & 1u)) >> 16;   // RNE
  return (ushort)r;
}
static __device__ __forceinline__ float bf2f(ushort h) {
  union { uint32_t u; float f; } c; c.u = ((uint32_t)h) << 16;
  return c.f;
}

// ---------------------------------------------------------------------------
// Stage-1 LayerNorm (reads fp32 x) + fp32 column partial sums.
// part layout: [b][c][WPB].
// ---------------------------------------------------------------------------
template<int DIN, bool WLO>
__global__ __launch_bounds__(256)
void ln_colsum_k(const float* __restrict__ in, const float* __restrict__ gma,
                 const float* __restrict__ bta, ushort* __restrict__ oh,
                 ushort* __restrict__ ol, float* __restrict__ part)
{
  constexpr int P2 = DIN / 2;
  constexpr int T2 = (P2 + 63) / 64;
  const int wid  = (blockIdx.x * 256 + threadIdx.x) >> 6;
  const int lane = threadIdx.x & 63;
  const int b = wid / WPB;
  const int w = wid - b * WPB;

  f32x2 gv[T2], bv[T2], acc[T2];
#pragma unroll
  for (int t = 0; t < T2; ++t) {
    int c2 = lane + 64 * t;
    if (c2 < P2) {
      gv[t] = *(const f32x2*)(gma + 2 * c2);
      bv[t] = *(const f32x2*)(bta + 2 * c2);
    } else { gv[t] = {0.f, 0.f}; bv[t] = {0.f, 0.f}; }
    acc[t] = {0.f, 0.f};
  }

  const size_t rbase = ((size_t)b * NTOK + (size_t)w * RPW) * DIN;
  const float* ip = in + rbase;
  ushort* oph = oh + rbase;
  ushort* opl = ol + rbase;

  for (int j = 0; j < RPW; ++j) {
    f32x2 v[T2];
    float s = 0.f, sq = 0.f;
#pragma unroll
    for (int t = 0; t < T2; ++t) {
      int c2 = lane + 64 * t;
      f32x2 xv = {0.f, 0.f};
      if (c2 < P2) xv = *(const f32x2*)(ip + (size_t)j * DIN + 2 * c2);
      v[t] = xv;
      s  += xv[0] + xv[1];
      sq += xv[0] * xv[0] + xv[1] * xv[1];
    }
#pragma unroll
    for (int off = 1; off < 64; off <<= 1) {
      s  += __shfl_xor(s, off);
      sq += __shfl_xor(sq, off);
    }
    float m   = s / (float)DIN;
    float var = sq / (float)DIN - m * m;
    float r   = 1.f / sqrtf(var + 1e-5f);
#pragma unroll
    for (int t = 0; t < T2; ++t) {
      int c2 = lane + 64 * t;
      if (c2 < P2) {
        float xn0 = (v[t][0] - m) * r * gv[t][0] + bv[t][0];
        float xn1 = (v[t][1] - m) * r * gv[t][1] + bv[t][1];
        ushort h0 = f2bf(xn0), h1 = f2bf(xn1);
        ((uint32_t*)(oph + (size_t)j * DIN))[c2] =
            (uint32_t)h0 | ((uint32_t)h1 << 16);
        if (WLO) {
          ushort l0 = f2bf(xn0 - bf2f(h0)), l1 = f2bf(xn1 - bf2f(h1));
          ((uint32_t*)(opl + (size_t)j * DIN))[c2] =
              (uint32_t)l0 | ((uint32_t)l1 << 16);
        }
        acc[t][0] += xn0;
        acc[t][1] += xn1;
      }
    }
  }
#pragma unroll
  for (int t = 0; t < T2; ++t) {
    int c2 = lane + 64 * t;
    if (c2 < P2) {
      int c = 2 * c2;
      part[((size_t)b * DIN + c) * WPB + w]     = acc[t][0];
      part[((size_t)b * DIN + c + 1) * WPB + w] = acc[t][1];
    }
  }
}

// ---------------------------------------------------------------------------
// scores_k: FUSED per-batch score pipeline. When CMP, also emits per-batch
// compacted column list (ranks unique -> deterministic), compacted bias, and
// gathered compacted weight Wc[b][256][384] for stage 4.
// ---------------------------------------------------------------------------
template<int DIN, int DOUT, int SLOTS, bool CMP>
__global__ __launch_bounds__(1024)
void scores_k(const float* __restrict__ part,
              const float* __restrict__ Wt, const float* __restrict__ bias,
              const float* __restrict__ W1, const float* __restrict__ b1,
              const float* __restrict__ W2, const float* __restrict__ b2,
              float* __restrict__ mask, int k,
              const ushort* __restrict__ wsrc, ushort* __restrict__ wc,
              int* __restrict__ list_g, float* __restrict__ biasc)
{
  constexpr int DH  = DOUT / 4;
  constexpr int DH4 = DH / 4;
  constexpr int NSLC = (1024 / DH4 < 64) ? 1024 / DH4 : 64;
  constexpr int RPSC = (DOUT + NSLC - 1) / NSLC;
  constexpr int C4  = DOUT / 4;
  constexpr int NSLD = (1024 / C4 < 64) ? 1024 / C4 : 64;
  constexpr int RPSD = (DH + NSLD - 1) / NSLD;

  __shared__ float xm[DIN];
  __shared__ float st[DOUT];
  __shared__ float h[DH];
  __shared__ float sc[DOUT];
  __shared__ float red[4096];
  __shared__ int lsh[256];

  const int b = blockIdx.x, tid = threadIdx.x;

  if constexpr (SLOTS == 25) {
    if (tid < DIN) {
      const float* p = part + ((size_t)b * DIN + tid) * 25;
      float s = 0.f;
#pragma unroll
      for (int i = 0; i < 25; ++i) s += p[i];
      xm[tid] = s * (1.f / (float)NTOK);
    }
  } else {
    const int cg = tid >> 2, wq = tid & 3;
    if (cg < DIN) {
      const float* p = part + ((size_t)b * DIN + cg) * WPB + wq * 56;
      f32x4 a = {0.f, 0.f, 0.f, 0.f};
#pragma unroll
      for (int u = 0; u < 14; ++u) {
        f32x4 t0 = *(const f32x4*)(p + u * 4);
        a[0] += t0[0]; a[1] += t0[1]; a[2] += t0[2]; a[3] += t0[3];
      }
      red[wq * DIN + cg] = (a[0] + a[1]) + (a[2] + a[3]);
    }
    __syncthreads();
    if (tid < DIN)
      xm[tid] = ((red[0 * DIN + tid] + red[1 * DIN + tid]) +
                 (red[2 * DIN + tid] + red[3 * DIN + tid])) * (1.f / (float)NTOK);
  }
  __syncthreads();

  {
    constexpr int RPS = DIN / 4;
    const int j4 = tid % C4, sl = tid / C4;
    if (sl < 4) {
      const float* wp = Wt + (size_t)(sl * RPS) * DOUT + j4 * 4;
      f32x4 acc = {0.f, 0.f, 0.f, 0.f};
#pragma unroll
      for (int r = 0; r < RPS; ++r) {
        f32x4 wv = *(const f32x4*)(wp + (size_t)r * DOUT);
        float xv = xm[sl * RPS + r];
        acc[0] = fmaf(xv, wv[0], acc[0]);
        acc[1] = fmaf(xv, wv[1], acc[1]);
        acc[2] = fmaf(xv, wv[2], acc[2]);
        acc[3] = fmaf(xv, wv[3], acc[3]);
      }
      *(f32x4*)&red[sl * DOUT + j4 * 4] = acc;
    }
  }
  __syncthreads();
  if (tid < DOUT)
    st[tid] = ((red[0 * DOUT + tid] + red[1 * DOUT + tid]) +
               (red[2 * DOUT + tid] + red[3 * DOUT + tid])) + bias[tid];
  __syncthreads();

  {
    const int j4 = tid % DH4, sl = tid / DH4;
    if (sl < NSLC) {
      f32x4 acc = {0.f, 0.f, 0.f, 0.f};
#pragma unroll
      for (int rr = 0; rr < RPSC; ++rr) {
        int r = sl * RPSC + rr;
        if (r < DOUT) {
          f32x4 wv = *(const f32x4*)(W1 + (size_t)r * DH + j4 * 4);
          float sv = st[r];
          acc[0] = fmaf(sv, wv[0], acc[0]);
          acc[1] = fmaf(sv, wv[1], acc[1]);
          acc[2] = fmaf(sv, wv[2], acc[2]);
          acc[3] = fmaf(sv, wv[3], acc[3]);
        }
      }
      *(f32x4*)&red[(size_t)sl * DH + j4 * 4] = acc;
    }
  }
  __syncthreads();
  if (tid < DH) {
    float a = 0.f;
#pragma unroll 4
    for (int sl = 0; sl < NSLC; ++sl) a += red[(size_t)sl * DH + tid];
    h[tid] = fmaxf(b1[tid] + a, 0.f);
  }
  __syncthreads();

  {
    const int c4 = tid % C4, sl = tid / C4;
    if (sl < NSLD) {
      f32x4 acc = {0.f, 0.f, 0.f, 0.f};
#pragma unroll
      for (int rr = 0; rr < RPSD; ++rr) {
        int r = sl * RPSD + rr;
        if (r < DH) {
          f32x4 wv = *(const f32x4*)(W2 + (size_t)r * DOUT + c4 * 4);
          float hv = h[r];
          acc[0] = fmaf(hv, wv[0], acc[0]);
          acc[1] = fmaf(hv, wv[1], acc[1]);
          acc[2] = fmaf(hv, wv[2], acc[2]);
          acc[3] = fmaf(hv, wv[3], acc[3]);
        }
      }
      *(f32x4*)&red[(size_t)sl * DOUT + c4 * 4] = acc;
    }
  }
  __syncthreads();
  for (int c = tid; c < DOUT; c += 1024) {
    float a = 0.f;
#pragma unroll 4
    for (int sl = 0; sl < NSLD; ++sl) a += red[(size_t)sl * DOUT + c];
    sc[c] = b2[c] + a;
  }
  __syncthreads();

  // stable rank -> mask (+ compacted list when CMP)
  for (int c = tid; c < DOUT; c += 1024) {
    float v = sc[c];
    int rank = 0;
#pragma unroll 8
    for (int j = 0; j < DOUT; ++j) {
      float u = sc[j];
      rank += (u > v) || (u == v && j < c);
    }
    mask[(size_t)b * DOUT + c] = (rank < k) ? 1.f : 0.f;
    if (CMP && rank < k) lsh[rank] = c;
  }
  if constexpr (CMP) {
    if (tid >= k && tid < 256) lsh[tid] = -1;
    __syncthreads();
    if (tid < 256) {
      int c = lsh[tid];
      list_g[b * 256 + tid] = c;
      biasc[b * 256 + tid] = (c >= 0) ? bias[c] : 0.f;
    }
    constexpr int U4 = 384 / 8;        // uint4 per row
    for (int idx = tid; idx < 256 * U4; idx += 1024) {
      int j = idx / U4, u = idx - j * U4;
      int src = lsh[j];
      uint4 v = make_uint4(0u, 0u, 0u, 0u);
      if (src >= 0) v = *(const uint4*)(wsrc + (size_t)src * 384 + u * 8);
      *(uint4*)(wc + (size_t)b * 98304 + (size_t)j * 384 + u * 8) = v;
    }
  }
}

// ---------------------------------------------------------------------------
// All 4 stages' W [K][N] fp32 -> hi/lo bf16 [Npad][K].
// ---------------------------------------------------------------------------
__global__ __launch_bounds__(256)
void convW_all_k(const float* __restrict__ W0, const float* __restrict__ W1,
                 const float* __restrict__ W2, const float* __restrict__ W3,
                 ushort* __restrict__ hi, ushort* __restrict__ lo)
{
  const int Kd[4]   = { 96, 96, 192, 384 };
  const int Nd[4]   = { 96, 192, 384, 768 };
  const int off[5]  = { 0, 12288, 36864, 110592, 405504 };
  const float* Wp[4] = { W0, W1, W2, W3 };

  int idx = blockIdx.x * 256 + threadIdx.x;
  if (idx >= 405504) return;
  int s = (idx >= off[1]) + (idx >= off[2]) + (idx >= off[3]);
  int local = idx - off[s];
  int K = Kd[s], N = Nd[s];
  int n = local / K, kk = local - n * K;
  float v = (n < N) ? Wp[s][(size_t)kk * N + n] : 0.f;
  ushort h = f2bf(v);
  hi[idx] = h;
  lo[idx] = f2bf(v - bf2f(h));
}

#define ASYNC16(GP, LP) __builtin_amdgcn_global_load_lds( \
    (const __attribute__((address_space(1))) void*)(GP),  \
    (__attribute__((address_space(3))) void*)(LP), 16, 0, 0)

// ---------------------------------------------------------------------------
// FUSED GEMM + bias + mask + LN-for-next-stage + colsum epilogue.
// ROUND-9 version (16x16x32 MFMA) — known good. Unchanged.
// ---------------------------------------------------------------------------
template<int K, int NSEG, int BNL, int N, int NWN, bool WLO>
__global__ __launch_bounds__(128 * NWN)
void gemm_ln_k(const ushort* __restrict__ a0, const ushort* __restrict__ a1,
               const ushort* __restrict__ a2,
               const ushort* __restrict__ b0, const ushort* __restrict__ b1,
               const ushort* __restrict__ b2,
               const float* __restrict__ bias, const float* __restrict__ msk,
               const float* __restrict__ gnext, const float* __restrict__ bnext,
               ushort* __restrict__ oh, ushort* __restrict__ ol,
               float* __restrict__ part)
{
  constexpr int T   = 128 * NWN;
  constexpr int R   = T / 4;
  constexpr int AI  = 128 / R;
  constexpr int BI  = BNL / R;
  constexpr int IS  = AI + BI;
  constexpr int WN  = N / NWN;
  constexpr int NFR = WN / 16;
  constexpr int KSTEPS = K / 32;
  constexpr int NT  = NSEG * KSTEPS;
  __shared__ __align__(16) ushort ldsA[3][128 * 32];
  __shared__ __align__(16) ushort ldsB[3][BNL * 32];

  const int tid  = threadIdx.x;
  const int lane = tid & 63;
  const int wid  = tid >> 6;
  const int wm = wid & 1, wn = wid >> 1;

  const int q8  = gridDim.x >> 3;
  const int bid = blockIdx.x;
  const int mt  = (bid & 7) * q8 + (bid >> 3);
  const size_t row0 = (size_t)mt * 128;

  const ushort* Aseg[3] = { a0, a1, a2 };
  const ushort* Bseg[3] = { b0, b1, b2 };

  f32x4 acc[4][NFR];
#pragma unroll
  for (int i = 0; i < 4; ++i)
#pragma unroll
    for (int j = 0; j < NFR; ++j) acc[i][j] = { 0.f, 0.f, 0.f, 0.f };

  const int c_row  = tid >> 2;
  const int c_phys = tid & 3;

#define STAGEF(BUF, TT)                                                        \
  {                                                                            \
    const int seg_ = (TT) / KSTEPS;                                            \
    const int k0_  = ((TT) % KSTEPS) * 32;                                     \
    const ushort* ap_ = Aseg[seg_];                                            \
    const ushort* bp_ = Bseg[seg_];                                            \
    _Pragma("unroll")                                                          \
    for (int r_ = 0; r_ < AI; ++r_) {                                          \
      int row_  = c_row + r_ * R;                                              \
      int slot_ = c_phys ^ ((row_ >> 1) & 3);                                  \
      ASYNC16(ap_ + (row0 + row_) * (size_t)K + (k0_ + slot_ * 8),             \
              &ldsA[BUF][(row_ * 4 + c_phys) * 8]);                            \
    }                                                                          \
    _Pragma("unroll")                                                          \
    for (int r_ = 0; r_ < BI; ++r_) {                                          \
      int row_  = c_row + r_ * R;                                              \
      int slot_ = c_phys ^ ((row_ >> 1) & 3);                                  \
      ASYNC16(bp_ + (size_t)row_ * K + (k0_ + slot_ * 8),                      \
              &ldsB[BUF][(row_ * 4 + c_phys) * 8]);                            \
    }                                                                          \
  }

  STAGEF(0, 0);
  STAGEF(1, 1);
#pragma unroll
  for (int t = 0; t < NT; ++t) {
    if (t == NT - 1)            { asm volatile("s_waitcnt vmcnt(0)" ::: "memory"); }
    else if constexpr (IS == 4) { asm volatile("s_waitcnt vmcnt(4)" ::: "memory"); }
    else                        { asm volatile("s_waitcnt vmcnt(5)" ::: "memory"); }
    __builtin_amdgcn_s_barrier();
    if (t + 2 < NT) STAGEF((t + 2) % 3, t + 2);
    const int buf = t % 3;
    const int slot = lane >> 4;
    const int r16  = lane & 15;
    bf16x8 af[4], bfr[NFR];
#pragma unroll
    for (int mi = 0; mi < 4; ++mi) {
      int r = wm * 64 + mi * 16 + r16;
      af[mi] = *(const bf16x8*)&ldsA[buf][(r * 4 + (slot ^ ((r >> 1) & 3))) * 8];
    }
#pragma unroll
    for (int ni = 0; ni < NFR; ++ni) {
      int r = wn * WN + ni * 16 + r16;
      bfr[ni] = *(const bf16x8*)&ldsB[buf][(r * 4 + (slot ^ ((r >> 1) & 3))) * 8];
    }
#pragma unroll
    for (int mi = 0; mi < 4; ++mi)
#pragma unroll
      for (int ni = 0; ni < NFR; ++ni)
        acc[mi][ni] = __builtin_amdgcn_mfma_f32_16x16x32_bf16(af[mi], bfr[ni],
                                                              acc[mi][ni], 0, 0, 0);
  }
#undef STAGEF

  // ---------------- fused epilogue (round-9, known good) ----------------
  __syncthreads();

  float* rowred = (float*)&ldsA[0][0];   // [NWN][128][2]
  ushort* xsh = (ushort*)&ldsB[0][0];    // [32][N]
  ushort* xsl = xsh + 32 * N;            // [32][N] if WLO
  float* colred = (float*)(xsh + 32 * N * (WLO ? 2 : 1)); // [2sets][2wm][N]

  const int l15 = lane & 15, l4 = lane >> 4;
  const int b0i = (int)(row0 / NTOK);
  const size_t rowB = (size_t)(b0i + 1) * NTOK;
  const bool strad = rowB < row0 + 128;

  float biasv[NFR], mk0a[NFR], mk1a[NFR], gvn[NFR], bvn[NFR];
#pragma unroll
  for (int ni = 0; ni < NFR; ++ni) {
    int n = wn * WN + ni * 16 + l15;
    biasv[ni] = bias[n];
    mk0a[ni] = msk[(size_t)b0i * N + n];
    mk1a[ni] = strad ? msk[(size_t)(b0i + 1) * N + n] : mk0a[ni];
    gvn[ni] = gnext[n];
    bvn[ni] = bnext[n];
  }

  float rs[16], rq[16];
#pragma unroll
  for (int i = 0; i < 16; ++i) { rs[i] = 0.f; rq[i] = 0.f; }
#pragma unroll
  for (int mi = 0; mi < 4; ++mi)
#pragma unroll
    for (int q = 0; q < 4; ++q) {
      size_t row = row0 + wm * 64 + mi * 16 + l4 * 4 + q;
      bool loB = row < rowB;
#pragma unroll
      for (int ni = 0; ni < NFR; ++ni) {
        float v = (acc[mi][ni][q] + biasv[ni]) * (loB ? mk0a[ni] : mk1a[ni]);
        acc[mi][ni][q] = v;
        rs[mi * 4 + q] += v;
        rq[mi * 4 + q] += v * v;
      }
    }
#pragma unroll
  for (int off = 1; off < 16; off <<= 1)
#pragma unroll
    for (int i = 0; i < 16; ++i) {
      rs[i] += __shfl_xor(rs[i], off);
      rq[i] += __shfl_xor(rq[i], off);
    }
  if (l15 == 0) {
#pragma unroll
    for (int mi = 0; mi < 4; ++mi)
#pragma unroll
      for (int q = 0; q < 4; ++q) {
        int r = wm * 64 + mi * 16 + l4 * 4 + q;
        rowred[(wn * 128 + r) * 2 + 0] = rs[mi * 4 + q];
        rowred[(wn * 128 + r) * 2 + 1] = rq[mi * 4 + q];
      }
  }
  __syncthreads();

  float mean[16], rstd[16];
#pragma unroll
  for (int mi = 0; mi < 4; ++mi)
#pragma unroll
    for (int q = 0; q < 4; ++q) {
      int r = wm * 64 + mi * 16 + l4 * 4 + q;
      float S = 0.f, Q = 0.f;
#pragma unroll
      for (int w = 0; w < NWN; ++w) {
        S += rowred[(w * 128 + r) * 2 + 0];
        Q += rowred[(w * 128 + r) * 2 + 1];
      }
      float mn  = S / (float)N;
      float var = Q / (float)N - mn * mn;
      mean[mi * 4 + q] = mn;
      rstd[mi * 4 + q] = 1.f / sqrtf(var + 1e-5f);
    }

  float cs0[NFR], cs1[NFR];
#pragma unroll
  for (int ni = 0; ni < NFR; ++ni) { cs0[ni] = 0.f; cs1[ni] = 0.f; }
#pragma unroll
  for (int mi = 0; mi < 4; ++mi) {
    __syncthreads();
#pragma unroll
    for (int q = 0; q < 4; ++q) {
      const int rl = l4 * 4 + q;
      const size_t row = row0 + wm * 64 + mi * 16 + rl;
      const bool loB = row < rowB;
      const float mn = mean[mi * 4 + q], rv = rstd[mi * 4 + q];
#pragma unroll
      for (int ni = 0; ni < NFR; ++ni) {
        const int n = wn * WN + ni * 16 + l15;
        float xn = (acc[mi][ni][q] - mn) * rv * gvn[ni] + bvn[ni];
        ushort hh = f2bf(xn);
        xsh[(wm * 16 + rl) * N + n] = hh;
        if constexpr (WLO) xsl[(wm * 16 + rl) * N + n] = f2bf(xn - bf2f(hh));
        if (loB) cs0[ni] += xn; else cs1[ni] += xn;
      }
    }
    __syncthreads();
    constexpr int U4R = N / 8;
    for (int idx = tid; idx < 32 * U4R; idx += T) {
      const int grp = idx / U4R, c = idx - grp * U4R;
      const size_t row = row0 + (grp >> 4) * 64 + mi * 16 + (grp & 15);
      *(uint4*)(oh + row * (size_t)N + c * 8) =
          *(const uint4*)(xsh + grp * N + c * 8);
      if constexpr (WLO)
        *(uint4*)(ol + row * (size_t)N + c * 8) =
            *(const uint4*)(xsl + grp * N + c * 8);
    }
  }

#pragma unroll
  for (int ni = 0; ni < NFR; ++ni) {
    cs0[ni] += __shfl_xor(cs0[ni], 16);
    cs0[ni] += __shfl_xor(cs0[ni], 32);
    cs1[ni] += __shfl_xor(cs1[ni], 16);
    cs1[ni] += __shfl_xor(cs1[ni], 32);
  }
  __syncthreads();
  if (l4 == 0) {
#pragma unroll
    for (int ni = 0; ni < NFR; ++ni) {
      int n = wn * WN + ni * 16 + l15;
      colred[(0 * 2 + wm) * N + n] = cs0[ni];
      colred[(1 * 2 + wm) * N + n] = cs1[ni];
    }
  }
  __syncthreads();
  if (wm == 0 && l4 == 0) {
    const int mt_lo = (b0i * NTOK) >> 7;
    const int slot0 = mt - mt_lo;
#pragma unroll
    for (int ni = 0; ni < NFR; ++ni) {
      int n = wn * WN + ni * 16 + l15;
      float t0 = colred[0 * N + n] + colred[1 * N + n];
      part[((size_t)b0i * N + n) * 25 + slot0] = t0;
      if (strad) {
        float t1 = colred[2 * N + n] + colred[3 * N + n];
        part[((size_t)(b0i + 1) * N + n) * 25 + 0] = t1;
      }
    }
  }
}

// ---------------------------------------------------------------------------
// Stage-4 COMPACTED GEMM: per-batch m-tiles (32 x 25 tiles of 128 rows, last
// tile 64 valid rows). Block = 128 rows x 256 compacted cols. 512 thr (8
// waves, 2m x 4n), 16x16x32 MFMA, triple-buffer. FIX vs r12: counted wait is
// vmcnt(3) (3 issues/step: 1 A + 2 B; wait for buf t = allow t+1's 3 in
// flight). A-row staging clamped to batch end (no OOB reads).
// Epilogue: zero-fill 16x768 LDS chunk, scatter active cols (+bias) to true
// column, coalesced f32x4 row stores. Inactive cols = exact 0.
// ---------------------------------------------------------------------------
template<int K>
__global__ __launch_bounds__(512)
void gemm_c4_k(const ushort* __restrict__ A, const ushort* __restrict__ Wc,
               const int* __restrict__ list, const float* __restrict__ biasc,
               float* __restrict__ C)
{
  constexpr int NT = K / 32;       // 12
  __shared__ __align__(16) ushort ldsA[3][128 * 32];
  __shared__ __align__(16) ushort ldsB[3][256 * 32];   // 48 KB; reused as cst

  const int tid  = threadIdx.x;
  const int lane = tid & 63;
  const int wid  = tid >> 6;
  const int wm = wid & 1, wn = wid >> 1;          // wn in 0..3

  // XCD-chunked bijective remap over 800 blocks (800 % 8 == 0)
  const int q8  = gridDim.x >> 3;
  const int bid = blockIdx.x;
  const int wg  = (bid & 7) * q8 + (bid >> 3);
  const int b   = wg / 25;
  const int mt  = wg - b * 25;
  const size_t row0 = (size_t)b * NTOK + (size_t)mt * 128;
  const int rows_valid = (mt == 24) ? 64 : 128;

  const ushort* bp = Wc + (size_t)b * 256 * K;

  const int c_row  = tid >> 2;     // 0..127
  const int c_phys = tid & 3;

  // clamp A staging row to batch end (rows beyond are never stored)
  size_t arow = row0 + c_row;
  const size_t rowEnd = (size_t)(b + 1) * NTOK;
  if (arow >= rowEnd) arow = rowEnd - 1;
  const ushort* apr = A + arow * (size_t)K;

  f32x4 acc[4][4];
#pragma unroll
  for (int i = 0; i < 4; ++i)
#pragma unroll
    for (int j = 0; j < 4; ++j) acc[i][j] = { 0.f, 0.f, 0.f, 0.f };

#define STAGEC(BUF, TT)                                                        \
  {                                                                            \
    const int k0_ = (TT) * 32;                                                 \
    {                                                                          \
      int slot_ = c_phys ^ ((c_row >> 1) & 3);                                 \
      ASYNC16(apr + (k0_ + slot_ * 8),                                         \
              &ldsA[BUF][(c_row * 4 + c_phys) * 8]);                           \
    }                                                                          \
    _Pragma("unroll")                                                          \
    for (int r_ = 0; r_ < 2; ++r_) {                                           \
      int row_  = c_row + r_ * 128;                                            \
      int slot_ = c_phys ^ ((row_ >> 1) & 3);                                  \
      ASYNC16(bp + (size_t)row_ * K + (k0_ + slot_ * 8),                       \
              &ldsB[BUF][(row_ * 4 + c_phys) * 8]);                            \
    }                                                                          \
  }

  STAGEC(0, 0);
  STAGEC(1, 1);
#pragma unroll
  for (int t = 0; t < NT; ++t) {
    if (t == NT - 1) { asm volatile("s_waitcnt vmcnt(0)" ::: "memory"); }
    else             { asm volatile("s_waitcnt vmcnt(3)" ::: "memory"); }
    __builtin_amdgcn_s_barrier();
    if (t + 2 < NT) STAGEC((t + 2) % 3, t + 2);
    const int buf = t % 3;
    const int slot = lane >> 4;
    const int r16  = lane & 15;
    bf16x8 af[4], bfr[4];
#pragma unroll
    for (int mi = 0; mi < 4; ++mi) {
      int r = wm * 64 + mi * 16 + r16;
      af[mi] = *(const bf16x8*)&ldsA[buf][(r * 4 + (slot ^ ((r >> 1) & 3))) * 8];
    }
#pragma unroll
    for (int ni = 0; ni < 4; ++ni) {
      int r = wn * 64 + ni * 16 + r16;
      bfr[ni] = *(const bf16x8*)&ldsB[buf][(r * 4 + (slot ^ ((r >> 1) & 3))) * 8];
    }
#pragma unroll
    for (int mi = 0; mi < 4; ++mi)
#pragma unroll
      for (int ni = 0; ni < 4; ++ni)
        acc[mi][ni] = __builtin_amdgcn_mfma_f32_16x16x32_bf16(af[mi], bfr[ni],
                                                              acc[mi][ni], 0, 0, 0);
  }
#undef STAGEC

  // ---------------- scatter epilogue ----------------
  float* cst = (float*)&ldsB[0][0];      // [16][768] fp32 = 49152 B (exact fit)

  const int l15 = lane & 15, l4 = lane >> 4;
  int   nj[4];
  float biasv[4];
#pragma unroll
  for (int ni = 0; ni < 4; ++ni) {
    int j = wn * 64 + ni * 16 + l15;
    nj[ni]    = list[b * 256 + j];
    biasv[ni] = biasc[b * 256 + j];
  }

#pragma unroll
  for (int hh = 0; hh < 8; ++hh) {       // 16-row chunks
    const int hrows = rows_valid - hh * 16;
    if (hrows <= 0) break;
    __syncthreads();                     // K-loop / prior chunk reads done
    for (int idx = tid; idx < 16 * 192; idx += 512)
      ((f32x4*)cst)[idx] = f32x4{0.f, 0.f, 0.f, 0.f};
    __syncthreads();
    if ((hh >> 2) == wm) {
      const int mi = hh & 3;
#pragma unroll
      for (int q = 0; q < 4; ++q) {
        const int rl = l4 * 4 + q;
#pragma unroll
        for (int ni = 0; ni < 4; ++ni)
          if (nj[ni] >= 0)
            cst[rl * 768 + nj[ni]] = acc[mi][ni][q] + biasv[ni];
      }
    }
    __syncthreads();
    const int nst = (hrows >= 16 ? 16 : hrows) * 192;
    for (int idx = tid; idx < nst; idx += 512) {
      const int grp = idx / 192, c = idx - grp * 192;
      const size_t row = row0 + hh * 16 + grp;
      *(f32x4*)(C + row * 768 + c * 4) = ((const f32x4*)cst)[grp * 192 + c];
    }
  }
}

// ---------------------------------------------------------------------------
extern "C" void kernel_launch(void* const* d_in, const int* in_sizes, int n_in,
                              void* d_out, int out_size, void* d_ws, size_t ws_size,
                              hipStream_t stream)
{
  (void)in_sizes; (void)n_in; (void)out_size; (void)ws_size;
  const float* x = (const float*)d_in[0];
  const float *sg[4], *sb[4], *sW[4], *sbias[4], *pW1[4], *pb1[4], *pW2[4], *pb2[4];
  for (int s = 0; s < 4; ++s) {
    int base = 1 + s * 8;
    sg[s]    = (const float*)d_in[base + 0];
    sb[s]    = (const float*)d_in[base + 1];
    sW[s]    = (const float*)d_in[base + 2];
    sbias[s] = (const float*)d_in[base + 3];
    pW1[s]   = (const float*)d_in[base + 4];
    pb1[s]   = (const float*)d_in[base + 5];
    pW2[s]   = (const float*)d_in[base + 6];
    pb2[s]   = (const float*)d_in[base + 7];
  }

  float* out = (float*)d_out;
  ushort* hiA = (ushort*)out;                    // x̃1 (M*96) then x̃3 (M*384)
  ushort* loA = (ushort*)(out + 19267584);       // lo1 then lo3
  ushort* loB = (ushort*)(out + 38535168);       // lo2 (M*192)

  char* ws = (char*)d_ws;
  ushort* hiB  = (ushort*)(ws);                  // x̃2 (M*192) then x̃4 (M*384)
  float*  part = (float*) (ws + 77070336);
  float*  mk   = (float*) (ws + 79822848);
  ushort* w_hi = (ushort*)(ws + 79921152);       // 811,008
  ushort* w_lo = (ushort*)(ws + 80732160);       // 811,008
  ushort* wc   = (ushort*)(ws + 81543168);       // 6,291,456 (32*256*384 bf16)
  int*    lst  = (int*)   (ws + 87834624);       // 32,768
  float*  bsc  = (float*) (ws + 87867392);       // 32,768 -> end 87,900,160

  const int woff[4] = { 0, 12288, 36864, 110592 };

  convW_all_k<<<(405504 + 255) / 256, 256, 0, stream>>>(
      sW[0], sW[1], sW[2], sW[3], w_hi, w_lo);

  const int LNG = 32 * WPB / 4;

  // ---- stage 1: LN1, scores1, fused gemm1+LN2
  ln_colsum_k<96, true><<<LNG, 256, 0, stream>>>(x, sg[0], sb[0], hiA, loA, part);
  scores_k<96, 96, 224, false><<<32, 1024, 0, stream>>>(part, sW[0], sbias[0],
      pW1[0], pb1[0], pW2[0], pb2[0], mk, 86, nullptr, nullptr, nullptr, nullptr);
  gemm_ln_k<96, 3, 128, 96, 2, true><<<784, 256, 0, stream>>>(
      hiA, hiA, loA, w_hi + woff[0], w_lo + woff[0], w_hi + woff[0],
      sbias[0], mk, sg[1], sb[1], hiB, loB, part);

  // ---- stage 2: scores2, fused gemm2+LN3
  scores_k<96, 192, 25, false><<<32, 1024, 0, stream>>>(part, sW[1], sbias[1],
      pW1[1], pb1[1], pW2[1], pb2[1], mk, 134, nullptr, nullptr, nullptr, nullptr);
  gemm_ln_k<96, 3, 192, 192, 2, true><<<784, 256, 0, stream>>>(
      hiB, hiB, loB, w_hi + woff[1], w_lo + woff[1], w_hi + woff[1],
      sbias[1], mk, sg[2], sb[2], hiA, loA, part);

  // ---- stage 3: scores3, fused gemm3+LN4
  scores_k<192, 384, 25, false><<<32, 1024, 0, stream>>>(part, sW[2], sbias[2],
      pW1[2], pb1[2], pW2[2], pb2[2], mk, 192, nullptr, nullptr, nullptr, nullptr);
  gemm_ln_k<192, 3, 384, 384, 4, false><<<784, 512, 0, stream>>>(
      hiA, hiA, loA, w_hi + woff[2], w_lo + woff[2], w_hi + woff[2],
      sbias[2], mk, sg[3], sb[3], hiB, (ushort*)nullptr, part);

  // ---- stage 4: scores4 (+compaction), compacted GEMM -> d_out
  scores_k<384, 768, 25, true><<<32, 1024, 0, stream>>>(part, sW[3], sbias[3],
      pW1[3], pb1[3], pW2[3], pb2[3], mk, 230, w_hi + woff[3], wc, lst, bsc);
  gemm_c4_k<384><<<800, 512, 0, stream>>>(hiB, wc, lst, bsc, out);
}

// Round 14
// 475.846 us; speedup vs baseline: 1.2452x; 1.0305x over previous
//
#include <hip/hip_runtime.h>
#include <hip/hip_bf16.h>
#include <stdint.h>

#define NTOK 3136
#define MTOT 100352
#define RPW  14          // rows per LN wave (stage-1 LN only)
#define WPB  224         // LN waves per batch (NTOK/RPW)

typedef __attribute__((ext_vector_type(8))) short bf16x8;
typedef __attribute__((ext_vector_type(4))) float f32x4;
typedef __attribute__((ext_vector_type(2))) float f32x2;

static __device__ __forceinline__ ushort f2bf(float x) {
  union { float f; uint32_t u; } c; c.f = x;
  uint32_t r = (c.u + 0x7FFFu + ((c.u >> 16) & 1u)) >> 16;   // RNE
  return (ushort)r;
}
static __device__ __forceinline__ float bf2f(ushort h) {
  union { uint32_t u; float f; } c; c.u = ((uint32_t)h) << 16;
  return c.f;
}

// ---------------------------------------------------------------------------
// Stage-1 LayerNorm (reads fp32 x) + fp32 column partial sums.
// part layout: [b][c][WPB].
// ---------------------------------------------------------------------------
template<int DIN, bool WLO>
__global__ __launch_bounds__(256)
void ln_colsum_k(const float* __restrict__ in, const float* __restrict__ gma,
                 const float* __restrict__ bta, ushort* __restrict__ oh,
                 ushort* __restrict__ ol, float* __restrict__ part)
{
  constexpr int P2 = DIN / 2;
  constexpr int T2 = (P2 + 63) / 64;
  const int wid  = (blockIdx.x * 256 + threadIdx.x) >> 6;
  const int lane = threadIdx.x & 63;
  const int b = wid / WPB;
  const int w = wid - b * WPB;

  f32x2 gv[T2], bv[T2], acc[T2];
#pragma unroll
  for (int t = 0; t < T2; ++t) {
    int c2 = lane + 64 * t;
    if (c2 < P2) {
      gv[t] = *(const f32x2*)(gma + 2 * c2);
      bv[t] = *(const f32x2*)(bta + 2 * c2);
    } else { gv[t] = {0.f, 0.f}; bv[t] = {0.f, 0.f}; }
    acc[t] = {0.f, 0.f};
  }

  const size_t rbase = ((size_t)b * NTOK + (size_t)w * RPW) * DIN;
  const float* ip = in + rbase;
  ushort* oph = oh + rbase;
  ushort* opl = ol + rbase;

  for (int j = 0; j < RPW; ++j) {
    f32x2 v[T2];
    float s = 0.f, sq = 0.f;
#pragma unroll
    for (int t = 0; t < T2; ++t) {
      int c2 = lane + 64 * t;
      f32x2 xv = {0.f, 0.f};
      if (c2 < P2) xv = *(const f32x2*)(ip + (size_t)j * DIN + 2 * c2);
      v[t] = xv;
      s  += xv[0] + xv[1];
      sq += xv[0] * xv[0] + xv[1] * xv[1];
    }
#pragma unroll
    for (int off = 1; off < 64; off <<= 1) {
      s  += __shfl_xor(s, off);
      sq += __shfl_xor(sq, off);
    }
    float m   = s / (float)DIN;
    float var = sq / (float)DIN - m * m;
    float r   = 1.f / sqrtf(var + 1e-5f);
#pragma unroll
    for (int t = 0; t < T2; ++t) {
      int c2 = lane + 64 * t;
      if (c2 < P2) {
        float xn0 = (v[t][0] - m) * r * gv[t][0] + bv[t][0];
        float xn1 = (v[t][1] - m) * r * gv[t][1] + bv[t][1];
        ushort h0 = f2bf(xn0), h1 = f2bf(xn1);
        ((uint32_t*)(oph + (size_t)j * DIN))[c2] =
            (uint32_t)h0 | ((uint32_t)h1 << 16);
        if (WLO) {
          ushort l0 = f2bf(xn0 - bf2f(h0)), l1 = f2bf(xn1 - bf2f(h1));
          ((uint32_t*)(opl + (size_t)j * DIN))[c2] =
              (uint32_t)l0 | ((uint32_t)l1 << 16);
        }
        acc[t][0] += xn0;
        acc[t][1] += xn1;
      }
    }
  }
#pragma unroll
  for (int t = 0; t < T2; ++t) {
    int c2 = lane + 64 * t;
    if (c2 < P2) {
      int c = 2 * c2;
      part[((size_t)b * DIN + c) * WPB + w]     = acc[t][0];
      part[((size_t)b * DIN + c + 1) * WPB + w] = acc[t][1];
    }
  }
}

// ---------------------------------------------------------------------------
// scores_k: FUSED per-batch score pipeline. When CMP, also emits per-batch
// compacted column list (ranks unique -> deterministic), compacted bias, and
// gathered compacted weight rows (hi, and lo when GLO) of length RLEN.
// ---------------------------------------------------------------------------
template<int DIN, int DOUT, int SLOTS, bool CMP, int CMPN, int RLEN, bool GLO>
__global__ __launch_bounds__(1024)
void scores_k(const float* __restrict__ part,
              const float* __restrict__ Wt, const float* __restrict__ bias,
              const float* __restrict__ W1, const float* __restrict__ b1,
              const float* __restrict__ W2, const float* __restrict__ b2,
              float* __restrict__ mask, int k,
              const ushort* __restrict__ whi, const ushort* __restrict__ wlo,
              ushort* __restrict__ wch, ushort* __restrict__ wcl,
              int* __restrict__ list_g, float* __restrict__ biasc)
{
  constexpr int DH  = DOUT / 4;
  constexpr int DH4 = DH / 4;
  constexpr int NSLC = (1024 / DH4 < 64) ? 1024 / DH4 : 64;
  constexpr int RPSC = (DOUT + NSLC - 1) / NSLC;
  constexpr int C4  = DOUT / 4;
  constexpr int NSLD = (1024 / C4 < 64) ? 1024 / C4 : 64;
  constexpr int RPSD = (DH + NSLD - 1) / NSLD;

  __shared__ float xm[DIN];
  __shared__ float st[DOUT];
  __shared__ float h[DH];
  __shared__ float sc[DOUT];
  __shared__ float red[4096];
  __shared__ int lsh[256];

  const int b = blockIdx.x, tid = threadIdx.x;

  if constexpr (SLOTS == 25) {
    if (tid < DIN) {
      const float* p = part + ((size_t)b * DIN + tid) * 25;
      float s = 0.f;
#pragma unroll
      for (int i = 0; i < 25; ++i) s += p[i];
      xm[tid] = s * (1.f / (float)NTOK);
    }
  } else {
    const int cg = tid >> 2, wq = tid & 3;
    if (cg < DIN) {
      const float* p = part + ((size_t)b * DIN + cg) * WPB + wq * 56;
      f32x4 a = {0.f, 0.f, 0.f, 0.f};
#pragma unroll
      for (int u = 0; u < 14; ++u) {
        f32x4 t0 = *(const f32x4*)(p + u * 4);
        a[0] += t0[0]; a[1] += t0[1]; a[2] += t0[2]; a[3] += t0[3];
      }
      red[wq * DIN + cg] = (a[0] + a[1]) + (a[2] + a[3]);
    }
    __syncthreads();
    if (tid < DIN)
      xm[tid] = ((red[0 * DIN + tid] + red[1 * DIN + tid]) +
                 (red[2 * DIN + tid] + red[3 * DIN + tid])) * (1.f / (float)NTOK);
  }
  __syncthreads();

  {
    constexpr int RPS = DIN / 4;
    const int j4 = tid % C4, sl = tid / C4;
    if (sl < 4) {
      const float* wp = Wt + (size_t)(sl * RPS) * DOUT + j4 * 4;
      f32x4 acc = {0.f, 0.f, 0.f, 0.f};
#pragma unroll
      for (int r = 0; r < RPS; ++r) {
        f32x4 wv = *(const f32x4*)(wp + (size_t)r * DOUT);
        float xv = xm[sl * RPS + r];
        acc[0] = fmaf(xv, wv[0], acc[0]);
        acc[1] = fmaf(xv, wv[1], acc[1]);
        acc[2] = fmaf(xv, wv[2], acc[2]);
        acc[3] = fmaf(xv, wv[3], acc[3]);
      }
      *(f32x4*)&red[sl * DOUT + j4 * 4] = acc;
    }
  }
  __syncthreads();
  if (tid < DOUT)
    st[tid] = ((red[0 * DOUT + tid] + red[1 * DOUT + tid]) +
               (red[2 * DOUT + tid] + red[3 * DOUT + tid])) + bias[tid];
  __syncthreads();

  {
    const int j4 = tid % DH4, sl = tid / DH4;
    if (sl < NSLC) {
      f32x4 acc = {0.f, 0.f, 0.f, 0.f};
#pragma unroll
      for (int rr = 0; rr < RPSC; ++rr) {
        int r = sl * RPSC + rr;
        if (r < DOUT) {
          f32x4 wv = *(const f32x4*)(W1 + (size_t)r * DH + j4 * 4);
          float sv = st[r];
          acc[0] = fmaf(sv, wv[0], acc[0]);
          acc[1] = fmaf(sv, wv[1], acc[1]);
          acc[2] = fmaf(sv, wv[2], acc[2]);
          acc[3] = fmaf(sv, wv[3], acc[3]);
        }
      }
      *(f32x4*)&red[(size_t)sl * DH + j4 * 4] = acc;
    }
  }
  __syncthreads();
  if (tid < DH) {
    float a = 0.f;
#pragma unroll 4
    for (int sl = 0; sl < NSLC; ++sl) a += red[(size_t)sl * DH + tid];
    h[tid] = fmaxf(b1[tid] + a, 0.f);
  }
  __syncthreads();

  {
    const int c4 = tid % C4, sl = tid / C4;
    if (sl < NSLD) {
      f32x4 acc = {0.f, 0.f, 0.f, 0.f};
#pragma unroll
      for (int rr = 0; rr < RPSD; ++rr) {
        int r = sl * RPSD + rr;
        if (r < DH) {
          f32x4 wv = *(const f32x4*)(W2 + (size_t)r * DOUT + c4 * 4);
          float hv = h[r];
          acc[0] = fmaf(hv, wv[0], acc[0]);
          acc[1] = fmaf(hv, wv[1], acc[1]);
          acc[2] = fmaf(hv, wv[2], acc[2]);
          acc[3] = fmaf(hv, wv[3], acc[3]);
        }
      }
      *(f32x4*)&red[(size_t)sl * DOUT + c4 * 4] = acc;
    }
  }
  __syncthreads();
  for (int c = tid; c < DOUT; c += 1024) {
    float a = 0.f;
#pragma unroll 4
    for (int sl = 0; sl < NSLD; ++sl) a += red[(size_t)sl * DOUT + c];
    sc[c] = b2[c] + a;
  }
  __syncthreads();

  // stable rank -> mask (+ compacted list when CMP)
  for (int c = tid; c < DOUT; c += 1024) {
    float v = sc[c];
    int rank = 0;
#pragma unroll 8
    for (int j = 0; j < DOUT; ++j) {
      float u = sc[j];
      rank += (u > v) || (u == v && j < c);
    }
    mask[(size_t)b * DOUT + c] = (rank < k) ? 1.f : 0.f;
    if (CMP && rank < k) lsh[rank] = c;
  }
  if constexpr (CMP) {
    if (tid >= k && tid < CMPN) lsh[tid] = -1;
    __syncthreads();
    if (tid < CMPN) {
      int c = lsh[tid];
      list_g[b * 256 + tid] = c;
      biasc[b * 256 + tid] = (c >= 0) ? bias[c] : 0.f;
    }
    constexpr int U4 = RLEN / 8;
    for (int idx = tid; idx < CMPN * U4; idx += 1024) {
      int j = idx / U4, u = idx - j * U4;
      int src = lsh[j];
      uint4 v = make_uint4(0u, 0u, 0u, 0u);
      if (src >= 0) v = *(const uint4*)(whi + (size_t)src * RLEN + u * 8);
      *(uint4*)(wch + ((size_t)b * CMPN + j) * RLEN + u * 8) = v;
      if constexpr (GLO) {
        uint4 vl = make_uint4(0u, 0u, 0u, 0u);
        if (src >= 0) vl = *(const uint4*)(wlo + (size_t)src * RLEN + u * 8);
        *(uint4*)(wcl + ((size_t)b * CMPN + j) * RLEN + u * 8) = vl;
      }
    }
  }
}

// ---------------------------------------------------------------------------
// All 4 stages' W [K][N] fp32 -> hi/lo bf16 [Npad][K].
// ---------------------------------------------------------------------------
__global__ __launch_bounds__(256)
void convW_all_k(const float* __restrict__ W0, const float* __restrict__ W1,
                 const float* __restrict__ W2, const float* __restrict__ W3,
                 ushort* __restrict__ hi, ushort* __restrict__ lo)
{
  const int Kd[4]   = { 96, 96, 192, 384 };
  const int Nd[4]   = { 96, 192, 384, 768 };
  const int off[5]  = { 0, 12288, 36864, 110592, 405504 };
  const float* Wp[4] = { W0, W1, W2, W3 };

  int idx = blockIdx.x * 256 + threadIdx.x;
  if (idx >= 405504) return;
  int s = (idx >= off[1]) + (idx >= off[2]) + (idx >= off[3]);
  int local = idx - off[s];
  int K = Kd[s], N = Nd[s];
  int n = local / K, kk = local - n * K;
  float v = (n < N) ? Wp[s][(size_t)kk * N + n] : 0.f;
  ushort h = f2bf(v);
  hi[idx] = h;
  lo[idx] = f2bf(v - bf2f(h));
}

#define ASYNC16(GP, LP) __builtin_amdgcn_global_load_lds( \
    (const __attribute__((address_space(1))) void*)(GP),  \
    (__attribute__((address_space(3))) void*)(LP), 16, 0, 0)

// ---------------------------------------------------------------------------
// FUSED GEMM + bias + mask + LN-for-next-stage + colsum epilogue.
// ROUND-9 version (16x16x32 MFMA) — known good. Used for stages 1-2.
// ---------------------------------------------------------------------------
template<int K, int NSEG, int BNL, int N, int NWN, bool WLO>
__global__ __launch_bounds__(128 * NWN)
void gemm_ln_k(const ushort* __restrict__ a0, const ushort* __restrict__ a1,
               const ushort* __restrict__ a2,
               const ushort* __restrict__ b0, const ushort* __restrict__ b1,
               const ushort* __restrict__ b2,
               const float* __restrict__ bias, const float* __restrict__ msk,
               const float* __restrict__ gnext, const float* __restrict__ bnext,
               ushort* __restrict__ oh, ushort* __restrict__ ol,
               float* __restrict__ part)
{
  constexpr int T   = 128 * NWN;
  constexpr int R   = T / 4;
  constexpr int AI  = 128 / R;
  constexpr int BI  = BNL / R;
  constexpr int IS  = AI + BI;
  constexpr int WN  = N / NWN;
  constexpr int NFR = WN / 16;
  constexpr int KSTEPS = K / 32;
  constexpr int NT  = NSEG * KSTEPS;
  __shared__ __align__(16) ushort ldsA[3][128 * 32];
  __shared__ __align__(16) ushort ldsB[3][BNL * 32];

  const int tid  = threadIdx.x;
  const int lane = tid & 63;
  const int wid  = tid >> 6;
  const int wm = wid & 1, wn = wid >> 1;

  const int q8  = gridDim.x >> 3;
  const int bid = blockIdx.x;
  const int mt  = (bid & 7) * q8 + (bid >> 3);
  const size_t row0 = (size_t)mt * 128;

  const ushort* Aseg[3] = { a0, a1, a2 };
  const ushort* Bseg[3] = { b0, b1, b2 };

  f32x4 acc[4][NFR];
#pragma unroll
  for (int i = 0; i < 4; ++i)
#pragma unroll
    for (int j = 0; j < NFR; ++j) acc[i][j] = { 0.f, 0.f, 0.f, 0.f };

  const int c_row  = tid >> 2;
  const int c_phys = tid & 3;

#define STAGEF(BUF, TT)                                                        \
  {                                                                            \
    const int seg_ = (TT) / KSTEPS;                                            \
    const int k0_  = ((TT) % KSTEPS) * 32;                                     \
    const ushort* ap_ = Aseg[seg_];                                            \
    const ushort* bp_ = Bseg[seg_];                                            \
    _Pragma("unroll")                                                          \
    for (int r_ = 0; r_ < AI; ++r_) {                                          \
      int row_  = c_row + r_ * R;                                              \
      int slot_ = c_phys ^ ((row_ >> 1) & 3);                                  \
      ASYNC16(ap_ + (row0 + row_) * (size_t)K + (k0_ + slot_ * 8),             \
              &ldsA[BUF][(row_ * 4 + c_phys) * 8]);                            \
    }                                                                          \
    _Pragma("unroll")                                                          \
    for (int r_ = 0; r_ < BI; ++r_) {                                          \
      int row_  = c_row + r_ * R;                                              \
      int slot_ = c_phys ^ ((row_ >> 1) & 3);                                  \
      ASYNC16(bp_ + (size_t)row_ * K + (k0_ + slot_ * 8),                      \
              &ldsB[BUF][(row_ * 4 + c_phys) * 8]);                            \
    }                                                                          \
  }

  STAGEF(0, 0);
  STAGEF(1, 1);
#pragma unroll
  for (int t = 0; t < NT; ++t) {
    if (t == NT - 1)            { asm volatile("s_waitcnt vmcnt(0)" ::: "memory"); }
    else if constexpr (IS == 4) { asm volatile("s_waitcnt vmcnt(4)" ::: "memory"); }
    else                        { asm volatile("s_waitcnt vmcnt(5)" ::: "memory"); }
    __builtin_amdgcn_s_barrier();
    if (t + 2 < NT) STAGEF((t + 2) % 3, t + 2);
    const int buf = t % 3;
    const int slot = lane >> 4;
    const int r16  = lane & 15;
    bf16x8 af[4], bfr[NFR];
#pragma unroll
    for (int mi = 0; mi < 4; ++mi) {
      int r = wm * 64 + mi * 16 + r16;
      af[mi] = *(const bf16x8*)&ldsA[buf][(r * 4 + (slot ^ ((r >> 1) & 3))) * 8];
    }
#pragma unroll
    for (int ni = 0; ni < NFR; ++ni) {
      int r = wn * WN + ni * 16 + r16;
      bfr[ni] = *(const bf16x8*)&ldsB[buf][(r * 4 + (slot ^ ((r >> 1) & 3))) * 8];
    }
#pragma unroll
    for (int mi = 0; mi < 4; ++mi)
#pragma unroll
      for (int ni = 0; ni < NFR; ++ni)
        acc[mi][ni] = __builtin_amdgcn_mfma_f32_16x16x32_bf16(af[mi], bfr[ni],
                                                              acc[mi][ni], 0, 0, 0);
  }
#undef STAGEF

  // ---------------- fused epilogue (round-9, known good) ----------------
  __syncthreads();

  float* rowred = (float*)&ldsA[0][0];   // [NWN][128][2]
  ushort* xsh = (ushort*)&ldsB[0][0];    // [32][N]
  ushort* xsl = xsh + 32 * N;            // [32][N] if WLO
  float* colred = (float*)(xsh + 32 * N * (WLO ? 2 : 1)); // [2sets][2wm][N]

  const int l15 = lane & 15, l4 = lane >> 4;
  const int b0i = (int)(row0 / NTOK);
  const size_t rowB = (size_t)(b0i + 1) * NTOK;
  const bool strad = rowB < row0 + 128;

  float biasv[NFR], mk0a[NFR], mk1a[NFR], gvn[NFR], bvn[NFR];
#pragma unroll
  for (int ni = 0; ni < NFR; ++ni) {
    int n = wn * WN + ni * 16 + l15;
    biasv[ni] = bias[n];
    mk0a[ni] = msk[(size_t)b0i * N + n];
    mk1a[ni] = strad ? msk[(size_t)(b0i + 1) * N + n] : mk0a[ni];
    gvn[ni] = gnext[n];
    bvn[ni] = bnext[n];
  }

  float rs[16], rq[16];
#pragma unroll
  for (int i = 0; i < 16; ++i) { rs[i] = 0.f; rq[i] = 0.f; }
#pragma unroll
  for (int mi = 0; mi < 4; ++mi)
#pragma unroll
    for (int q = 0; q < 4; ++q) {
      size_t row = row0 + wm * 64 + mi * 16 + l4 * 4 + q;
      bool loB = row < rowB;
#pragma unroll
      for (int ni = 0; ni < NFR; ++ni) {
        float v = (acc[mi][ni][q] + biasv[ni]) * (loB ? mk0a[ni] : mk1a[ni]);
        acc[mi][ni][q] = v;
        rs[mi * 4 + q] += v;
        rq[mi * 4 + q] += v * v;
      }
    }
#pragma unroll
  for (int off = 1; off < 16; off <<= 1)
#pragma unroll
    for (int i = 0; i < 16; ++i) {
      rs[i] += __shfl_xor(rs[i], off);
      rq[i] += __shfl_xor(rq[i], off);
    }
  if (l15 == 0) {
#pragma unroll
    for (int mi = 0; mi < 4; ++mi)
#pragma unroll
      for (int q = 0; q < 4; ++q) {
        int r = wm * 64 + mi * 16 + l4 * 4 + q;
        rowred[(wn * 128 + r) * 2 + 0] = rs[mi * 4 + q];
        rowred[(wn * 128 + r) * 2 + 1] = rq[mi * 4 + q];
      }
  }
  __syncthreads();

  float mean[16], rstd[16];
#pragma unroll
  for (int mi = 0; mi < 4; ++mi)
#pragma unroll
    for (int q = 0; q < 4; ++q) {
      int r = wm * 64 + mi * 16 + l4 * 4 + q;
      float S = 0.f, Q = 0.f;
#pragma unroll
      for (int w = 0; w < NWN; ++w) {
        S += rowred[(w * 128 + r) * 2 + 0];
        Q += rowred[(w * 128 + r) * 2 + 1];
      }
      float mn  = S / (float)N;
      float var = Q / (float)N - mn * mn;
      mean[mi * 4 + q] = mn;
      rstd[mi * 4 + q] = 1.f / sqrtf(var + 1e-5f);
    }

  float cs0[NFR], cs1[NFR];
#pragma unroll
  for (int ni = 0; ni < NFR; ++ni) { cs0[ni] = 0.f; cs1[ni] = 0.f; }
#pragma unroll
  for (int mi = 0; mi < 4; ++mi) {
    __syncthreads();
#pragma unroll
    for (int q = 0; q < 4; ++q) {
      const int rl = l4 * 4 + q;
      const size_t row = row0 + wm * 64 + mi * 16 + rl;
      const bool loB = row < rowB;
      const float mn = mean[mi * 4 + q], rv = rstd[mi * 4 + q];
#pragma unroll
      for (int ni = 0; ni < NFR; ++ni) {
        const int n = wn * WN + ni * 16 + l15;
        float xn = (acc[mi][ni][q] - mn) * rv * gvn[ni] + bvn[ni];
        ushort hh = f2bf(xn);
        xsh[(wm * 16 + rl) * N + n] = hh;
        if constexpr (WLO) xsl[(wm * 16 + rl) * N + n] = f2bf(xn - bf2f(hh));
        if (loB) cs0[ni] += xn; else cs1[ni] += xn;
      }
    }
    __syncthreads();
    constexpr int U4R = N / 8;
    for (int idx = tid; idx < 32 * U4R; idx += T) {
      const int grp = idx / U4R, c = idx - grp * U4R;
      const size_t row = row0 + (grp >> 4) * 64 + mi * 16 + (grp & 15);
      *(uint4*)(oh + row * (size_t)N + c * 8) =
          *(const uint4*)(xsh + grp * N + c * 8);
      if constexpr (WLO)
        *(uint4*)(ol + row * (size_t)N + c * 8) =
            *(const uint4*)(xsl + grp * N + c * 8);
    }
  }

#pragma unroll
  for (int ni = 0; ni < NFR; ++ni) {
    cs0[ni] += __shfl_xor(cs0[ni], 16);
    cs0[ni] += __shfl_xor(cs0[ni], 32);
    cs1[ni] += __shfl_xor(cs1[ni], 16);
    cs1[ni] += __shfl_xor(cs1[ni], 32);
  }
  __syncthreads();
  if (l4 == 0) {
#pragma unroll
    for (int ni = 0; ni < NFR; ++ni) {
      int n = wn * WN + ni * 16 + l15;
      colred[(0 * 2 + wm) * N + n] = cs0[ni];
      colred[(1 * 2 + wm) * N + n] = cs1[ni];
    }
  }
  __syncthreads();
  if (wm == 0 && l4 == 0) {
    const int mt_lo = (b0i * NTOK) >> 7;
    const int slot0 = mt - mt_lo;
#pragma unroll
    for (int ni = 0; ni < NFR; ++ni) {
      int n = wn * WN + ni * 16 + l15;
      float t0 = colred[0 * N + n] + colred[1 * N + n];
      part[((size_t)b0i * N + n) * 25 + slot0] = t0;
      if (strad) {
        float t1 = colred[2 * N + n] + colred[3 * N + n];
        part[((size_t)(b0i + 1) * N + n) * 25 + 0] = t1;
      }
    }
  }
}

// ---------------------------------------------------------------------------
// Stage-3 COMPACT GEMM + LN epilogue. Per-batch m-tiles (25 per batch, last
// has 64 valid rows -> no straddle). Block = 128 rows x NC=192 ACTIVE cols
// (Wc3 hi/lo gathered by scores3), 3 hi/lo segments, 256 thr (2m x 2n waves,
// WN=96). Triple-buffer, IS = 2A+3B = 5 -> vmcnt(5). Epilogue: row stats
// from actives (inactive v = 0 exactly); scatter s = v*rv to true columns in
// LDS; DENSE x~4 store: xn[c] = gamma[c]*(s[c]-mn*rv) + beta[c]; colsums via
// closed form gamma*(sum_s - sum_mnrv) + nrows*beta -> part[b][c][mt].
// ---------------------------------------------------------------------------
template<int K, int NC, int N>
__global__ __launch_bounds__(256)
void gemm_lnc_k(const ushort* __restrict__ ahi, const ushort* __restrict__ alo,
                const ushort* __restrict__ wch, const ushort* __restrict__ wcl,
                const int* __restrict__ list, const float* __restrict__ biasc,
                const float* __restrict__ gnext, const float* __restrict__ bnext,
                ushort* __restrict__ oh, float* __restrict__ part)
{
  constexpr int KSTEPS = K / 32;       // 6
  constexpr int NT  = 3 * KSTEPS;      // 18
  constexpr int WN  = NC / 2;          // 96
  constexpr int NFR = WN / 16;         // 6
  __shared__ __align__(16) ushort ldsA[3][128 * 32];
  __shared__ __align__(16) ushort ldsB[3][NC * 32];
  __shared__ float rowred[2][128][2];
  __shared__ float rowmnrv[128];
  __shared__ float rowrv[128];

  const int tid  = threadIdx.x;
  const int lane = tid & 63;
  const int wid  = tid >> 6;
  const int wm = wid & 1, wn = wid >> 1;

  const int q8  = gridDim.x >> 3;
  const int bid = blockIdx.x;
  const int wg  = (bid & 7) * q8 + (bid >> 3);
  const int b   = wg / 25;
  const int mt  = wg - b * 25;
  const size_t row0 = (size_t)b * NTOK + (size_t)mt * 128;
  const size_t rowEnd = (size_t)(b + 1) * NTOK;
  const int rows_valid = (mt == 24) ? 64 : 128;

  const ushort* Aseg[3] = { ahi, ahi, alo };
  const ushort* Bseg[3] = { wch + (size_t)b * NC * K, wcl + (size_t)b * NC * K,
                            wch + (size_t)b * NC * K };

  f32x4 acc[4][NFR];
#pragma unroll
  for (int i = 0; i < 4; ++i)
#pragma unroll
    for (int j = 0; j < NFR; ++j) acc[i][j] = { 0.f, 0.f, 0.f, 0.f };

  const int c_row  = tid >> 2;     // 0..63
  const int c_phys = tid & 3;

#define STAGEL(BUF, TT)                                                        \
  {                                                                            \
    const int seg_ = (TT) / KSTEPS;                                            \
    const int k0_  = ((TT) % KSTEPS) * 32;                                     \
    const ushort* ap_ = Aseg[seg_];                                            \
    const ushort* bp_ = Bseg[seg_];                                            \
    _Pragma("unroll")                                                          \
    for (int r_ = 0; r_ < 2; ++r_) {                                           \
      int row_  = c_row + r_ * 64;                                             \
      int slot_ = c_phys ^ ((row_ >> 1) & 3);                                  \
      size_t ar_ = row0 + row_;                                                \
      if (ar_ >= rowEnd) ar_ = rowEnd - 1;                                     \
      ASYNC16(ap_ + ar_ * (size_t)K + (k0_ + slot_ * 8),                       \
              &ldsA[BUF][(row_ * 4 + c_phys) * 8]);                            \
    }                                                                          \
    _Pragma("unroll")                                                          \
    for (int r_ = 0; r_ < 3; ++r_) {                                           \
      int row_  = c_row + r_ * 64;                                             \
      int slot_ = c_phys ^ ((row_ >> 1) & 3);                                  \
      ASYNC16(bp_ + (size_t)row_ * K + (k0_ + slot_ * 8),                      \
              &ldsB[BUF][(row_ * 4 + c_phys) * 8]);                            \
    }                                                                          \
  }

  STAGEL(0, 0);
  STAGEL(1, 1);
#pragma unroll
  for (int t = 0; t < NT; ++t) {
    if (t == NT - 1) { asm volatile("s_waitcnt vmcnt(0)" ::: "memory"); }
    else             { asm volatile("s_waitcnt vmcnt(5)" ::: "memory"); }
    __builtin_amdgcn_s_barrier();
    if (t + 2 < NT) STAGEL((t + 2) % 3, t + 2);
    const int buf = t % 3;
    const int slot = lane >> 4;
    const int r16  = lane & 15;
    bf16x8 af[4], bfr[NFR];
#pragma unroll
    for (int mi = 0; mi < 4; ++mi) {
      int r = wm * 64 + mi * 16 + r16;
      af[mi] = *(const bf16x8*)&ldsA[buf][(r * 4 + (slot ^ ((r >> 1) & 3))) * 8];
    }
#pragma unroll
    for (int ni = 0; ni < NFR; ++ni) {
      int r = wn * WN + ni * 16 + r16;
      bfr[ni] = *(const bf16x8*)&ldsB[buf][(r * 4 + (slot ^ ((r >> 1) & 3))) * 8];
    }
#pragma unroll
    for (int mi = 0; mi < 4; ++mi)
#pragma unroll
      for (int ni = 0; ni < NFR; ++ni)
        acc[mi][ni] = __builtin_amdgcn_mfma_f32_16x16x32_bf16(af[mi], bfr[ni],
                                                              acc[mi][ni], 0, 0, 0);
  }
#undef STAGEL

  // ---------------- compact-LN epilogue ----------------
  __syncthreads();

  const int l15 = lane & 15, l4 = lane >> 4;

  int   nj[NFR];
  float biasv[NFR];
#pragma unroll
  for (int ni = 0; ni < NFR; ++ni) {
    int j = wn * WN + ni * 16 + l15;
    nj[ni]    = list[b * 256 + j];       // always >= 0 (k == NC == 192)
    biasv[ni] = biasc[b * 256 + j];
  }

  // v = acc + biasc (active cols); row partial sums (inactive contribute 0)
  float rs[16], rq[16];
#pragma unroll
  for (int i = 0; i < 16; ++i) { rs[i] = 0.f; rq[i] = 0.f; }
#pragma unroll
  for (int mi = 0; mi < 4; ++mi)
#pragma unroll
    for (int q = 0; q < 4; ++q) {
#pragma unroll
      for (int ni = 0; ni < NFR; ++ni) {
        float v = acc[mi][ni][q] + biasv[ni];
        acc[mi][ni][q] = v;
        rs[mi * 4 + q] += v;
        rq[mi * 4 + q] += v * v;
      }
    }
#pragma unroll
  for (int off = 1; off < 16; off <<= 1)
#pragma unroll
    for (int i = 0; i < 16; ++i) {
      rs[i] += __shfl_xor(rs[i], off);
      rq[i] += __shfl_xor(rq[i], off);
    }
  if (l15 == 0) {
#pragma unroll
    for (int mi = 0; mi < 4; ++mi)
#pragma unroll
      for (int q = 0; q < 4; ++q) {
        int r = wm * 64 + mi * 16 + l4 * 4 + q;
        rowred[wn][r][0] = rs[mi * 4 + q];
        rowred[wn][r][1] = rq[mi * 4 + q];
      }
  }
  __syncthreads();
  if (tid < 128) {
    float S = rowred[0][tid][0] + rowred[1][tid][0];
    float Q = rowred[0][tid][1] + rowred[1][tid][1];
    float mn = S / (float)N;
    float rv = 1.f / sqrtf(Q / (float)N - mn * mn + 1e-5f);
    rowmnrv[tid] = mn * rv;
    rowrv[tid]   = rv;
  }
  __syncthreads();

  float* sbuf = (float*)&ldsB[0][0];     // [16][N] fp32 = 24 KB
  float colS = 0.f, colS2 = 0.f;         // cols tid and 256+tid

#pragma unroll
  for (int h = 0; h < 8; ++h) {
    if (h * 16 >= rows_valid) break;
    __syncthreads();
    for (int idx = tid; idx < 16 * N / 4; idx += 256)
      ((f32x4*)sbuf)[idx] = f32x4{0.f, 0.f, 0.f, 0.f};
    __syncthreads();
    if ((h >> 2) == wm) {
      const int mi = h & 3;
#pragma unroll
      for (int q = 0; q < 4; ++q) {
        const int rl = l4 * 4 + q;
        const float rv = rowrv[h * 16 + rl];
#pragma unroll
        for (int ni = 0; ni < NFR; ++ni)
          sbuf[rl * N + nj[ni]] = acc[mi][ni][q] * rv;
      }
    }
    __syncthreads();
    // colsum(s) accumulate, fixed column per thread
    {
      float a = 0.f;
#pragma unroll
      for (int rl = 0; rl < 16; ++rl) a += sbuf[rl * N + tid];
      colS += a;
      if (tid < N - 256) {
        float a2 = 0.f;
        const int c2 = 256 + tid;
#pragma unroll
        for (int rl = 0; rl < 16; ++rl) a2 += sbuf[rl * N + c2];
        colS2 += a2;
      }
    }
    // dense coalesced store of x~4 (hi only)
    for (int idx = tid; idx < 16 * (N / 8); idx += 256) {
      const int rl = idx / (N / 8), cg = idx - rl * (N / 8);
      const float mnrv = rowmnrv[h * 16 + rl];
      const float* sp = sbuf + rl * N + cg * 8;
      f32x4 s0 = *(const f32x4*)(sp);
      f32x4 s1 = *(const f32x4*)(sp + 4);
      f32x4 g0 = *(const f32x4*)(gnext + cg * 8);
      f32x4 g1 = *(const f32x4*)(gnext + cg * 8 + 4);
      f32x4 e0 = *(const f32x4*)(bnext + cg * 8);
      f32x4 e1 = *(const f32x4*)(bnext + cg * 8 + 4);
      uint32_t w[4];
#pragma unroll
      for (int j = 0; j < 2; ++j) {
        ushort ha = f2bf(g0[2*j]   * (s0[2*j]   - mnrv) + e0[2*j]);
        ushort hb = f2bf(g0[2*j+1] * (s0[2*j+1] - mnrv) + e0[2*j+1]);
        w[j] = (uint32_t)ha | ((uint32_t)hb << 16);
      }
#pragma unroll
      for (int j = 0; j < 2; ++j) {
        ushort ha = f2bf(g1[2*j]   * (s1[2*j]   - mnrv) + e1[2*j]);
        ushort hb = f2bf(g1[2*j+1] * (s1[2*j+1] - mnrv) + e1[2*j+1]);
        w[2 + j] = (uint32_t)ha | ((uint32_t)hb << 16);
      }
      *(uint4*)(oh + (row0 + h * 16 + rl) * (size_t)N + cg * 8) =
          make_uint4(w[0], w[1], w[2], w[3]);
    }
  }

  // part[b][c][mt] = gamma*(colS - sum_mnrv) + rows_valid*beta
  float msum = 0.f;
  for (int r = 0; r < rows_valid; ++r) msum += rowmnrv[r];
  {
    const int c = tid;
    part[((size_t)b * N + c) * 25 + mt] =
        gnext[c] * (colS - msum) + (float)rows_valid * bnext[c];
    if (tid < N - 256) {
      const int c2 = 256 + tid;
      part[((size_t)b * N + c2) * 25 + mt] =
          gnext[c2] * (colS2 - msum) + (float)rows_valid * bnext[c2];
    }
  }
}

// ---------------------------------------------------------------------------
// Stage-4 COMPACTED GEMM (round-13, known good): per-batch m-tiles, 128 rows
// x 256 compacted cols, 512 thr, vmcnt(3), scatter epilogue.
// ---------------------------------------------------------------------------
template<int K>
__global__ __launch_bounds__(512)
void gemm_c4_k(const ushort* __restrict__ A, const ushort* __restrict__ Wc,
               const int* __restrict__ list, const float* __restrict__ biasc,
               float* __restrict__ C)
{
  constexpr int NT = K / 32;       // 12
  __shared__ __align__(16) ushort ldsA[3][128 * 32];
  __shared__ __align__(16) ushort ldsB[3][256 * 32];   // 48 KB; reused as cst

  const int tid  = threadIdx.x;
  const int lane = tid & 63;
  const int wid  = tid >> 6;
  const int wm = wid & 1, wn = wid >> 1;          // wn in 0..3

  const int q8  = gridDim.x >> 3;
  const int bid = blockIdx.x;
  const int wg  = (bid & 7) * q8 + (bid >> 3);
  const int b   = wg / 25;
  const int mt  = wg - b * 25;
  const size_t row0 = (size_t)b * NTOK + (size_t)mt * 128;
  const int rows_valid = (mt == 24) ? 64 : 128;

  const ushort* bp = Wc + (size_t)b * 256 * K;

  const int c_row  = tid >> 2;     // 0..127
  const int c_phys = tid & 3;

  size_t arow = row0 + c_row;
  const size_t rowEnd = (size_t)(b + 1) * NTOK;
  if (arow >= rowEnd) arow = rowEnd - 1;
  const ushort* apr = A + arow * (size_t)K;

  f32x4 acc[4][4];
#pragma unroll
  for (int i = 0; i < 4; ++i)
#pragma unroll
    for (int j = 0; j < 4; ++j) acc[i][j] = { 0.f, 0.f, 0.f, 0.f };

#define STAGEC(BUF, TT)                                                        \
  {                                                                            \
    const int k0_ = (TT) * 32;                                                 \
    {                                                                          \
      int slot_ = c_phys ^ ((c_row >> 1) & 3);                                 \
      ASYNC16(apr + (k0_ + slot_ * 8),                                         \
              &ldsA[BUF][(c_row * 4 + c_phys) * 8]);                           \
    }                                                                          \
    _Pragma("unroll")                                                          \
    for (int r_ = 0; r_ < 2; ++r_) {                                           \
      int row_  = c_row + r_ * 128;                                            \
      int slot_ = c_phys ^ ((row_ >> 1) & 3);                                  \
      ASYNC16(bp + (size_t)row_ * K + (k0_ + slot_ * 8),                       \
              &ldsB[BUF][(row_ * 4 + c_phys) * 8]);                            \
    }                                                                          \
  }

  STAGEC(0, 0);
  STAGEC(1, 1);
#pragma unroll
  for (int t = 0; t < NT; ++t) {
    if (t == NT - 1) { asm volatile("s_waitcnt vmcnt(0)" ::: "memory"); }
    else             { asm volatile("s_waitcnt vmcnt(3)" ::: "memory"); }
    __builtin_amdgcn_s_barrier();
    if (t + 2 < NT) STAGEC((t + 2) % 3, t + 2);
    const int buf = t % 3;
    const int slot = lane >> 4;
    const int r16  = lane & 15;
    bf16x8 af[4], bfr[4];
#pragma unroll
    for (int mi = 0; mi < 4; ++mi) {
      int r = wm * 64 + mi * 16 + r16;
      af[mi] = *(const bf16x8*)&ldsA[buf][(r * 4 + (slot ^ ((r >> 1) & 3))) * 8];
    }
#pragma unroll
    for (int ni = 0; ni < 4; ++ni) {
      int r = wn * 64 + ni * 16 + r16;
      bfr[ni] = *(const bf16x8*)&ldsB[buf][(r * 4 + (slot ^ ((r >> 1) & 3))) * 8];
    }
#pragma unroll
    for (int mi = 0; mi < 4; ++mi)
#pragma unroll
      for (int ni = 0; ni < 4; ++ni)
        acc[mi][ni] = __builtin_amdgcn_mfma_f32_16x16x32_bf16(af[mi], bfr[ni],
                                                              acc[mi][ni], 0, 0, 0);
  }
#undef STAGEC

  float* cst = (float*)&ldsB[0][0];      // [16][768] fp32

  const int l15 = lane & 15, l4 = lane >> 4;
  int   nj[4];
  float biasv[4];
#pragma unroll
  for (int ni = 0; ni < 4; ++ni) {
    int j = wn * 64 + ni * 16 + l15;
    nj[ni]    = list[b * 256 + j];
    biasv[ni] = biasc[b * 256 + j];
  }

#pragma unroll
  for (int hh = 0; hh < 8; ++hh) {
    const int hrows = rows_valid - hh * 16;
    if (hrows <= 0) break;
    __syncthreads();
    for (int idx = tid; idx < 16 * 192; idx += 512)
      ((f32x4*)cst)[idx] = f32x4{0.f, 0.f, 0.f, 0.f};
    __syncthreads();
    if ((hh >> 2) == wm) {
      const int mi = hh & 3;
#pragma unroll
      for (int q = 0; q < 4; ++q) {
        const int rl = l4 * 4 + q;
#pragma unroll
        for (int ni = 0; ni < 4; ++ni)
          if (nj[ni] >= 0)
            cst[rl * 768 + nj[ni]] = acc[mi][ni][q] + biasv[ni];
      }
    }
    __syncthreads();
    const int nst = (hrows >= 16 ? 16 : hrows) * 192;
    for (int idx = tid; idx < nst; idx += 512) {
      const int grp = idx / 192, c = idx - grp * 192;
      const size_t row = row0 + hh * 16 + grp;
      *(f32x4*)(C + row * 768 + c * 4) = ((const f32x4*)cst)[grp * 192 + c];
    }
  }
}

// ---------------------------------------------------------------------------
extern "C" void kernel_launch(void* const* d_in, const int* in_sizes, int n_in,
                              void* d_out, int out_size, void* d_ws, size_t ws_size,
                              hipStream_t stream)
{
  (void)in_sizes; (void)n_in; (void)out_size; (void)ws_size;
  const float* x = (const float*)d_in[0];
  const float *sg[4], *sb[4], *sW[4], *sbias[4], *pW1[4], *pb1[4], *pW2[4], *pb2[4];
  for (int s = 0; s < 4; ++s) {
    int base = 1 + s * 8;
    sg[s]    = (const float*)d_in[base + 0];
    sb[s]    = (const float*)d_in[base + 1];
    sW[s]    = (const float*)d_in[base + 2];
    sbias[s] = (const float*)d_in[base + 3];
    pW1[s]   = (const float*)d_in[base + 4];
    pb1[s]   = (const float*)d_in[base + 5];
    pW2[s]   = (const float*)d_in[base + 6];
    pb2[s]   = (const float*)d_in[base + 7];
  }

  float* out = (float*)d_out;
  ushort* hiA = (ushort*)out;                    // x̃1 (M*96) then x̃3 (M*384... M*192)
  ushort* loA = (ushort*)(out + 19267584);       // lo1 then lo3
  ushort* loB = (ushort*)(out + 38535168);       // lo2 (M*192)

  char* ws = (char*)d_ws;
  ushort* hiB  = (ushort*)(ws);                  // x̃2 (M*192) then x̃4 (M*384)
  float*  part = (float*) (ws + 77070336);
  float*  mk   = (float*) (ws + 79822848);
  ushort* w_hi = (ushort*)(ws + 79921152);       // 811,008
  ushort* w_lo = (ushort*)(ws + 80732160);       // 811,008
  ushort* wc   = (ushort*)(ws + 81543168);       // 6,291,456 B capacity
  int*    lst  = (int*)   (ws + 87834624);       // 32,768
  float*  bsc  = (float*) (ws + 87867392);       // 32,768 -> end 87,900,160

  // stage-3 compacted weights live inside wc (hi then lo), overwritten later
  // by stage-4's gather (serial stream -> safe).
  ushort* wch3 = wc;                              // 32*192*192 = 1,179,648 elems
  ushort* wcl3 = wc + 1179648;                    // 1,179,648 elems

  const int woff[4] = { 0, 12288, 36864, 110592 };

  convW_all_k<<<(405504 + 255) / 256, 256, 0, stream>>>(
      sW[0], sW[1], sW[2], sW[3], w_hi, w_lo);

  const int LNG = 32 * WPB / 4;

  // ---- stage 1: LN1, scores1, fused gemm1+LN2
  ln_colsum_k<96, true><<<LNG, 256, 0, stream>>>(x, sg[0], sb[0], hiA, loA, part);
  scores_k<96, 96, 224, false, 256, 384, false><<<32, 1024, 0, stream>>>(
      part, sW[0], sbias[0], pW1[0], pb1[0], pW2[0], pb2[0], mk, 86,
      nullptr, nullptr, nullptr, nullptr, nullptr, nullptr);
  gemm_ln_k<96, 3, 128, 96, 2, true><<<784, 256, 0, stream>>>(
      hiA, hiA, loA, w_hi + woff[0], w_lo + woff[0], w_hi + woff[0],
      sbias[0], mk, sg[1], sb[1], hiB, loB, part);

  // ---- stage 2: scores2, fused gemm2+LN3
  scores_k<96, 192, 25, false, 256, 384, false><<<32, 1024, 0, stream>>>(
      part, sW[1], sbias[1], pW1[1], pb1[1], pW2[1], pb2[1], mk, 134,
      nullptr, nullptr, nullptr, nullptr, nullptr, nullptr);
  gemm_ln_k<96, 3, 192, 192, 2, true><<<784, 256, 0, stream>>>(
      hiB, hiB, loB, w_hi + woff[1], w_lo + woff[1], w_hi + woff[1],
      sbias[1], mk, sg[2], sb[2], hiA, loA, part);

  // ---- stage 3: scores3 (+hi/lo compaction, k=192), compact gemm3+LN4
  scores_k<192, 384, 25, true, 192, 192, true><<<32, 1024, 0, stream>>>(
      part, sW[2], sbias[2], pW1[2], pb1[2], pW2[2], pb2[2], mk, 192,
      w_hi + woff[2], w_lo + woff[2], wch3, wcl3, lst, bsc);
  gemm_lnc_k<192, 192, 384><<<800, 256, 0, stream>>>(
      hiA, loA, wch3, wcl3, lst, bsc, sg[3], sb[3], hiB, part);

  // ---- stage 4: scores4 (+compaction), compacted GEMM -> d_out
  scores_k<384, 768, 25, true, 256, 384, false><<<32, 1024, 0, stream>>>(
      part, sW[3], sbias[3], pW1[3], pb1[3], pW2[3], pb2[3], mk, 230,
      w_hi + woff[3], nullptr, wc, nullptr, lst, bsc);
  gemm_c4_k<384><<<800, 512, 0, stream>>>(hiB, wc, lst, bsc, out);
}

// Round 15
// 461.932 us; speedup vs baseline: 1.2827x; 1.0301x over previous
//
#include <hip/hip_runtime.h>
#include <hip/hip_bf16.h>
#include <stdint.h>

#define NTOK 3136
#define MTOT 100352
#define RPW  14          // rows per LN wave (stage-1 LN only)
#define WPB  224         // LN waves per batch (NTOK/RPW)

typedef __attribute__((ext_vector_type(8))) short bf16x8;
typedef __attribute__((ext_vector_type(4))) float f32x4;
typedef __attribute__((ext_vector_type(2))) float f32x2;

static __device__ __forceinline__ ushort f2bf(float x) {
  union { float f; uint32_t u; } c; c.f = x;
  uint32_t r = (c.u + 0x7FFFu + ((c.u >> 16) & 1u)) >> 16;   // RNE
  return (ushort)r;
}
static __device__ __forceinline__ float bf2f(ushort h) {
  union { uint32_t u; float f; } c; c.u = ((uint32_t)h) << 16;
  return c.f;
}

// ---------------------------------------------------------------------------
// Stage-1 LayerNorm (reads fp32 x) + fp32 column partial sums.
// part layout: [b][c][WPB].
// ---------------------------------------------------------------------------
template<int DIN, bool WLO>
__global__ __launch_bounds__(256)
void ln_colsum_k(const float* __restrict__ in, const float* __restrict__ gma,
                 const float* __restrict__ bta, ushort* __restrict__ oh,
                 ushort* __restrict__ ol, float* __restrict__ part)
{
  constexpr int P2 = DIN / 2;
  constexpr int T2 = (P2 + 63) / 64;
  const int wid  = (blockIdx.x * 256 + threadIdx.x) >> 6;
  const int lane = threadIdx.x & 63;
  const int b = wid / WPB;
  const int w = wid - b * WPB;

  f32x2 gv[T2], bv[T2], acc[T2];
#pragma unroll
  for (int t = 0; t < T2; ++t) {
    int c2 = lane + 64 * t;
    if (c2 < P2) {
      gv[t] = *(const f32x2*)(gma + 2 * c2);
      bv[t] = *(const f32x2*)(bta + 2 * c2);
    } else { gv[t] = {0.f, 0.f}; bv[t] = {0.f, 0.f}; }
    acc[t] = {0.f, 0.f};
  }

  const size_t rbase = ((size_t)b * NTOK + (size_t)w * RPW) * DIN;
  const float* ip = in + rbase;
  ushort* oph = oh + rbase;
  ushort* opl = ol + rbase;

  for (int j = 0; j < RPW; ++j) {
    f32x2 v[T2];
    float s = 0.f, sq = 0.f;
#pragma unroll
    for (int t = 0; t < T2; ++t) {
      int c2 = lane + 64 * t;
      f32x2 xv = {0.f, 0.f};
      if (c2 < P2) xv = *(const f32x2*)(ip + (size_t)j * DIN + 2 * c2);
      v[t] = xv;
      s  += xv[0] + xv[1];
      sq += xv[0] * xv[0] + xv[1] * xv[1];
    }
#pragma unroll
    for (int off = 1; off < 64; off <<= 1) {
      s  += __shfl_xor(s, off);
      sq += __shfl_xor(sq, off);
    }
    float m   = s / (float)DIN;
    float var = sq / (float)DIN - m * m;
    float r   = 1.f / sqrtf(var + 1e-5f);
#pragma unroll
    for (int t = 0; t < T2; ++t) {
      int c2 = lane + 64 * t;
      if (c2 < P2) {
        float xn0 = (v[t][0] - m) * r * gv[t][0] + bv[t][0];
        float xn1 = (v[t][1] - m) * r * gv[t][1] + bv[t][1];
        ushort h0 = f2bf(xn0), h1 = f2bf(xn1);
        ((uint32_t*)(oph + (size_t)j * DIN))[c2] =
            (uint32_t)h0 | ((uint32_t)h1 << 16);
        if (WLO) {
          ushort l0 = f2bf(xn0 - bf2f(h0)), l1 = f2bf(xn1 - bf2f(h1));
          ((uint32_t*)(opl + (size_t)j * DIN))[c2] =
              (uint32_t)l0 | ((uint32_t)l1 << 16);
        }
        acc[t][0] += xn0;
        acc[t][1] += xn1;
      }
    }
  }
#pragma unroll
  for (int t = 0; t < T2; ++t) {
    int c2 = lane + 64 * t;
    if (c2 < P2) {
      int c = 2 * c2;
      part[((size_t)b * DIN + c) * WPB + w]     = acc[t][0];
      part[((size_t)b * DIN + c + 1) * WPB + w] = acc[t][1];
    }
  }
}

// ---------------------------------------------------------------------------
// scores_k: FUSED per-batch score pipeline. When CMP, also emits per-batch
// compacted column list (ranks unique -> deterministic), compacted bias, and
// gathered compacted weight rows (hi, and lo when GLO) of length RLEN.
// ---------------------------------------------------------------------------
template<int DIN, int DOUT, int SLOTS, bool CMP, int CMPN, int RLEN, bool GLO>
__global__ __launch_bounds__(1024)
void scores_k(const float* __restrict__ part,
              const float* __restrict__ Wt, const float* __restrict__ bias,
              const float* __restrict__ W1, const float* __restrict__ b1,
              const float* __restrict__ W2, const float* __restrict__ b2,
              float* __restrict__ mask, int k,
              const ushort* __restrict__ whi, const ushort* __restrict__ wlo,
              ushort* __restrict__ wch, ushort* __restrict__ wcl,
              int* __restrict__ list_g, float* __restrict__ biasc)
{
  constexpr int DH  = DOUT / 4;
  constexpr int DH4 = DH / 4;
  constexpr int NSLC = (1024 / DH4 < 64) ? 1024 / DH4 : 64;
  constexpr int RPSC = (DOUT + NSLC - 1) / NSLC;
  constexpr int C4  = DOUT / 4;
  constexpr int NSLD = (1024 / C4 < 64) ? 1024 / C4 : 64;
  constexpr int RPSD = (DH + NSLD - 1) / NSLD;

  __shared__ float xm[DIN];
  __shared__ float st[DOUT];
  __shared__ float h[DH];
  __shared__ float sc[DOUT];
  __shared__ float red[4096];
  __shared__ int lsh[256];

  const int b = blockIdx.x, tid = threadIdx.x;

  if constexpr (SLOTS == 25) {
    if (tid < DIN) {
      const float* p = part + ((size_t)b * DIN + tid) * 25;
      float s = 0.f;
#pragma unroll
      for (int i = 0; i < 25; ++i) s += p[i];
      xm[tid] = s * (1.f / (float)NTOK);
    }
  } else {
    const int cg = tid >> 2, wq = tid & 3;
    if (cg < DIN) {
      const float* p = part + ((size_t)b * DIN + cg) * WPB + wq * 56;
      f32x4 a = {0.f, 0.f, 0.f, 0.f};
#pragma unroll
      for (int u = 0; u < 14; ++u) {
        f32x4 t0 = *(const f32x4*)(p + u * 4);
        a[0] += t0[0]; a[1] += t0[1]; a[2] += t0[2]; a[3] += t0[3];
      }
      red[wq * DIN + cg] = (a[0] + a[1]) + (a[2] + a[3]);
    }
    __syncthreads();
    if (tid < DIN)
      xm[tid] = ((red[0 * DIN + tid] + red[1 * DIN + tid]) +
                 (red[2 * DIN + tid] + red[3 * DIN + tid])) * (1.f / (float)NTOK);
  }
  __syncthreads();

  {
    constexpr int RPS = DIN / 4;
    const int j4 = tid % C4, sl = tid / C4;
    if (sl < 4) {
      const float* wp = Wt + (size_t)(sl * RPS) * DOUT + j4 * 4;
      f32x4 acc = {0.f, 0.f, 0.f, 0.f};
#pragma unroll
      for (int r = 0; r < RPS; ++r) {
        f32x4 wv = *(const f32x4*)(wp + (size_t)r * DOUT);
        float xv = xm[sl * RPS + r];
        acc[0] = fmaf(xv, wv[0], acc[0]);
        acc[1] = fmaf(xv, wv[1], acc[1]);
        acc[2] = fmaf(xv, wv[2], acc[2]);
        acc[3] = fmaf(xv, wv[3], acc[3]);
      }
      *(f32x4*)&red[sl * DOUT + j4 * 4] = acc;
    }
  }
  __syncthreads();
  if (tid < DOUT)
    st[tid] = ((red[0 * DOUT + tid] + red[1 * DOUT + tid]) +
               (red[2 * DOUT + tid] + red[3 * DOUT + tid])) + bias[tid];
  __syncthreads();

  {
    const int j4 = tid % DH4, sl = tid / DH4;
    if (sl < NSLC) {
      f32x4 acc = {0.f, 0.f, 0.f, 0.f};
#pragma unroll
      for (int rr = 0; rr < RPSC; ++rr) {
        int r = sl * RPSC + rr;
        if (r < DOUT) {
          f32x4 wv = *(const f32x4*)(W1 + (size_t)r * DH + j4 * 4);
          float sv = st[r];
          acc[0] = fmaf(sv, wv[0], acc[0]);
          acc[1] = fmaf(sv, wv[1], acc[1]);
          acc[2] = fmaf(sv, wv[2], acc[2]);
          acc[3] = fmaf(sv, wv[3], acc[3]);
        }
      }
      *(f32x4*)&red[(size_t)sl * DH + j4 * 4] = acc;
    }
  }
  __syncthreads();
  if (tid < DH) {
    float a = 0.f;
#pragma unroll 4
    for (int sl = 0; sl < NSLC; ++sl) a += red[(size_t)sl * DH + tid];
    h[tid] = fmaxf(b1[tid] + a, 0.f);
  }
  __syncthreads();

  {
    const int c4 = tid % C4, sl = tid / C4;
    if (sl < NSLD) {
      f32x4 acc = {0.f, 0.f, 0.f, 0.f};
#pragma unroll
      for (int rr = 0; rr < RPSD; ++rr) {
        int r = sl * RPSD + rr;
        if (r < DH) {
          f32x4 wv = *(const f32x4*)(W2 + (size_t)r * DOUT + c4 * 4);
          float hv = h[r];
          acc[0] = fmaf(hv, wv[0], acc[0]);
          acc[1] = fmaf(hv, wv[1], acc[1]);
          acc[2] = fmaf(hv, wv[2], acc[2]);
          acc[3] = fmaf(hv, wv[3], acc[3]);
        }
      }
      *(f32x4*)&red[(size_t)sl * DOUT + c4 * 4] = acc;
    }
  }
  __syncthreads();
  for (int c = tid; c < DOUT; c += 1024) {
    float a = 0.f;
#pragma unroll 4
    for (int sl = 0; sl < NSLD; ++sl) a += red[(size_t)sl * DOUT + c];
    sc[c] = b2[c] + a;
  }
  __syncthreads();

  // stable rank -> mask (+ compacted list when CMP)
  for (int c = tid; c < DOUT; c += 1024) {
    float v = sc[c];
    int rank = 0;
#pragma unroll 8
    for (int j = 0; j < DOUT; ++j) {
      float u = sc[j];
      rank += (u > v) || (u == v && j < c);
    }
    mask[(size_t)b * DOUT + c] = (rank < k) ? 1.f : 0.f;
    if (CMP && rank < k) lsh[rank] = c;
  }
  if constexpr (CMP) {
    if (tid >= k && tid < CMPN) lsh[tid] = -1;
    __syncthreads();
    if (tid < CMPN) {
      int c = lsh[tid];
      list_g[b * 256 + tid] = c;
      biasc[b * 256 + tid] = (c >= 0) ? bias[c] : 0.f;
    }
    constexpr int U4 = RLEN / 8;
    for (int idx = tid; idx < CMPN * U4; idx += 1024) {
      int j = idx / U4, u = idx - j * U4;
      int src = lsh[j];
      uint4 v = make_uint4(0u, 0u, 0u, 0u);
      if (src >= 0) v = *(const uint4*)(whi + (size_t)src * RLEN + u * 8);
      *(uint4*)(wch + ((size_t)b * CMPN + j) * RLEN + u * 8) = v;
      if constexpr (GLO) {
        uint4 vl = make_uint4(0u, 0u, 0u, 0u);
        if (src >= 0) vl = *(const uint4*)(wlo + (size_t)src * RLEN + u * 8);
        *(uint4*)(wcl + ((size_t)b * CMPN + j) * RLEN + u * 8) = vl;
      }
    }
  }
}

// ---------------------------------------------------------------------------
// All 4 stages' W [K][N] fp32 -> hi/lo bf16 [Npad][K].
// ---------------------------------------------------------------------------
__global__ __launch_bounds__(256)
void convW_all_k(const float* __restrict__ W0, const float* __restrict__ W1,
                 const float* __restrict__ W2, const float* __restrict__ W3,
                 ushort* __restrict__ hi, ushort* __restrict__ lo)
{
  const int Kd[4]   = { 96, 96, 192, 384 };
  const int Nd[4]   = { 96, 192, 384, 768 };
  const int off[5]  = { 0, 12288, 36864, 110592, 405504 };
  const float* Wp[4] = { W0, W1, W2, W3 };

  int idx = blockIdx.x * 256 + threadIdx.x;
  if (idx >= 405504) return;
  int s = (idx >= off[1]) + (idx >= off[2]) + (idx >= off[3]);
  int local = idx - off[s];
  int K = Kd[s], N = Nd[s];
  int n = local / K, kk = local - n * K;
  float v = (n < N) ? Wp[s][(size_t)kk * N + n] : 0.f;
  ushort h = f2bf(v);
  hi[idx] = h;
  lo[idx] = f2bf(v - bf2f(h));
}

#define ASYNC16(GP, LP) __builtin_amdgcn_global_load_lds( \
    (const __attribute__((address_space(1))) void*)(GP),  \
    (__attribute__((address_space(3))) void*)(LP), 16, 0, 0)

// ---------------------------------------------------------------------------
// FUSED-SEGMENT GEMM + bias + mask + LN-for-next-stage + colsum epilogue.
// Per k-step stage ALL FOUR tiles (Ahi, Alo, Whi, Wlo) once, then 3 MFMA
// passes (Ah·Bh, Ah·Bl, Al·Bh) against the same LDS. Double-buffered 2-phase:
// issue STAGE(t+1), compute t from LDS, vmcnt(0)+barrier (own-loads drained
// BEFORE barrier -> cross-wave safe). Barriers: K/32 (was 3*K/32).
// Epilogue identical to round-14 (known good), LDS aliased into buffers.
// ---------------------------------------------------------------------------
template<int K, int BNL, int N, int NWN, bool WLO>
__global__ __launch_bounds__(128 * NWN)
void gemm_ln_k(const ushort* __restrict__ ahi, const ushort* __restrict__ alo,
               const ushort* __restrict__ bhi, const ushort* __restrict__ blo,
               const float* __restrict__ bias, const float* __restrict__ msk,
               const float* __restrict__ gnext, const float* __restrict__ bnext,
               ushort* __restrict__ oh, ushort* __restrict__ ol,
               float* __restrict__ part)
{
  constexpr int T   = 128 * NWN;
  constexpr int R   = T / 4;
  constexpr int AI  = 128 / R;
  constexpr int BI  = BNL / R;
  constexpr int KS  = K / 32;
  constexpr int WN  = N / NWN;
  constexpr int NFR = WN / 16;
  __shared__ __align__(16) ushort ldsAh[2][128 * 32];
  __shared__ __align__(16) ushort ldsAl[2][128 * 32];
  __shared__ __align__(16) ushort ldsBh[2][BNL * 32];
  __shared__ __align__(16) ushort ldsBl[2][BNL * 32];

  const int tid  = threadIdx.x;
  const int lane = tid & 63;
  const int wid  = tid >> 6;
  const int wm = wid & 1, wn = wid >> 1;

  const int q8  = gridDim.x >> 3;
  const int bid = blockIdx.x;
  const int mt  = (bid & 7) * q8 + (bid >> 3);
  const size_t row0 = (size_t)mt * 128;

  f32x4 acc[4][NFR];
#pragma unroll
  for (int i = 0; i < 4; ++i)
#pragma unroll
    for (int j = 0; j < NFR; ++j) acc[i][j] = { 0.f, 0.f, 0.f, 0.f };

  const int c_row  = tid >> 2;
  const int c_phys = tid & 3;

#define STG(BUF, KK)                                                           \
  {                                                                            \
    const int k0_ = (KK) * 32;                                                 \
    _Pragma("unroll")                                                          \
    for (int r_ = 0; r_ < AI; ++r_) {                                          \
      int row_  = c_row + r_ * R;                                              \
      int slot_ = c_phys ^ ((row_ >> 1) & 3);                                  \
      ASYNC16(ahi + (row0 + row_) * (size_t)K + (k0_ + slot_ * 8),             \
              &ldsAh[BUF][(row_ * 4 + c_phys) * 8]);                           \
      ASYNC16(alo + (row0 + row_) * (size_t)K + (k0_ + slot_ * 8),             \
              &ldsAl[BUF][(row_ * 4 + c_phys) * 8]);                           \
    }                                                                          \
    _Pragma("unroll")                                                          \
    for (int r_ = 0; r_ < BI; ++r_) {                                          \
      int row_  = c_row + r_ * R;                                              \
      int slot_ = c_phys ^ ((row_ >> 1) & 3);                                  \
      ASYNC16(bhi + (size_t)row_ * K + (k0_ + slot_ * 8),                      \
              &ldsBh[BUF][(row_ * 4 + c_phys) * 8]);                           \
      ASYNC16(blo + (size_t)row_ * K + (k0_ + slot_ * 8),                      \
              &ldsBl[BUF][(row_ * 4 + c_phys) * 8]);                           \
    }                                                                          \
  }

  STG(0, 0);
  asm volatile("s_waitcnt vmcnt(0)" ::: "memory");
  __builtin_amdgcn_s_barrier();
#pragma unroll
  for (int t = 0; t < KS; ++t) {
    if (t + 1 < KS) STG((t + 1) & 1, t + 1);
    const int buf = t & 1;
    const int slot = lane >> 4;
    const int r16  = lane & 15;
    bf16x8 ah[4], al[4], bh[NFR], bl[NFR];
#pragma unroll
    for (int mi = 0; mi < 4; ++mi) {
      int r = wm * 64 + mi * 16 + r16;
      int off = (r * 4 + (slot ^ ((r >> 1) & 3))) * 8;
      ah[mi] = *(const bf16x8*)&ldsAh[buf][off];
      al[mi] = *(const bf16x8*)&ldsAl[buf][off];
    }
#pragma unroll
    for (int ni = 0; ni < NFR; ++ni) {
      int r = wn * WN + ni * 16 + r16;
      int off = (r * 4 + (slot ^ ((r >> 1) & 3))) * 8;
      bh[ni] = *(const bf16x8*)&ldsBh[buf][off];
      bl[ni] = *(const bf16x8*)&ldsBl[buf][off];
    }
#pragma unroll
    for (int mi = 0; mi < 4; ++mi)
#pragma unroll
      for (int ni = 0; ni < NFR; ++ni)
        acc[mi][ni] = __builtin_amdgcn_mfma_f32_16x16x32_bf16(ah[mi], bh[ni],
                                                              acc[mi][ni], 0, 0, 0);
#pragma unroll
    for (int mi = 0; mi < 4; ++mi)
#pragma unroll
      for (int ni = 0; ni < NFR; ++ni)
        acc[mi][ni] = __builtin_amdgcn_mfma_f32_16x16x32_bf16(ah[mi], bl[ni],
                                                              acc[mi][ni], 0, 0, 0);
#pragma unroll
    for (int mi = 0; mi < 4; ++mi)
#pragma unroll
      for (int ni = 0; ni < NFR; ++ni)
        acc[mi][ni] = __builtin_amdgcn_mfma_f32_16x16x32_bf16(al[mi], bh[ni],
                                                              acc[mi][ni], 0, 0, 0);
    if (t + 1 < KS) {
      asm volatile("s_waitcnt vmcnt(0)" ::: "memory");
      __builtin_amdgcn_s_barrier();
    }
  }
#undef STG

  // ---------------- fused epilogue (round-14 logic, aliased LDS) -----------
  __syncthreads();

  float* rowred = (float*)&ldsAh[0][0];   // [NWN][128][2]
  float* colred = (float*)&ldsAl[0][0];   // [2sets][2wm][N]
  ushort* xsh = (ushort*)&ldsBh[0][0];    // [32][N]
  ushort* xsl = (ushort*)&ldsBl[0][0];    // [32][N] if WLO

  const int l15 = lane & 15, l4 = lane >> 4;
  const int b0i = (int)(row0 / NTOK);
  const size_t rowB = (size_t)(b0i + 1) * NTOK;
  const bool strad = rowB < row0 + 128;

  float biasv[NFR], mk0a[NFR], mk1a[NFR], gvn[NFR], bvn[NFR];
#pragma unroll
  for (int ni = 0; ni < NFR; ++ni) {
    int n = wn * WN + ni * 16 + l15;
    biasv[ni] = bias[n];
    mk0a[ni] = msk[(size_t)b0i * N + n];
    mk1a[ni] = strad ? msk[(size_t)(b0i + 1) * N + n] : mk0a[ni];
    gvn[ni] = gnext[n];
    bvn[ni] = bnext[n];
  }

  float rs[16], rq[16];
#pragma unroll
  for (int i = 0; i < 16; ++i) { rs[i] = 0.f; rq[i] = 0.f; }
#pragma unroll
  for (int mi = 0; mi < 4; ++mi)
#pragma unroll
    for (int q = 0; q < 4; ++q) {
      size_t row = row0 + wm * 64 + mi * 16 + l4 * 4 + q;
      bool loB = row < rowB;
#pragma unroll
      for (int ni = 0; ni < NFR; ++ni) {
        float v = (acc[mi][ni][q] + biasv[ni]) * (loB ? mk0a[ni] : mk1a[ni]);
        acc[mi][ni][q] = v;
        rs[mi * 4 + q] += v;
        rq[mi * 4 + q] += v * v;
      }
    }
#pragma unroll
  for (int off = 1; off < 16; off <<= 1)
#pragma unroll
    for (int i = 0; i < 16; ++i) {
      rs[i] += __shfl_xor(rs[i], off);
      rq[i] += __shfl_xor(rq[i], off);
    }
  if (l15 == 0) {
#pragma unroll
    for (int mi = 0; mi < 4; ++mi)
#pragma unroll
      for (int q = 0; q < 4; ++q) {
        int r = wm * 64 + mi * 16 + l4 * 4 + q;
        rowred[(wn * 128 + r) * 2 + 0] = rs[mi * 4 + q];
        rowred[(wn * 128 + r) * 2 + 1] = rq[mi * 4 + q];
      }
  }
  __syncthreads();

  float mean[16], rstd[16];
#pragma unroll
  for (int mi = 0; mi < 4; ++mi)
#pragma unroll
    for (int q = 0; q < 4; ++q) {
      int r = wm * 64 + mi * 16 + l4 * 4 + q;
      float S = 0.f, Q = 0.f;
#pragma unroll
      for (int w = 0; w < NWN; ++w) {
        S += rowred[(w * 128 + r) * 2 + 0];
        Q += rowred[(w * 128 + r) * 2 + 1];
      }
      float mn  = S / (float)N;
      float var = Q / (float)N - mn * mn;
      mean[mi * 4 + q] = mn;
      rstd[mi * 4 + q] = 1.f / sqrtf(var + 1e-5f);
    }

  float cs0[NFR], cs1[NFR];
#pragma unroll
  for (int ni = 0; ni < NFR; ++ni) { cs0[ni] = 0.f; cs1[ni] = 0.f; }
#pragma unroll
  for (int mi = 0; mi < 4; ++mi) {
    __syncthreads();
#pragma unroll
    for (int q = 0; q < 4; ++q) {
      const int rl = l4 * 4 + q;
      const size_t row = row0 + wm * 64 + mi * 16 + rl;
      const bool loB = row < rowB;
      const float mn = mean[mi * 4 + q], rv = rstd[mi * 4 + q];
#pragma unroll
      for (int ni = 0; ni < NFR; ++ni) {
        const int n = wn * WN + ni * 16 + l15;
        float xn = (acc[mi][ni][q] - mn) * rv * gvn[ni] + bvn[ni];
        ushort hh = f2bf(xn);
        xsh[(wm * 16 + rl) * N + n] = hh;
        if constexpr (WLO) xsl[(wm * 16 + rl) * N + n] = f2bf(xn - bf2f(hh));
        if (loB) cs0[ni] += xn; else cs1[ni] += xn;
      }
    }
    __syncthreads();
    constexpr int U4R = N / 8;
    for (int idx = tid; idx < 32 * U4R; idx += T) {
      const int grp = idx / U4R, c = idx - grp * U4R;
      const size_t row = row0 + (grp >> 4) * 64 + mi * 16 + (grp & 15);
      *(uint4*)(oh + row * (size_t)N + c * 8) =
          *(const uint4*)(xsh + grp * N + c * 8);
      if constexpr (WLO)
        *(uint4*)(ol + row * (size_t)N + c * 8) =
            *(const uint4*)(xsl + grp * N + c * 8);
    }
  }

#pragma unroll
  for (int ni = 0; ni < NFR; ++ni) {
    cs0[ni] += __shfl_xor(cs0[ni], 16);
    cs0[ni] += __shfl_xor(cs0[ni], 32);
    cs1[ni] += __shfl_xor(cs1[ni], 16);
    cs1[ni] += __shfl_xor(cs1[ni], 32);
  }
  __syncthreads();
  if (l4 == 0) {
#pragma unroll
    for (int ni = 0; ni < NFR; ++ni) {
      int n = wn * WN + ni * 16 + l15;
      colred[(0 * 2 + wm) * N + n] = cs0[ni];
      colred[(1 * 2 + wm) * N + n] = cs1[ni];
    }
  }
  __syncthreads();
  if (wm == 0 && l4 == 0) {
    const int mt_lo = (b0i * NTOK) >> 7;
    const int slot0 = mt - mt_lo;
#pragma unroll
    for (int ni = 0; ni < NFR; ++ni) {
      int n = wn * WN + ni * 16 + l15;
      float t0 = colred[0 * N + n] + colred[1 * N + n];
      part[((size_t)b0i * N + n) * 25 + slot0] = t0;
      if (strad) {
        float t1 = colred[2 * N + n] + colred[3 * N + n];
        part[((size_t)(b0i + 1) * N + n) * 25 + 0] = t1;
      }
    }
  }
}

// ---------------------------------------------------------------------------
// Stage-3 COMPACT GEMM + LN epilogue, fused-segment 2-phase K-loop.
// Per-batch m-tiles (25/batch, last 64 valid rows). Block = 128 rows x
// NC=192 ACTIVE cols, 256 thr. Barriers: K/32 = 6 (was 18). Epilogue
// unchanged from round-14 (known good), scratch aliased into buffers.
// ---------------------------------------------------------------------------
template<int K, int NC, int N>
__global__ __launch_bounds__(256)
void gemm_lnc_k(const ushort* __restrict__ ahi, const ushort* __restrict__ alo,
                const ushort* __restrict__ wch, const ushort* __restrict__ wcl,
                const int* __restrict__ list, const float* __restrict__ biasc,
                const float* __restrict__ gnext, const float* __restrict__ bnext,
                ushort* __restrict__ oh, float* __restrict__ part)
{
  constexpr int KS  = K / 32;          // 6
  constexpr int WN  = NC / 2;          // 96
  constexpr int NFR = WN / 16;         // 6
  __shared__ __align__(16) ushort ldsAh[2][128 * 32];
  __shared__ __align__(16) ushort ldsAl[2][128 * 32];
  __shared__ __align__(16) ushort ldsBh[2][NC * 32];
  __shared__ __align__(16) ushort ldsBl[2][NC * 32];

  const int tid  = threadIdx.x;
  const int lane = tid & 63;
  const int wid  = tid >> 6;
  const int wm = wid & 1, wn = wid >> 1;

  const int q8  = gridDim.x >> 3;
  const int bid = blockIdx.x;
  const int wg  = (bid & 7) * q8 + (bid >> 3);
  const int b   = wg / 25;
  const int mt  = wg - b * 25;
  const size_t row0 = (size_t)b * NTOK + (size_t)mt * 128;
  const size_t rowEnd = (size_t)(b + 1) * NTOK;
  const int rows_valid = (mt == 24) ? 64 : 128;

  const ushort* bph = wch + (size_t)b * NC * K;
  const ushort* bpl = wcl + (size_t)b * NC * K;

  f32x4 acc[4][NFR];
#pragma unroll
  for (int i = 0; i < 4; ++i)
#pragma unroll
    for (int j = 0; j < NFR; ++j) acc[i][j] = { 0.f, 0.f, 0.f, 0.f };

  const int c_row  = tid >> 2;     // 0..63
  const int c_phys = tid & 3;

#define STGL(BUF, KK)                                                          \
  {                                                                            \
    const int k0_ = (KK) * 32;                                                 \
    _Pragma("unroll")                                                          \
    for (int r_ = 0; r_ < 2; ++r_) {                                           \
      int row_  = c_row + r_ * 64;                                             \
      int slot_ = c_phys ^ ((row_ >> 1) & 3);                                  \
      size_t ar_ = row0 + row_;                                                \
      if (ar_ >= rowEnd) ar_ = rowEnd - 1;                                     \
      ASYNC16(ahi + ar_ * (size_t)K + (k0_ + slot_ * 8),                       \
              &ldsAh[BUF][(row_ * 4 + c_phys) * 8]);                           \
      ASYNC16(alo + ar_ * (size_t)K + (k0_ + slot_ * 8),                       \
              &ldsAl[BUF][(row_ * 4 + c_phys) * 8]);                           \
    }                                                                          \
    _Pragma("unroll")                                                          \
    for (int r_ = 0; r_ < 3; ++r_) {                                           \
      int row_  = c_row + r_ * 64;                                             \
      int slot_ = c_phys ^ ((row_ >> 1) & 3);                                  \
      ASYNC16(bph + (size_t)row_ * K + (k0_ + slot_ * 8),                      \
              &ldsBh[BUF][(row_ * 4 + c_phys) * 8]);                           \
      ASYNC16(bpl + (size_t)row_ * K + (k0_ + slot_ * 8),                      \
              &ldsBl[BUF][(row_ * 4 + c_phys) * 8]);                           \
    }                                                                          \
  }

  STGL(0, 0);
  asm volatile("s_waitcnt vmcnt(0)" ::: "memory");
  __builtin_amdgcn_s_barrier();
#pragma unroll
  for (int t = 0; t < KS; ++t) {
    if (t + 1 < KS) STGL((t + 1) & 1, t + 1);
    const int buf = t & 1;
    const int slot = lane >> 4;
    const int r16  = lane & 15;
    bf16x8 ah[4], al[4], bh[NFR], bl[NFR];
#pragma unroll
    for (int mi = 0; mi < 4; ++mi) {
      int r = wm * 64 + mi * 16 + r16;
      int off = (r * 4 + (slot ^ ((r >> 1) & 3))) * 8;
      ah[mi] = *(const bf16x8*)&ldsAh[buf][off];
      al[mi] = *(const bf16x8*)&ldsAl[buf][off];
    }
#pragma unroll
    for (int ni = 0; ni < NFR; ++ni) {
      int r = wn * WN + ni * 16 + r16;
      int off = (r * 4 + (slot ^ ((r >> 1) & 3))) * 8;
      bh[ni] = *(const bf16x8*)&ldsBh[buf][off];
      bl[ni] = *(const bf16x8*)&ldsBl[buf][off];
    }
#pragma unroll
    for (int mi = 0; mi < 4; ++mi)
#pragma unroll
      for (int ni = 0; ni < NFR; ++ni)
        acc[mi][ni] = __builtin_amdgcn_mfma_f32_16x16x32_bf16(ah[mi], bh[ni],
                                                              acc[mi][ni], 0, 0, 0);
#pragma unroll
    for (int mi = 0; mi < 4; ++mi)
#pragma unroll
      for (int ni = 0; ni < NFR; ++ni)
        acc[mi][ni] = __builtin_amdgcn_mfma_f32_16x16x32_bf16(ah[mi], bl[ni],
                                                              acc[mi][ni], 0, 0, 0);
#pragma unroll
    for (int mi = 0; mi < 4; ++mi)
#pragma unroll
      for (int ni = 0; ni < NFR; ++ni)
        acc[mi][ni] = __builtin_amdgcn_mfma_f32_16x16x32_bf16(al[mi], bh[ni],
                                                              acc[mi][ni], 0, 0, 0);
    if (t + 1 < KS) {
      asm volatile("s_waitcnt vmcnt(0)" ::: "memory");
      __builtin_amdgcn_s_barrier();
    }
  }
#undef STGL

  // ---------------- compact-LN epilogue (round-14 logic) -------------------
  __syncthreads();

  float* rr      = (float*)&ldsAh[0][0];
  float* rowredp = rr;                   // [2][128][2] = 512 floats
  float* rowmnrv = rr + 512;             // [128]
  float* rowrv   = rr + 640;             // [128]
  float* sbuf    = (float*)&ldsBh[0][0]; // [16][N] fp32 = 24 KB

  const int l15 = lane & 15, l4 = lane >> 4;

  int   nj[NFR];
  float biasv[NFR];
#pragma unroll
  for (int ni = 0; ni < NFR; ++ni) {
    int j = wn * WN + ni * 16 + l15;
    nj[ni]    = list[b * 256 + j];       // always >= 0 (k == NC == 192)
    biasv[ni] = biasc[b * 256 + j];
  }

  float rs[16], rq[16];
#pragma unroll
  for (int i = 0; i < 16; ++i) { rs[i] = 0.f; rq[i] = 0.f; }
#pragma unroll
  for (int mi = 0; mi < 4; ++mi)
#pragma unroll
    for (int q = 0; q < 4; ++q) {
#pragma unroll
      for (int ni = 0; ni < NFR; ++ni) {
        float v = acc[mi][ni][q] + biasv[ni];
        acc[mi][ni][q] = v;
        rs[mi * 4 + q] += v;
        rq[mi * 4 + q] += v * v;
      }
    }
#pragma unroll
  for (int off = 1; off < 16; off <<= 1)
#pragma unroll
    for (int i = 0; i < 16; ++i) {
      rs[i] += __shfl_xor(rs[i], off);
      rq[i] += __shfl_xor(rq[i], off);
    }
  if (l15 == 0) {
#pragma unroll
    for (int mi = 0; mi < 4; ++mi)
#pragma unroll
      for (int q = 0; q < 4; ++q) {
        int r = wm * 64 + mi * 16 + l4 * 4 + q;
        rowredp[(wn * 128 + r) * 2 + 0] = rs[mi * 4 + q];
        rowredp[(wn * 128 + r) * 2 + 1] = rq[mi * 4 + q];
      }
  }
  __syncthreads();
  if (tid < 128) {
    float S = rowredp[(0 * 128 + tid) * 2 + 0] + rowredp[(1 * 128 + tid) * 2 + 0];
    float Q = rowredp[(0 * 128 + tid) * 2 + 1] + rowredp[(1 * 128 + tid) * 2 + 1];
    float mn = S / (float)N;
    float rv = 1.f / sqrtf(Q / (float)N - mn * mn + 1e-5f);
    rowmnrv[tid] = mn * rv;
    rowrv[tid]   = rv;
  }
  __syncthreads();

  float colS = 0.f, colS2 = 0.f;         // cols tid and 256+tid

#pragma unroll
  for (int h = 0; h < 8; ++h) {
    if (h * 16 >= rows_valid) break;
    __syncthreads();
    for (int idx = tid; idx < 16 * N / 4; idx += 256)
      ((f32x4*)sbuf)[idx] = f32x4{0.f, 0.f, 0.f, 0.f};
    __syncthreads();
    if ((h >> 2) == wm) {
      const int mi = h & 3;
#pragma unroll
      for (int q = 0; q < 4; ++q) {
        const int rl = l4 * 4 + q;
        const float rv = rowrv[h * 16 + rl];
#pragma unroll
        for (int ni = 0; ni < NFR; ++ni)
          sbuf[rl * N + nj[ni]] = acc[mi][ni][q] * rv;
      }
    }
    __syncthreads();
    {
      float a = 0.f;
#pragma unroll
      for (int rl = 0; rl < 16; ++rl) a += sbuf[rl * N + tid];
      colS += a;
      if (tid < N - 256) {
        float a2 = 0.f;
        const int c2 = 256 + tid;
#pragma unroll
        for (int rl = 0; rl < 16; ++rl) a2 += sbuf[rl * N + c2];
        colS2 += a2;
      }
    }
    for (int idx = tid; idx < 16 * (N / 8); idx += 256) {
      const int rl = idx / (N / 8), cg = idx - rl * (N / 8);
      const float mnrv = rowmnrv[h * 16 + rl];
      const float* sp = sbuf + rl * N + cg * 8;
      f32x4 s0 = *(const f32x4*)(sp);
      f32x4 s1 = *(const f32x4*)(sp + 4);
      f32x4 g0 = *(const f32x4*)(gnext + cg * 8);
      f32x4 g1 = *(const f32x4*)(gnext + cg * 8 + 4);
      f32x4 e0 = *(const f32x4*)(bnext + cg * 8);
      f32x4 e1 = *(const f32x4*)(bnext + cg * 8 + 4);
      uint32_t w[4];
#pragma unroll
      for (int j = 0; j < 2; ++j) {
        ushort ha = f2bf(g0[2*j]   * (s0[2*j]   - mnrv) + e0[2*j]);
        ushort hb = f2bf(g0[2*j+1] * (s0[2*j+1] - mnrv) + e0[2*j+1]);
        w[j] = (uint32_t)ha | ((uint32_t)hb << 16);
      }
#pragma unroll
      for (int j = 0; j < 2; ++j) {
        ushort ha = f2bf(g1[2*j]   * (s1[2*j]   - mnrv) + e1[2*j]);
        ushort hb = f2bf(g1[2*j+1] * (s1[2*j+1] - mnrv) + e1[2*j+1]);
        w[2 + j] = (uint32_t)ha | ((uint32_t)hb << 16);
      }
      *(uint4*)(oh + (row0 + h * 16 + rl) * (size_t)N + cg * 8) =
          make_uint4(w[0], w[1], w[2], w[3]);
    }
  }

  float msum = 0.f;
  for (int r = 0; r < rows_valid; ++r) msum += rowmnrv[r];
  {
    const int c = tid;
    part[((size_t)b * N + c) * 25 + mt] =
        gnext[c] * (colS - msum) + (float)rows_valid * bnext[c];
    if (tid < N - 256) {
      const int c2 = 256 + tid;
      part[((size_t)b * N + c2) * 25 + mt] =
          gnext[c2] * (colS2 - msum) + (float)rows_valid * bnext[c2];
    }
  }
}

// ---------------------------------------------------------------------------
// Stage-4 COMPACTED GEMM (round-13, known good): per-batch m-tiles, 128 rows
// x 256 compacted cols, 512 thr, vmcnt(3), scatter epilogue.
// ---------------------------------------------------------------------------
template<int K>
__global__ __launch_bounds__(512)
void gemm_c4_k(const ushort* __restrict__ A, const ushort* __restrict__ Wc,
               const int* __restrict__ list, const float* __restrict__ biasc,
               float* __restrict__ C)
{
  constexpr int NT = K / 32;       // 12
  __shared__ __align__(16) ushort ldsA[3][128 * 32];
  __shared__ __align__(16) ushort ldsB[3][256 * 32];   // 48 KB; reused as cst

  const int tid  = threadIdx.x;
  const int lane = tid & 63;
  const int wid  = tid >> 6;
  const int wm = wid & 1, wn = wid >> 1;          // wn in 0..3

  const int q8  = gridDim.x >> 3;
  const int bid = blockIdx.x;
  const int wg  = (bid & 7) * q8 + (bid >> 3);
  const int b   = wg / 25;
  const int mt  = wg - b * 25;
  const size_t row0 = (size_t)b * NTOK + (size_t)mt * 128;
  const int rows_valid = (mt == 24) ? 64 : 128;

  const ushort* bp = Wc + (size_t)b * 256 * K;

  const int c_row  = tid >> 2;     // 0..127
  const int c_phys = tid & 3;

  size_t arow = row0 + c_row;
  const size_t rowEnd = (size_t)(b + 1) * NTOK;
  if (arow >= rowEnd) arow = rowEnd - 1;
  const ushort* apr = A + arow * (size_t)K;

  f32x4 acc[4][4];
#pragma unroll
  for (int i = 0; i < 4; ++i)
#pragma unroll
    for (int j = 0; j < 4; ++j) acc[i][j] = { 0.f, 0.f, 0.f, 0.f };

#define STAGEC(BUF, TT)                                                        \
  {                                                                            \
    const int k0_ = (TT) * 32;                                                 \
    {                                                                          \
      int slot_ = c_phys ^ ((c_row >> 1) & 3);                                 \
      ASYNC16(apr + (k0_ + slot_ * 8),                                         \
              &ldsA[BUF][(c_row * 4 + c_phys) * 8]);                           \
    }                                                                          \
    _Pragma("unroll")                                                          \
    for (int r_ = 0; r_ < 2; ++r_) {                                           \
      int row_  = c_row + r_ * 128;                                            \
      int slot_ = c_phys ^ ((row_ >> 1) & 3);                                  \
      ASYNC16(bp + (size_t)row_ * K + (k0_ + slot_ * 8),                       \
              &ldsB[BUF][(row_ * 4 + c_phys) * 8]);                            \
    }                                                                          \
  }

  STAGEC(0, 0);
  STAGEC(1, 1);
#pragma unroll
  for (int t = 0; t < NT; ++t) {
    if (t == NT - 1) { asm volatile("s_waitcnt vmcnt(0)" ::: "memory"); }
    else             { asm volatile("s_waitcnt vmcnt(3)" ::: "memory"); }
    __builtin_amdgcn_s_barrier();
    if (t + 2 < NT) STAGEC((t + 2) % 3, t + 2);
    const int buf = t % 3;
    const int slot = lane >> 4;
    const int r16  = lane & 15;
    bf16x8 af[4], bfr[4];
#pragma unroll
    for (int mi = 0; mi < 4; ++mi) {
      int r = wm * 64 + mi * 16 + r16;
      af[mi] = *(const bf16x8*)&ldsA[buf][(r * 4 + (slot ^ ((r >> 1) & 3))) * 8];
    }
#pragma unroll
    for (int ni = 0; ni < 4; ++ni) {
      int r = wn * 64 + ni * 16 + r16;
      bfr[ni] = *(const bf16x8*)&ldsB[buf][(r * 4 + (slot ^ ((r >> 1) & 3))) * 8];
    }
#pragma unroll
    for (int mi = 0; mi < 4; ++mi)
#pragma unroll
      for (int ni = 0; ni < 4; ++ni)
        acc[mi][ni] = __builtin_amdgcn_mfma_f32_16x16x32_bf16(af[mi], bfr[ni],
                                                              acc[mi][ni], 0, 0, 0);
  }
#undef STAGEC

  float* cst = (float*)&ldsB[0][0];      // [16][768] fp32

  const int l15 = lane & 15, l4 = lane >> 4;
  int   nj[4];
  float biasv[4];
#pragma unroll
  for (int ni = 0; ni < 4; ++ni) {
    int j = wn * 64 + ni * 16 + l15;
    nj[ni]    = list[b * 256 + j];
    biasv[ni] = biasc[b * 256 + j];
  }

#pragma unroll
  for (int hh = 0; hh < 8; ++hh) {
    const int hrows = rows_valid - hh * 16;
    if (hrows <= 0) break;
    __syncthreads();
    for (int idx = tid; idx < 16 * 192; idx += 512)
      ((f32x4*)cst)[idx] = f32x4{0.f, 0.f, 0.f, 0.f};
    __syncthreads();
    if ((hh >> 2) == wm) {
      const int mi = hh & 3;
#pragma unroll
      for (int q = 0; q < 4; ++q) {
        const int rl = l4 * 4 + q;
#pragma unroll
        for (int ni = 0; ni < 4; ++ni)
          if (nj[ni] >= 0)
            cst[rl * 768 + nj[ni]] = acc[mi][ni][q] + biasv[ni];
      }
    }
    __syncthreads();
    const int nst = (hrows >= 16 ? 16 : hrows) * 192;
    for (int idx = tid; idx < nst; idx += 512) {
      const int grp = idx / 192, c = idx - grp * 192;
      const size_t row = row0 + hh * 16 + grp;
      *(f32x4*)(C + row * 768 + c * 4) = ((const f32x4*)cst)[grp * 192 + c];
    }
  }
}

// ---------------------------------------------------------------------------
extern "C" void kernel_launch(void* const* d_in, const int* in_sizes, int n_in,
                              void* d_out, int out_size, void* d_ws, size_t ws_size,
                              hipStream_t stream)
{
  (void)in_sizes; (void)n_in; (void)out_size; (void)ws_size;
  const float* x = (const float*)d_in[0];
  const float *sg[4], *sb[4], *sW[4], *sbias[4], *pW1[4], *pb1[4], *pW2[4], *pb2[4];
  for (int s = 0; s < 4; ++s) {
    int base = 1 + s * 8;
    sg[s]    = (const float*)d_in[base + 0];
    sb[s]    = (const float*)d_in[base + 1];
    sW[s]    = (const float*)d_in[base + 2];
    sbias[s] = (const float*)d_in[base + 3];
    pW1[s]   = (const float*)d_in[base + 4];
    pb1[s]   = (const float*)d_in[base + 5];
    pW2[s]   = (const float*)d_in[base + 6];
    pb2[s]   = (const float*)d_in[base + 7];
  }

  float* out = (float*)d_out;
  ushort* hiA = (ushort*)out;                    // x̃1 (M*96) then x̃3 (M*192)
  ushort* loA = (ushort*)(out + 19267584);       // lo1 then lo3
  ushort* loB = (ushort*)(out + 38535168);       // lo2 (M*192)

  char* ws = (char*)d_ws;
  ushort* hiB  = (ushort*)(ws);                  // x̃2 (M*192) then x̃4 (M*384)
  float*  part = (float*) (ws + 77070336);
  float*  mk   = (float*) (ws + 79822848);
  ushort* w_hi = (ushort*)(ws + 79921152);       // 811,008
  ushort* w_lo = (ushort*)(ws + 80732160);       // 811,008
  ushort* wc   = (ushort*)(ws + 81543168);       // 6,291,456 B capacity
  int*    lst  = (int*)   (ws + 87834624);       // 32,768
  float*  bsc  = (float*) (ws + 87867392);       // 32,768 -> end 87,900,160

  ushort* wch3 = wc;                              // 32*192*192 elems
  ushort* wcl3 = wc + 1179648;

  const int woff[4] = { 0, 12288, 36864, 110592 };

  convW_all_k<<<(405504 + 255) / 256, 256, 0, stream>>>(
      sW[0], sW[1], sW[2], sW[3], w_hi, w_lo);

  const int LNG = 32 * WPB / 4;

  // ---- stage 1: LN1, scores1, fused gemm1+LN2
  ln_colsum_k<96, true><<<LNG, 256, 0, stream>>>(x, sg[0], sb[0], hiA, loA, part);
  scores_k<96, 96, 224, false, 256, 384, false><<<32, 1024, 0, stream>>>(
      part, sW[0], sbias[0], pW1[0], pb1[0], pW2[0], pb2[0], mk, 86,
      nullptr, nullptr, nullptr, nullptr, nullptr, nullptr);
  gemm_ln_k<96, 128, 96, 2, true><<<784, 256, 0, stream>>>(
      hiA, loA, w_hi + woff[0], w_lo + woff[0],
      sbias[0], mk, sg[1], sb[1], hiB, loB, part);

  // ---- stage 2: scores2, fused gemm2+LN3
  scores_k<96, 192, 25, false, 256, 384, false><<<32, 1024, 0, stream>>>(
      part, sW[1], sbias[1], pW1[1], pb1[1], pW2[1], pb2[1], mk, 134,
      nullptr, nullptr, nullptr, nullptr, nullptr, nullptr);
  gemm_ln_k<96, 192, 192, 2, true><<<784, 256, 0, stream>>>(
      hiB, loB, w_hi + woff[1], w_lo + woff[1],
      sbias[1], mk, sg[2], sb[2], hiA, loA, part);

  // ---- stage 3: scores3 (+hi/lo compaction, k=192), compact gemm3+LN4
  scores_k<192, 384, 25, true, 192, 192, true><<<32, 1024, 0, stream>>>(
      part, sW[2], sbias[2], pW1[2], pb1[2], pW2[2], pb2[2], mk, 192,
      w_hi + woff[2], w_lo + woff[2], wch3, wcl3, lst, bsc);
  gemm_lnc_k<192, 192, 384><<<800, 256, 0, stream>>>(
      hiA, loA, wch3, wcl3, lst, bsc, sg[3], sb[3], hiB, part);

  // ---- stage 4: scores4 (+compaction), compacted GEMM -> d_out
  scores_k<384, 768, 25, true, 256, 384, false><<<32, 1024, 0, stream>>>(
      part, sW[3], sbias[3], pW1[3], pb1[3], pW2[3], pb2[3], mk, 230,
      w_hi + woff[3], nullptr, wc, nullptr, lst, bsc);
  gemm_c4_k<384><<<800, 512, 0, stream>>>(hiB, wc, lst, bsc, out);
}

// Round 16
// 452.913 us; speedup vs baseline: 1.3083x; 1.0199x over previous
//
#include <hip/hip_runtime.h>
#include <hip/hip_bf16.h>
#include <stdint.h>

#define NTOK 3136
#define MTOT 100352
#define RPW  14          // rows per LN wave (stage-1 LN only)
#define WPB  224         // LN waves per batch (NTOK/RPW)

typedef __attribute__((ext_vector_type(8))) short bf16x8;
typedef __attribute__((ext_vector_type(4))) float f32x4;
typedef __attribute__((ext_vector_type(2))) float f32x2;

static __device__ __forceinline__ ushort f2bf(float x) {
  union { float f; uint32_t u; } c; c.f = x;
  uint32_t r = (c.u + 0x7FFFu + ((c.u >> 16) & 1u)) >> 16;   // RNE
  return (ushort)r;
}
static __device__ __forceinline__ float bf2f(ushort h) {
  union { uint32_t u; float f; } c; c.u = ((uint32_t)h) << 16;
  return c.f;
}

// ---------------------------------------------------------------------------
// Stage-1 LayerNorm (reads fp32 x) + fp32 column partial sums.
// part layout: [b][c][WPB].
// ---------------------------------------------------------------------------
template<int DIN, bool WLO>
__global__ __launch_bounds__(256)
void ln_colsum_k(const float* __restrict__ in, const float* __restrict__ gma,
                 const float* __restrict__ bta, ushort* __restrict__ oh,
                 ushort* __restrict__ ol, float* __restrict__ part)
{
  constexpr int P2 = DIN / 2;
  constexpr int T2 = (P2 + 63) / 64;
  const int wid  = (blockIdx.x * 256 + threadIdx.x) >> 6;
  const int lane = threadIdx.x & 63;
  const int b = wid / WPB;
  const int w = wid - b * WPB;

  f32x2 gv[T2], bv[T2], acc[T2];
#pragma unroll
  for (int t = 0; t < T2; ++t) {
    int c2 = lane + 64 * t;
    if (c2 < P2) {
      gv[t] = *(const f32x2*)(gma + 2 * c2);
      bv[t] = *(const f32x2*)(bta + 2 * c2);
    } else { gv[t] = {0.f, 0.f}; bv[t] = {0.f, 0.f}; }
    acc[t] = {0.f, 0.f};
  }

  const size_t rbase = ((size_t)b * NTOK + (size_t)w * RPW) * DIN;
  const float* ip = in + rbase;
  ushort* oph = oh + rbase;
  ushort* opl = ol + rbase;

  for (int j = 0; j < RPW; ++j) {
    f32x2 v[T2];
    float s = 0.f, sq = 0.f;
#pragma unroll
    for (int t = 0; t < T2; ++t) {
      int c2 = lane + 64 * t;
      f32x2 xv = {0.f, 0.f};
      if (c2 < P2) xv = *(const f32x2*)(ip + (size_t)j * DIN + 2 * c2);
      v[t] = xv;
      s  += xv[0] + xv[1];
      sq += xv[0] * xv[0] + xv[1] * xv[1];
    }
#pragma unroll
    for (int off = 1; off < 64; off <<= 1) {
      s  += __shfl_xor(s, off);
      sq += __shfl_xor(sq, off);
    }
    float m   = s / (float)DIN;
    float var = sq / (float)DIN - m * m;
    float r   = 1.f / sqrtf(var + 1e-5f);
#pragma unroll
    for (int t = 0; t < T2; ++t) {
      int c2 = lane + 64 * t;
      if (c2 < P2) {
        float xn0 = (v[t][0] - m) * r * gv[t][0] + bv[t][0];
        float xn1 = (v[t][1] - m) * r * gv[t][1] + bv[t][1];
        ushort h0 = f2bf(xn0), h1 = f2bf(xn1);
        ((uint32_t*)(oph + (size_t)j * DIN))[c2] =
            (uint32_t)h0 | ((uint32_t)h1 << 16);
        if (WLO) {
          ushort l0 = f2bf(xn0 - bf2f(h0)), l1 = f2bf(xn1 - bf2f(h1));
          ((uint32_t*)(opl + (size_t)j * DIN))[c2] =
              (uint32_t)l0 | ((uint32_t)l1 << 16);
        }
        acc[t][0] += xn0;
        acc[t][1] += xn1;
      }
    }
  }
#pragma unroll
  for (int t = 0; t < T2; ++t) {
    int c2 = lane + 64 * t;
    if (c2 < P2) {
      int c = 2 * c2;
      part[((size_t)b * DIN + c) * WPB + w]     = acc[t][0];
      part[((size_t)b * DIN + c + 1) * WPB + w] = acc[t][1];
    }
  }
}

// ---------------------------------------------------------------------------
// scores_k: FUSED per-batch score pipeline. When CMP, also emits per-batch
// compacted column list (ranks unique -> deterministic) + compacted bias.
// (Weight gathering now happens inside the consuming GEMMs via list[].)
// ---------------------------------------------------------------------------
template<int DIN, int DOUT, int SLOTS, bool CMP, int CMPN>
__global__ __launch_bounds__(1024)
void scores_k(const float* __restrict__ part,
              const float* __restrict__ Wt, const float* __restrict__ bias,
              const float* __restrict__ W1, const float* __restrict__ b1,
              const float* __restrict__ W2, const float* __restrict__ b2,
              float* __restrict__ mask, int k,
              int* __restrict__ list_g, float* __restrict__ biasc)
{
  constexpr int DH  = DOUT / 4;
  constexpr int DH4 = DH / 4;
  constexpr int NSLC = (1024 / DH4 < 64) ? 1024 / DH4 : 64;
  constexpr int RPSC = (DOUT + NSLC - 1) / NSLC;
  constexpr int C4  = DOUT / 4;
  constexpr int NSLD = (1024 / C4 < 64) ? 1024 / C4 : 64;
  constexpr int RPSD = (DH + NSLD - 1) / NSLD;

  __shared__ float xm[DIN];
  __shared__ float st[DOUT];
  __shared__ float h[DH];
  __shared__ float sc[DOUT];
  __shared__ float red[4096];
  __shared__ int lsh[256];

  const int b = blockIdx.x, tid = threadIdx.x;

  if constexpr (SLOTS == 25) {
    if (tid < DIN) {
      const float* p = part + ((size_t)b * DIN + tid) * 25;
      float s = 0.f;
#pragma unroll
      for (int i = 0; i < 25; ++i) s += p[i];
      xm[tid] = s * (1.f / (float)NTOK);
    }
  } else {
    const int cg = tid >> 2, wq = tid & 3;
    if (cg < DIN) {
      const float* p = part + ((size_t)b * DIN + cg) * WPB + wq * 56;
      f32x4 a = {0.f, 0.f, 0.f, 0.f};
#pragma unroll
      for (int u = 0; u < 14; ++u) {
        f32x4 t0 = *(const f32x4*)(p + u * 4);
        a[0] += t0[0]; a[1] += t0[1]; a[2] += t0[2]; a[3] += t0[3];
      }
      red[wq * DIN + cg] = (a[0] + a[1]) + (a[2] + a[3]);
    }
    __syncthreads();
    if (tid < DIN)
      xm[tid] = ((red[0 * DIN + tid] + red[1 * DIN + tid]) +
                 (red[2 * DIN + tid] + red[3 * DIN + tid])) * (1.f / (float)NTOK);
  }
  __syncthreads();

  {
    constexpr int RPS = DIN / 4;
    const int j4 = tid % C4, sl = tid / C4;
    if (sl < 4) {
      const float* wp = Wt + (size_t)(sl * RPS) * DOUT + j4 * 4;
      f32x4 acc = {0.f, 0.f, 0.f, 0.f};
#pragma unroll
      for (int r = 0; r < RPS; ++r) {
        f32x4 wv = *(const f32x4*)(wp + (size_t)r * DOUT);
        float xv = xm[sl * RPS + r];
        acc[0] = fmaf(xv, wv[0], acc[0]);
        acc[1] = fmaf(xv, wv[1], acc[1]);
        acc[2] = fmaf(xv, wv[2], acc[2]);
        acc[3] = fmaf(xv, wv[3], acc[3]);
      }
      *(f32x4*)&red[sl * DOUT + j4 * 4] = acc;
    }
  }
  __syncthreads();
  if (tid < DOUT)
    st[tid] = ((red[0 * DOUT + tid] + red[1 * DOUT + tid]) +
               (red[2 * DOUT + tid] + red[3 * DOUT + tid])) + bias[tid];
  __syncthreads();

  {
    const int j4 = tid % DH4, sl = tid / DH4;
    if (sl < NSLC) {
      f32x4 acc = {0.f, 0.f, 0.f, 0.f};
#pragma unroll
      for (int rr = 0; rr < RPSC; ++rr) {
        int r = sl * RPSC + rr;
        if (r < DOUT) {
          f32x4 wv = *(const f32x4*)(W1 + (size_t)r * DH + j4 * 4);
          float sv = st[r];
          acc[0] = fmaf(sv, wv[0], acc[0]);
          acc[1] = fmaf(sv, wv[1], acc[1]);
          acc[2] = fmaf(sv, wv[2], acc[2]);
          acc[3] = fmaf(sv, wv[3], acc[3]);
        }
      }
      *(f32x4*)&red[(size_t)sl * DH + j4 * 4] = acc;
    }
  }
  __syncthreads();
  if (tid < DH) {
    float a = 0.f;
#pragma unroll 4
    for (int sl = 0; sl < NSLC; ++sl) a += red[(size_t)sl * DH + tid];
    h[tid] = fmaxf(b1[tid] + a, 0.f);
  }
  __syncthreads();

  {
    const int c4 = tid % C4, sl = tid / C4;
    if (sl < NSLD) {
      f32x4 acc = {0.f, 0.f, 0.f, 0.f};
#pragma unroll
      for (int rr = 0; rr < RPSD; ++rr) {
        int r = sl * RPSD + rr;
        if (r < DH) {
          f32x4 wv = *(const f32x4*)(W2 + (size_t)r * DOUT + c4 * 4);
          float hv = h[r];
          acc[0] = fmaf(hv, wv[0], acc[0]);
          acc[1] = fmaf(hv, wv[1], acc[1]);
          acc[2] = fmaf(hv, wv[2], acc[2]);
          acc[3] = fmaf(hv, wv[3], acc[3]);
        }
      }
      *(f32x4*)&red[(size_t)sl * DOUT + c4 * 4] = acc;
    }
  }
  __syncthreads();
  for (int c = tid; c < DOUT; c += 1024) {
    float a = 0.f;
#pragma unroll 4
    for (int sl = 0; sl < NSLD; ++sl) a += red[(size_t)sl * DOUT + c];
    sc[c] = b2[c] + a;
  }
  __syncthreads();

  for (int c = tid; c < DOUT; c += 1024) {
    float v = sc[c];
    int rank = 0;
#pragma unroll 8
    for (int j = 0; j < DOUT; ++j) {
      float u = sc[j];
      rank += (u > v) || (u == v && j < c);
    }
    mask[(size_t)b * DOUT + c] = (rank < k) ? 1.f : 0.f;
    if (CMP && rank < k) lsh[rank] = c;
  }
  if constexpr (CMP) {
    if (tid >= k && tid < CMPN) lsh[tid] = -1;
    __syncthreads();
    if (tid < CMPN) {
      int c = lsh[tid];
      list_g[b * 256 + tid] = c;
      biasc[b * 256 + tid] = (c >= 0) ? bias[c] : 0.f;
    }
  }
}

// ---------------------------------------------------------------------------
// All 4 stages' W [K][N] fp32 -> hi/lo bf16 [Npad][K].
// ---------------------------------------------------------------------------
__global__ __launch_bounds__(256)
void convW_all_k(const float* __restrict__ W0, const float* __restrict__ W1,
                 const float* __restrict__ W2, const float* __restrict__ W3,
                 ushort* __restrict__ hi, ushort* __restrict__ lo)
{
  const int Kd[4]   = { 96, 96, 192, 384 };
  const int Nd[4]   = { 96, 192, 384, 768 };
  const int off[5]  = { 0, 12288, 36864, 110592, 405504 };
  const float* Wp[4] = { W0, W1, W2, W3 };

  int idx = blockIdx.x * 256 + threadIdx.x;
  if (idx >= 405504) return;
  int s = (idx >= off[1]) + (idx >= off[2]) + (idx >= off[3]);
  int local = idx - off[s];
  int K = Kd[s], N = Nd[s];
  int n = local / K, kk = local - n * K;
  float v = (n < N) ? Wp[s][(size_t)kk * N + n] : 0.f;
  ushort h = f2bf(v);
  hi[idx] = h;
  lo[idx] = f2bf(v - bf2f(h));
}

#define ASYNC16(GP, LP) __builtin_amdgcn_global_load_lds( \
    (const __attribute__((address_space(1))) void*)(GP),  \
    (__attribute__((address_space(3))) void*)(LP), 16, 0, 0)

// ---------------------------------------------------------------------------
// FUSED-SEGMENT GEMM + bias + mask + LN-for-next-stage + colsum epilogue.
// SINGLE-buffered K-loop (KS=3): {issue loads, vmcnt(0)+barrier, 3 MFMA
// passes, barrier}. LDS halves to 32/40 KB -> 4-5 blocks/CU; inter-block
// TLP hides load latency and the epilogue barriers. Epilogue = round-15.
// ---------------------------------------------------------------------------
template<int K, int BNL, int N, int NWN, bool WLO>
__global__ __launch_bounds__(128 * NWN)
void gemm_ln_k(const ushort* __restrict__ ahi, const ushort* __restrict__ alo,
               const ushort* __restrict__ bhi, const ushort* __restrict__ blo,
               const float* __restrict__ bias, const float* __restrict__ msk,
               const float* __restrict__ gnext, const float* __restrict__ bnext,
               ushort* __restrict__ oh, ushort* __restrict__ ol,
               float* __restrict__ part)
{
  constexpr int T   = 128 * NWN;
  constexpr int R   = T / 4;
  constexpr int AI  = 128 / R;
  constexpr int BI  = BNL / R;
  constexpr int KS  = K / 32;
  constexpr int WN  = N / NWN;
  constexpr int NFR = WN / 16;
  __shared__ __align__(16) ushort ldsAh[128 * 32];
  __shared__ __align__(16) ushort ldsAl[128 * 32];
  __shared__ __align__(16) ushort ldsBh[BNL * 32];
  __shared__ __align__(16) ushort ldsBl[BNL * 32];

  const int tid  = threadIdx.x;
  const int lane = tid & 63;
  const int wid  = tid >> 6;
  const int wm = wid & 1, wn = wid >> 1;

  const int q8  = gridDim.x >> 3;
  const int bid = blockIdx.x;
  const int mt  = (bid & 7) * q8 + (bid >> 3);
  const size_t row0 = (size_t)mt * 128;

  f32x4 acc[4][NFR];
#pragma unroll
  for (int i = 0; i < 4; ++i)
#pragma unroll
    for (int j = 0; j < NFR; ++j) acc[i][j] = { 0.f, 0.f, 0.f, 0.f };

  const int c_row  = tid >> 2;
  const int c_phys = tid & 3;

#define STG(KK)                                                                \
  {                                                                            \
    const int k0_ = (KK) * 32;                                                 \
    _Pragma("unroll")                                                          \
    for (int r_ = 0; r_ < AI; ++r_) {                                          \
      int row_  = c_row + r_ * R;                                              \
      int slot_ = c_phys ^ ((row_ >> 1) & 3);                                  \
      ASYNC16(ahi + (row0 + row_) * (size_t)K + (k0_ + slot_ * 8),             \
              &ldsAh[(row_ * 4 + c_phys) * 8]);                                \
      ASYNC16(alo + (row0 + row_) * (size_t)K + (k0_ + slot_ * 8),             \
              &ldsAl[(row_ * 4 + c_phys) * 8]);                                \
    }                                                                          \
    _Pragma("unroll")                                                          \
    for (int r_ = 0; r_ < BI; ++r_) {                                          \
      int row_  = c_row + r_ * R;                                              \
      int slot_ = c_phys ^ ((row_ >> 1) & 3);                                  \
      ASYNC16(bhi + (size_t)row_ * K + (k0_ + slot_ * 8),                      \
              &ldsBh[(row_ * 4 + c_phys) * 8]);                                \
      ASYNC16(blo + (size_t)row_ * K + (k0_ + slot_ * 8),                      \
              &ldsBl[(row_ * 4 + c_phys) * 8]);                                \
    }                                                                          \
  }

#pragma unroll
  for (int t = 0; t < KS; ++t) {
    STG(t);
    asm volatile("s_waitcnt vmcnt(0)" ::: "memory");
    __builtin_amdgcn_s_barrier();
    const int slot = lane >> 4;
    const int r16  = lane & 15;
    bf16x8 ah[4], al[4], bh[NFR], bl[NFR];
#pragma unroll
    for (int mi = 0; mi < 4; ++mi) {
      int r = wm * 64 + mi * 16 + r16;
      int off = (r * 4 + (slot ^ ((r >> 1) & 3))) * 8;
      ah[mi] = *(const bf16x8*)&ldsAh[off];
      al[mi] = *(const bf16x8*)&ldsAl[off];
    }
#pragma unroll
    for (int ni = 0; ni < NFR; ++ni) {
      int r = wn * WN + ni * 16 + r16;
      int off = (r * 4 + (slot ^ ((r >> 1) & 3))) * 8;
      bh[ni] = *(const bf16x8*)&ldsBh[off];
      bl[ni] = *(const bf16x8*)&ldsBl[off];
    }
#pragma unroll
    for (int mi = 0; mi < 4; ++mi)
#pragma unroll
      for (int ni = 0; ni < NFR; ++ni)
        acc[mi][ni] = __builtin_amdgcn_mfma_f32_16x16x32_bf16(ah[mi], bh[ni],
                                                              acc[mi][ni], 0, 0, 0);
#pragma unroll
    for (int mi = 0; mi < 4; ++mi)
#pragma unroll
      for (int ni = 0; ni < NFR; ++ni)
        acc[mi][ni] = __builtin_amdgcn_mfma_f32_16x16x32_bf16(ah[mi], bl[ni],
                                                              acc[mi][ni], 0, 0, 0);
#pragma unroll
    for (int mi = 0; mi < 4; ++mi)
#pragma unroll
      for (int ni = 0; ni < NFR; ++ni)
        acc[mi][ni] = __builtin_amdgcn_mfma_f32_16x16x32_bf16(al[mi], bh[ni],
                                                              acc[mi][ni], 0, 0, 0);
    if (t + 1 < KS) __builtin_amdgcn_s_barrier();
  }
#undef STG

  // ---------------- fused epilogue (round-15 logic, aliased LDS) -----------
  __syncthreads();

  float* rowred = (float*)&ldsAh[0];     // [NWN][128][2]  (2 KB)
  float* colred = (float*)&ldsAl[0];     // [2sets][2wm][N]
  ushort* xsh = (ushort*)&ldsBh[0];      // [32][N]
  ushort* xsl = (ushort*)&ldsBl[0];      // [32][N] if WLO

  const int l15 = lane & 15, l4 = lane >> 4;
  const int b0i = (int)(row0 / NTOK);
  const size_t rowB = (size_t)(b0i + 1) * NTOK;
  const bool strad = rowB < row0 + 128;

  float biasv[NFR], mk0a[NFR], mk1a[NFR], gvn[NFR], bvn[NFR];
#pragma unroll
  for (int ni = 0; ni < NFR; ++ni) {
    int n = wn * WN + ni * 16 + l15;
    biasv[ni] = bias[n];
    mk0a[ni] = msk[(size_t)b0i * N + n];
    mk1a[ni] = strad ? msk[(size_t)(b0i + 1) * N + n] : mk0a[ni];
    gvn[ni] = gnext[n];
    bvn[ni] = bnext[n];
  }

  float rs[16], rq[16];
#pragma unroll
  for (int i = 0; i < 16; ++i) { rs[i] = 0.f; rq[i] = 0.f; }
#pragma unroll
  for (int mi = 0; mi < 4; ++mi)
#pragma unroll
    for (int q = 0; q < 4; ++q) {
      size_t row = row0 + wm * 64 + mi * 16 + l4 * 4 + q;
      bool loB = row < rowB;
#pragma unroll
      for (int ni = 0; ni < NFR; ++ni) {
        float v = (acc[mi][ni][q] + biasv[ni]) * (loB ? mk0a[ni] : mk1a[ni]);
        acc[mi][ni][q] = v;
        rs[mi * 4 + q] += v;
        rq[mi * 4 + q] += v * v;
      }
    }
#pragma unroll
  for (int off = 1; off < 16; off <<= 1)
#pragma unroll
    for (int i = 0; i < 16; ++i) {
      rs[i] += __shfl_xor(rs[i], off);
      rq[i] += __shfl_xor(rq[i], off);
    }
  if (l15 == 0) {
#pragma unroll
    for (int mi = 0; mi < 4; ++mi)
#pragma unroll
      for (int q = 0; q < 4; ++q) {
        int r = wm * 64 + mi * 16 + l4 * 4 + q;
        rowred[(wn * 128 + r) * 2 + 0] = rs[mi * 4 + q];
        rowred[(wn * 128 + r) * 2 + 1] = rq[mi * 4 + q];
      }
  }
  __syncthreads();

  float mean[16], rstd[16];
#pragma unroll
  for (int mi = 0; mi < 4; ++mi)
#pragma unroll
    for (int q = 0; q < 4; ++q) {
      int r = wm * 64 + mi * 16 + l4 * 4 + q;
      float S = 0.f, Q = 0.f;
#pragma unroll
      for (int w = 0; w < NWN; ++w) {
        S += rowred[(w * 128 + r) * 2 + 0];
        Q += rowred[(w * 128 + r) * 2 + 1];
      }
      float mn  = S / (float)N;
      float var = Q / (float)N - mn * mn;
      mean[mi * 4 + q] = mn;
      rstd[mi * 4 + q] = 1.f / sqrtf(var + 1e-5f);
    }

  float cs0[NFR], cs1[NFR];
#pragma unroll
  for (int ni = 0; ni < NFR; ++ni) { cs0[ni] = 0.f; cs1[ni] = 0.f; }
#pragma unroll
  for (int mi = 0; mi < 4; ++mi) {
    __syncthreads();
#pragma unroll
    for (int q = 0; q < 4; ++q) {
      const int rl = l4 * 4 + q;
      const size_t row = row0 + wm * 64 + mi * 16 + rl;
      const bool loB = row < rowB;
      const float mn = mean[mi * 4 + q], rv = rstd[mi * 4 + q];
#pragma unroll
      for (int ni = 0; ni < NFR; ++ni) {
        const int n = wn * WN + ni * 16 + l15;
        float xn = (acc[mi][ni][q] - mn) * rv * gvn[ni] + bvn[ni];
        ushort hh = f2bf(xn);
        xsh[(wm * 16 + rl) * N + n] = hh;
        if constexpr (WLO) xsl[(wm * 16 + rl) * N + n] = f2bf(xn - bf2f(hh));
        if (loB) cs0[ni] += xn; else cs1[ni] += xn;
      }
    }
    __syncthreads();
    constexpr int U4R = N / 8;
    for (int idx = tid; idx < 32 * U4R; idx += T) {
      const int grp = idx / U4R, c = idx - grp * U4R;
      const size_t row = row0 + (grp >> 4) * 64 + mi * 16 + (grp & 15);
      *(uint4*)(oh + row * (size_t)N + c * 8) =
          *(const uint4*)(xsh + grp * N + c * 8);
      if constexpr (WLO)
        *(uint4*)(ol + row * (size_t)N + c * 8) =
            *(const uint4*)(xsl + grp * N + c * 8);
    }
  }

#pragma unroll
  for (int ni = 0; ni < NFR; ++ni) {
    cs0[ni] += __shfl_xor(cs0[ni], 16);
    cs0[ni] += __shfl_xor(cs0[ni], 32);
    cs1[ni] += __shfl_xor(cs1[ni], 16);
    cs1[ni] += __shfl_xor(cs1[ni], 32);
  }
  __syncthreads();
  if (l4 == 0) {
#pragma unroll
    for (int ni = 0; ni < NFR; ++ni) {
      int n = wn * WN + ni * 16 + l15;
      colred[(0 * 2 + wm) * N + n] = cs0[ni];
      colred[(1 * 2 + wm) * N + n] = cs1[ni];
    }
  }
  __syncthreads();
  if (wm == 0 && l4 == 0) {
    const int mt_lo = (b0i * NTOK) >> 7;
    const int slot0 = mt - mt_lo;
#pragma unroll
    for (int ni = 0; ni < NFR; ++ni) {
      int n = wn * WN + ni * 16 + l15;
      float t0 = colred[0 * N + n] + colred[1 * N + n];
      part[((size_t)b0i * N + n) * 25 + slot0] = t0;
      if (strad) {
        float t1 = colred[2 * N + n] + colred[3 * N + n];
        part[((size_t)(b0i + 1) * N + n) * 25 + 0] = t1;
      }
    }
  }
}

// ---------------------------------------------------------------------------
// Stage-3 COMPACT GEMM + LN epilogue (round-15 structure). B rows staged
// DIRECTLY from w_hi/w_lo via list[] indirection (L2-resident; no Wc buf).
// ---------------------------------------------------------------------------
template<int K, int NC, int N>
__global__ __launch_bounds__(256)
void gemm_lnc_k(const ushort* __restrict__ ahi, const ushort* __restrict__ alo,
                const ushort* __restrict__ whi, const ushort* __restrict__ wlo,
                const int* __restrict__ list, const float* __restrict__ biasc,
                const float* __restrict__ gnext, const float* __restrict__ bnext,
                ushort* __restrict__ oh, float* __restrict__ part)
{
  constexpr int KS  = K / 32;          // 6
  constexpr int WN  = NC / 2;          // 96
  constexpr int NFR = WN / 16;         // 6
  __shared__ __align__(16) ushort ldsAh[2][128 * 32];
  __shared__ __align__(16) ushort ldsAl[2][128 * 32];
  __shared__ __align__(16) ushort ldsBh[2][NC * 32];
  __shared__ __align__(16) ushort ldsBl[2][NC * 32];

  const int tid  = threadIdx.x;
  const int lane = tid & 63;
  const int wid  = tid >> 6;
  const int wm = wid & 1, wn = wid >> 1;

  const int q8  = gridDim.x >> 3;
  const int bid = blockIdx.x;
  const int wg  = (bid & 7) * q8 + (bid >> 3);
  const int b   = wg / 25;
  const int mt  = wg - b * 25;
  const size_t row0 = (size_t)b * NTOK + (size_t)mt * 128;
  const size_t rowEnd = (size_t)(b + 1) * NTOK;
  const int rows_valid = (mt == 24) ? 64 : 128;

  const int c_row  = tid >> 2;     // 0..63
  const int c_phys = tid & 3;

  // per-thread indirect B row sources (k == NC -> always valid; clamp safe)
  int bsrc[3];
#pragma unroll
  for (int r_ = 0; r_ < 3; ++r_) {
    int s = list[b * 256 + c_row + r_ * 64];
    bsrc[r_] = (s < 0) ? 0 : s;
  }

  f32x4 acc[4][NFR];
#pragma unroll
  for (int i = 0; i < 4; ++i)
#pragma unroll
    for (int j = 0; j < NFR; ++j) acc[i][j] = { 0.f, 0.f, 0.f, 0.f };

#define STGL(BUF, KK)                                                          \
  {                                                                            \
    const int k0_ = (KK) * 32;                                                 \
    _Pragma("unroll")                                                          \
    for (int r_ = 0; r_ < 2; ++r_) {                                           \
      int row_  = c_row + r_ * 64;                                             \
      int slot_ = c_phys ^ ((row_ >> 1) & 3);                                  \
      size_t ar_ = row0 + row_;                                                \
      if (ar_ >= rowEnd) ar_ = rowEnd - 1;                                     \
      ASYNC16(ahi + ar_ * (size_t)K + (k0_ + slot_ * 8),                       \
              &ldsAh[BUF][(row_ * 4 + c_phys) * 8]);                           \
      ASYNC16(alo + ar_ * (size_t)K + (k0_ + slot_ * 8),                       \
              &ldsAl[BUF][(row_ * 4 + c_phys) * 8]);                           \
    }                                                                          \
    _Pragma("unroll")                                                          \
    for (int r_ = 0; r_ < 3; ++r_) {                                           \
      int row_  = c_row + r_ * 64;                                             \
      int slot_ = c_phys ^ ((row_ >> 1) & 3);                                  \
      ASYNC16(whi + (size_t)bsrc[r_] * K + (k0_ + slot_ * 8),                  \
              &ldsBh[BUF][(row_ * 4 + c_phys) * 8]);                           \
      ASYNC16(wlo + (size_t)bsrc[r_] * K + (k0_ + slot_ * 8),                  \
              &ldsBl[BUF][(row_ * 4 + c_phys) * 8]);                           \
    }                                                                          \
  }

  STGL(0, 0);
  asm volatile("s_waitcnt vmcnt(0)" ::: "memory");
  __builtin_amdgcn_s_barrier();
#pragma unroll
  for (int t = 0; t < KS; ++t) {
    if (t + 1 < KS) STGL((t + 1) & 1, t + 1);
    const int buf = t & 1;
    const int slot = lane >> 4;
    const int r16  = lane & 15;
    bf16x8 ah[4], al[4], bh[NFR], bl[NFR];
#pragma unroll
    for (int mi = 0; mi < 4; ++mi) {
      int r = wm * 64 + mi * 16 + r16;
      int off = (r * 4 + (slot ^ ((r >> 1) & 3))) * 8;
      ah[mi] = *(const bf16x8*)&ldsAh[buf][off];
      al[mi] = *(const bf16x8*)&ldsAl[buf][off];
    }
#pragma unroll
    for (int ni = 0; ni < NFR; ++ni) {
      int r = wn * WN + ni * 16 + r16;
      int off = (r * 4 + (slot ^ ((r >> 1) & 3))) * 8;
      bh[ni] = *(const bf16x8*)&ldsBh[buf][off];
      bl[ni] = *(const bf16x8*)&ldsBl[buf][off];
    }
#pragma unroll
    for (int mi = 0; mi < 4; ++mi)
#pragma unroll
      for (int ni = 0; ni < NFR; ++ni)
        acc[mi][ni] = __builtin_amdgcn_mfma_f32_16x16x32_bf16(ah[mi], bh[ni],
                                                              acc[mi][ni], 0, 0, 0);
#pragma unroll
    for (int mi = 0; mi < 4; ++mi)
#pragma unroll
      for (int ni = 0; ni < NFR; ++ni)
        acc[mi][ni] = __builtin_amdgcn_mfma_f32_16x16x32_bf16(ah[mi], bl[ni],
                                                              acc[mi][ni], 0, 0, 0);
#pragma unroll
    for (int mi = 0; mi < 4; ++mi)
#pragma unroll
      for (int ni = 0; ni < NFR; ++ni)
        acc[mi][ni] = __builtin_amdgcn_mfma_f32_16x16x32_bf16(al[mi], bh[ni],
                                                              acc[mi][ni], 0, 0, 0);
    if (t + 1 < KS) {
      asm volatile("s_waitcnt vmcnt(0)" ::: "memory");
      __builtin_amdgcn_s_barrier();
    }
  }
#undef STGL

  // ---------------- compact-LN epilogue (round-15, known good) -------------
  __syncthreads();

  float* rr      = (float*)&ldsAh[0][0];
  float* rowredp = rr;                   // [2][128][2] = 512 floats
  float* rowmnrv = rr + 512;             // [128]
  float* rowrv   = rr + 640;             // [128]
  float* sbuf    = (float*)&ldsBh[0][0]; // [16][N] fp32 = 24 KB

  const int l15 = lane & 15, l4 = lane >> 4;

  int   nj[NFR];
  float biasv[NFR];
#pragma unroll
  for (int ni = 0; ni < NFR; ++ni) {
    int j = wn * WN + ni * 16 + l15;
    nj[ni]    = list[b * 256 + j];       // always >= 0 (k == NC == 192)
    biasv[ni] = biasc[b * 256 + j];
  }

  float rs[16], rq[16];
#pragma unroll
  for (int i = 0; i < 16; ++i) { rs[i] = 0.f; rq[i] = 0.f; }
#pragma unroll
  for (int mi = 0; mi < 4; ++mi)
#pragma unroll
    for (int q = 0; q < 4; ++q) {
#pragma unroll
      for (int ni = 0; ni < NFR; ++ni) {
        float v = acc[mi][ni][q] + biasv[ni];
        acc[mi][ni][q] = v;
        rs[mi * 4 + q] += v;
        rq[mi * 4 + q] += v * v;
      }
    }
#pragma unroll
  for (int off = 1; off < 16; off <<= 1)
#pragma unroll
    for (int i = 0; i < 16; ++i) {
      rs[i] += __shfl_xor(rs[i], off);
      rq[i] += __shfl_xor(rq[i], off);
    }
  if (l15 == 0) {
#pragma unroll
    for (int mi = 0; mi < 4; ++mi)
#pragma unroll
      for (int q = 0; q < 4; ++q) {
        int r = wm * 64 + mi * 16 + l4 * 4 + q;
        rowredp[(wn * 128 + r) * 2 + 0] = rs[mi * 4 + q];
        rowredp[(wn * 128 + r) * 2 + 1] = rq[mi * 4 + q];
      }
  }
  __syncthreads();
  if (tid < 128) {
    float S = rowredp[(0 * 128 + tid) * 2 + 0] + rowredp[(1 * 128 + tid) * 2 + 0];
    float Q = rowredp[(0 * 128 + tid) * 2 + 1] + rowredp[(1 * 128 + tid) * 2 + 1];
    float mn = S / (float)N;
    float rv = 1.f / sqrtf(Q / (float)N - mn * mn + 1e-5f);
    rowmnrv[tid] = mn * rv;
    rowrv[tid]   = rv;
  }
  __syncthreads();

  float colS = 0.f, colS2 = 0.f;

#pragma unroll
  for (int h = 0; h < 8; ++h) {
    if (h * 16 >= rows_valid) break;
    __syncthreads();
    for (int idx = tid; idx < 16 * N / 4; idx += 256)
      ((f32x4*)sbuf)[idx] = f32x4{0.f, 0.f, 0.f, 0.f};
    __syncthreads();
    if ((h >> 2) == wm) {
      const int mi = h & 3;
#pragma unroll
      for (int q = 0; q < 4; ++q) {
        const int rl = l4 * 4 + q;
        const float rv = rowrv[h * 16 + rl];
#pragma unroll
        for (int ni = 0; ni < NFR; ++ni)
          sbuf[rl * N + nj[ni]] = acc[mi][ni][q] * rv;
      }
    }
    __syncthreads();
    {
      float a = 0.f;
#pragma unroll
      for (int rl = 0; rl < 16; ++rl) a += sbuf[rl * N + tid];
      colS += a;
      if (tid < N - 256) {
        float a2 = 0.f;
        const int c2 = 256 + tid;
#pragma unroll
        for (int rl = 0; rl < 16; ++rl) a2 += sbuf[rl * N + c2];
        colS2 += a2;
      }
    }
    for (int idx = tid; idx < 16 * (N / 8); idx += 256) {
      const int rl = idx / (N / 8), cg = idx - rl * (N / 8);
      const float mnrv = rowmnrv[h * 16 + rl];
      const float* sp = sbuf + rl * N + cg * 8;
      f32x4 s0 = *(const f32x4*)(sp);
      f32x4 s1 = *(const f32x4*)(sp + 4);
      f32x4 g0 = *(const f32x4*)(gnext + cg * 8);
      f32x4 g1 = *(const f32x4*)(gnext + cg * 8 + 4);
      f32x4 e0 = *(const f32x4*)(bnext + cg * 8);
      f32x4 e1 = *(const f32x4*)(bnext + cg * 8 + 4);
      uint32_t w[4];
#pragma unroll
      for (int j = 0; j < 2; ++j) {
        ushort ha = f2bf(g0[2*j]   * (s0[2*j]   - mnrv) + e0[2*j]);
        ushort hb = f2bf(g0[2*j+1] * (s0[2*j+1] - mnrv) + e0[2*j+1]);
        w[j] = (uint32_t)ha | ((uint32_t)hb << 16);
      }
#pragma unroll
      for (int j = 0; j < 2; ++j) {
        ushort ha = f2bf(g1[2*j]   * (s1[2*j]   - mnrv) + e1[2*j]);
        ushort hb = f2bf(g1[2*j+1] * (s1[2*j+1] - mnrv) + e1[2*j+1]);
        w[2 + j] = (uint32_t)ha | ((uint32_t)hb << 16);
      }
      *(uint4*)(oh + (row0 + h * 16 + rl) * (size_t)N + cg * 8) =
          make_uint4(w[0], w[1], w[2], w[3]);
    }
  }

  float msum = 0.f;
  for (int r = 0; r < rows_valid; ++r) msum += rowmnrv[r];
  {
    const int c = tid;
    part[((size_t)b * N + c) * 25 + mt] =
        gnext[c] * (colS - msum) + (float)rows_valid * bnext[c];
    if (tid < N - 256) {
      const int c2 = 256 + tid;
      part[((size_t)b * N + c2) * 25 + mt] =
          gnext[c2] * (colS2 - msum) + (float)rows_valid * bnext[c2];
    }
  }
}

// ---------------------------------------------------------------------------
// Stage-4 COMPACTED GEMM (round-13 structure): per-batch m-tiles, 128 rows x
// 256 compacted cols, 512 thr, vmcnt(3). B rows staged DIRECTLY from w_hi
// via list[] indirection (clamped; inactive cols guarded by nj<0 at write).
// ---------------------------------------------------------------------------
template<int K>
__global__ __launch_bounds__(512)
void gemm_c4_k(const ushort* __restrict__ A, const ushort* __restrict__ whi,
               const int* __restrict__ list, const float* __restrict__ biasc,
               float* __restrict__ C)
{
  constexpr int NT = K / 32;       // 12
  __shared__ __align__(16) ushort ldsA[3][128 * 32];
  __shared__ __align__(16) ushort ldsB[3][256 * 32];   // 48 KB; reused as cst

  const int tid  = threadIdx.x;
  const int lane = tid & 63;
  const int wid  = tid >> 6;
  const int wm = wid & 1, wn = wid >> 1;          // wn in 0..3

  const int q8  = gridDim.x >> 3;
  const int bid = blockIdx.x;
  const int wg  = (bid & 7) * q8 + (bid >> 3);
  const int b   = wg / 25;
  const int mt  = wg - b * 25;
  const size_t row0 = (size_t)b * NTOK + (size_t)mt * 128;
  const int rows_valid = (mt == 24) ? 64 : 128;

  const int c_row  = tid >> 2;     // 0..127
  const int c_phys = tid & 3;

  size_t arow = row0 + c_row;
  const size_t rowEnd = (size_t)(b + 1) * NTOK;
  if (arow >= rowEnd) arow = rowEnd - 1;
  const ushort* apr = A + arow * (size_t)K;

  // per-thread indirect B row sources (clamped; garbage cols never stored)
  int bsrc[2];
#pragma unroll
  for (int r_ = 0; r_ < 2; ++r_) {
    int s = list[b * 256 + c_row + r_ * 128];
    bsrc[r_] = (s < 0) ? 0 : s;
  }

  f32x4 acc[4][4];
#pragma unroll
  for (int i = 0; i < 4; ++i)
#pragma unroll
    for (int j = 0; j < 4; ++j) acc[i][j] = { 0.f, 0.f, 0.f, 0.f };

#define STAGEC(BUF, TT)                                                        \
  {                                                                            \
    const int k0_ = (TT) * 32;                                                 \
    {                                                                          \
      int slot_ = c_phys ^ ((c_row >> 1) & 3);                                 \
      ASYNC16(apr + (k0_ + slot_ * 8),                                         \
              &ldsA[BUF][(c_row * 4 + c_phys) * 8]);                           \
    }                                                                          \
    _Pragma("unroll")                                                          \
    for (int r_ = 0; r_ < 2; ++r_) {                                           \
      int row_  = c_row + r_ * 128;                                            \
      int slot_ = c_phys ^ ((row_ >> 1) & 3);                                  \
      ASYNC16(whi + (size_t)bsrc[r_] * K + (k0_ + slot_ * 8),                  \
              &ldsB[BUF][(row_ * 4 + c_phys) * 8]);                            \
    }                                                                          \
  }

  STAGEC(0, 0);
  STAGEC(1, 1);
#pragma unroll
  for (int t = 0; t < NT; ++t) {
    if (t == NT - 1) { asm volatile("s_waitcnt vmcnt(0)" ::: "memory"); }
    else             { asm volatile("s_waitcnt vmcnt(3)" ::: "memory"); }
    __builtin_amdgcn_s_barrier();
    if (t + 2 < NT) STAGEC((t + 2) % 3, t + 2);
    const int buf = t % 3;
    const int slot = lane >> 4;
    const int r16  = lane & 15;
    bf16x8 af[4], bfr[4];
#pragma unroll
    for (int mi = 0; mi < 4; ++mi) {
      int r = wm * 64 + mi * 16 + r16;
      af[mi] = *(const bf16x8*)&ldsA[buf][(r * 4 + (slot ^ ((r >> 1) & 3))) * 8];
    }
#pragma unroll
    for (int ni = 0; ni < 4; ++ni) {
      int r = wn * 64 + ni * 16 + r16;
      bfr[ni] = *(const bf16x8*)&ldsB[buf][(r * 4 + (slot ^ ((r >> 1) & 3))) * 8];
    }
#pragma unroll
    for (int mi = 0; mi < 4; ++mi)
#pragma unroll
      for (int ni = 0; ni < 4; ++ni)
        acc[mi][ni] = __builtin_amdgcn_mfma_f32_16x16x32_bf16(af[mi], bfr[ni],
                                                              acc[mi][ni], 0, 0, 0);
  }
#undef STAGEC

  float* cst = (float*)&ldsB[0][0];      // [16][768] fp32

  const int l15 = lane & 15, l4 = lane >> 4;
  int   nj[4];
  float biasv[4];
#pragma unroll
  for (int ni = 0; ni < 4; ++ni) {
    int j = wn * 64 + ni * 16 + l15;
    nj[ni]    = list[b * 256 + j];
    biasv[ni] = biasc[b * 256 + j];
  }

#pragma unroll
  for (int hh = 0; hh < 8; ++hh) {
    const int hrows = rows_valid - hh * 16;
    if (hrows <= 0) break;
    __syncthreads();
    for (int idx = tid; idx < 16 * 192; idx += 512)
      ((f32x4*)cst)[idx] = f32x4{0.f, 0.f, 0.f, 0.f};
    __syncthreads();
    if ((hh >> 2) == wm) {
      const int mi = hh & 3;
#pragma unroll
      for (int q = 0; q < 4; ++q) {
        const int rl = l4 * 4 + q;
#pragma unroll
        for (int ni = 0; ni < 4; ++ni)
          if (nj[ni] >= 0)
            cst[rl * 768 + nj[ni]] = acc[mi][ni][q] + biasv[ni];
      }
    }
    __syncthreads();
    const int nst = (hrows >= 16 ? 16 : hrows) * 192;
    for (int idx = tid; idx < nst; idx += 512) {
      const int grp = idx / 192, c = idx - grp * 192;
      const size_t row = row0 + hh * 16 + grp;
      *(f32x4*)(C + row * 768 + c * 4) = ((const f32x4*)cst)[grp * 192 + c];
    }
  }
}

// ---------------------------------------------------------------------------
extern "C" void kernel_launch(void* const* d_in, const int* in_sizes, int n_in,
                              void* d_out, int out_size, void* d_ws, size_t ws_size,
                              hipStream_t stream)
{
  (void)in_sizes; (void)n_in; (void)out_size; (void)ws_size;
  const float* x = (const float*)d_in[0];
  const float *sg[4], *sb[4], *sW[4], *sbias[4], *pW1[4], *pb1[4], *pW2[4], *pb2[4];
  for (int s = 0; s < 4; ++s) {
    int base = 1 + s * 8;
    sg[s]    = (const float*)d_in[base + 0];
    sb[s]    = (const float*)d_in[base + 1];
    sW[s]    = (const float*)d_in[base + 2];
    sbias[s] = (const float*)d_in[base + 3];
    pW1[s]   = (const float*)d_in[base + 4];
    pb1[s]   = (const float*)d_in[base + 5];
    pW2[s]   = (const float*)d_in[base + 6];
    pb2[s]   = (const float*)d_in[base + 7];
  }

  float* out = (float*)d_out;
  ushort* hiA = (ushort*)out;                    // x̃1 (M*96) then x̃3 (M*192)
  ushort* loA = (ushort*)(out + 19267584);       // lo1 then lo3
  ushort* loB = (ushort*)(out + 38535168);       // lo2 (M*192)

  char* ws = (char*)d_ws;
  ushort* hiB  = (ushort*)(ws);                  // x̃2 (M*192) then x̃4 (M*384)
  float*  part = (float*) (ws + 77070336);
  float*  mk   = (float*) (ws + 79822848);
  ushort* w_hi = (ushort*)(ws + 79921152);       // 811,008
  ushort* w_lo = (ushort*)(ws + 80732160);       // 811,008
  int*    lst  = (int*)   (ws + 87834624);       // 32,768
  float*  bsc  = (float*) (ws + 87867392);       // 32,768 -> end 87,900,160

  const int woff[4] = { 0, 12288, 36864, 110592 };

  convW_all_k<<<(405504 + 255) / 256, 256, 0, stream>>>(
      sW[0], sW[1], sW[2], sW[3], w_hi, w_lo);

  const int LNG = 32 * WPB / 4;

  // ---- stage 1: LN1, scores1, fused gemm1+LN2 (single-buffer K-loop)
  ln_colsum_k<96, true><<<LNG, 256, 0, stream>>>(x, sg[0], sb[0], hiA, loA, part);
  scores_k<96, 96, 224, false, 256><<<32, 1024, 0, stream>>>(
      part, sW[0], sbias[0], pW1[0], pb1[0], pW2[0], pb2[0], mk, 86,
      nullptr, nullptr);
  gemm_ln_k<96, 128, 96, 2, true><<<784, 256, 0, stream>>>(
      hiA, loA, w_hi + woff[0], w_lo + woff[0],
      sbias[0], mk, sg[1], sb[1], hiB, loB, part);

  // ---- stage 2: scores2, fused gemm2+LN3 (single-buffer K-loop)
  scores_k<96, 192, 25, false, 256><<<32, 1024, 0, stream>>>(
      part, sW[1], sbias[1], pW1[1], pb1[1], pW2[1], pb2[1], mk, 134,
      nullptr, nullptr);
  gemm_ln_k<96, 192, 192, 2, true><<<784, 256, 0, stream>>>(
      hiB, loB, w_hi + woff[1], w_lo + woff[1],
      sbias[1], mk, sg[2], sb[2], hiA, loA, part);

  // ---- stage 3: scores3 (list+biasc only), compact gemm3+LN4 (indirect B)
  scores_k<192, 384, 25, true, 192><<<32, 1024, 0, stream>>>(
      part, sW[2], sbias[2], pW1[2], pb1[2], pW2[2], pb2[2], mk, 192,
      lst, bsc);
  gemm_lnc_k<192, 192, 384><<<800, 256, 0, stream>>>(
      hiA, loA, w_hi + woff[2], w_lo + woff[2], lst, bsc, sg[3], sb[3],
      hiB, part);

  // ---- stage 4: scores4 (list+biasc only), compacted GEMM (indirect B)
  scores_k<384, 768, 25, true, 256><<<32, 1024, 0, stream>>>(
      part, sW[3], sbias[3], pW1[3], pb1[3], pW2[3], pb2[3], mk, 230,
      lst, bsc);
  gemm_c4_k<384><<<800, 512, 0, stream>>>(hiB, w_hi + woff[3], lst, bsc, out);
}

// Round 17
// 443.220 us; speedup vs baseline: 1.3369x; 1.0219x over previous
//
#include <hip/hip_runtime.h>
#include <hip/hip_bf16.h>
#include <stdint.h>

#define NTOK 3136
#define MTOT 100352

typedef __attribute__((ext_vector_type(8))) short bf16x8;
typedef __attribute__((ext_vector_type(4))) float f32x4;
typedef __attribute__((ext_vector_type(2))) float f32x2;

static __device__ __forceinline__ ushort f2bf(float x) {
  union { float f; uint32_t u; } c; c.f = x;
  uint32_t r = (c.u + 0x7FFFu + ((c.u >> 16) & 1u)) >> 16;   // RNE
  return (ushort)r;
}
static __device__ __forceinline__ float bf2f(ushort h) {
  union { uint32_t u; float f; } c; c.u = ((uint32_t)h) << 16;
  return c.f;
}

// ---------------------------------------------------------------------------
// Stage-1 LayerNorm: 64 rows/block (3136 = 64*49, no batch straddle).
// 4 threads/row x 24 channels: lane-dense, f32x4 loads (lane-contiguous),
// packed uint4 bf16 hi/lo stores, width-4 shuffle row stats.
// Colsums via one LDS reduce -> part[b][c][49].
// ---------------------------------------------------------------------------
__global__ __launch_bounds__(256)
void ln1_k(const float* __restrict__ in, const float* __restrict__ gma,
           const float* __restrict__ bta, ushort* __restrict__ oh,
           ushort* __restrict__ ol, float* __restrict__ part)
{
  __shared__ float red[64][104];
  const int tid = threadIdx.x;
  const int g = tid >> 2, sub = tid & 3;
  const int blk = blockIdx.x;            // 0..1567
  const int b = blk / 49, t49 = blk - b * 49;
  const size_t row = (size_t)b * NTOK + (size_t)t49 * 64 + g;
  const float* ip = in + row * 96 + sub * 24;

  f32x4 v[6];
  float s = 0.f, sq = 0.f;
#pragma unroll
  for (int u = 0; u < 6; ++u) {
    v[u] = *(const f32x4*)(ip + u * 4);
    s  += (v[u][0] + v[u][1]) + (v[u][2] + v[u][3]);
    sq += (v[u][0]*v[u][0] + v[u][1]*v[u][1]) +
          (v[u][2]*v[u][2] + v[u][3]*v[u][3]);
  }
  s  += __shfl_xor(s, 1);  s  += __shfl_xor(s, 2);
  sq += __shfl_xor(sq, 1); sq += __shfl_xor(sq, 2);
  const float m   = s * (1.f / 96.f);
  const float var = sq * (1.f / 96.f) - m * m;
  const float r   = 1.f / sqrtf(var + 1e-5f);

  uint32_t hiw[12], low[12];
#pragma unroll
  for (int u = 0; u < 6; ++u) {
    f32x4 gv = *(const f32x4*)(gma + sub * 24 + u * 4);
    f32x4 bv = *(const f32x4*)(bta + sub * 24 + u * 4);
    f32x4 xn;
#pragma unroll
    for (int e = 0; e < 4; ++e) xn[e] = (v[u][e] - m) * r * gv[e] + bv[e];
    *(f32x4*)&red[g][sub * 24 + u * 4] = xn;
    ushort h0 = f2bf(xn[0]), h1 = f2bf(xn[1]);
    ushort h2 = f2bf(xn[2]), h3 = f2bf(xn[3]);
    hiw[2*u]   = (uint32_t)h0 | ((uint32_t)h1 << 16);
    hiw[2*u+1] = (uint32_t)h2 | ((uint32_t)h3 << 16);
    ushort l0 = f2bf(xn[0] - bf2f(h0)), l1 = f2bf(xn[1] - bf2f(h1));
    ushort l2 = f2bf(xn[2] - bf2f(h2)), l3 = f2bf(xn[3] - bf2f(h3));
    low[2*u]   = (uint32_t)l0 | ((uint32_t)l1 << 16);
    low[2*u+1] = (uint32_t)l2 | ((uint32_t)l3 << 16);
  }
  {
    ushort* op = oh + row * 96 + sub * 24;
    *(uint4*)(op + 0)  = make_uint4(hiw[0], hiw[1], hiw[2],  hiw[3]);
    *(uint4*)(op + 8)  = make_uint4(hiw[4], hiw[5], hiw[6],  hiw[7]);
    *(uint4*)(op + 16) = make_uint4(hiw[8], hiw[9], hiw[10], hiw[11]);
    ushort* opl = ol + row * 96 + sub * 24;
    *(uint4*)(opl + 0)  = make_uint4(low[0], low[1], low[2],  low[3]);
    *(uint4*)(opl + 8)  = make_uint4(low[4], low[5], low[6],  low[7]);
    *(uint4*)(opl + 16) = make_uint4(low[8], low[9], low[10], low[11]);
  }
  __syncthreads();
  if (tid < 96) {
    float a = 0.f;
#pragma unroll 8
    for (int g2 = 0; g2 < 64; ++g2) a += red[g2][tid];
    part[((size_t)b * 96 + tid) * 49 + t49] = a;
  }
}

// ---------------------------------------------------------------------------
// scores_k: FUSED per-batch score pipeline. part layout [b][c][SLOTS].
// When CMP, also emits compacted column list + compacted bias.
// ---------------------------------------------------------------------------
template<int DIN, int DOUT, int SLOTS, bool CMP, int CMPN>
__global__ __launch_bounds__(1024)
void scores_k(const float* __restrict__ part,
              const float* __restrict__ Wt, const float* __restrict__ bias,
              const float* __restrict__ W1, const float* __restrict__ b1,
              const float* __restrict__ W2, const float* __restrict__ b2,
              float* __restrict__ mask, int k,
              int* __restrict__ list_g, float* __restrict__ biasc)
{
  constexpr int DH  = DOUT / 4;
  constexpr int DH4 = DH / 4;
  constexpr int NSLC = (1024 / DH4 < 64) ? 1024 / DH4 : 64;
  constexpr int RPSC = (DOUT + NSLC - 1) / NSLC;
  constexpr int C4  = DOUT / 4;
  constexpr int NSLD = (1024 / C4 < 64) ? 1024 / C4 : 64;
  constexpr int RPSD = (DH + NSLD - 1) / NSLD;

  __shared__ float xm[DIN];
  __shared__ float st[DOUT];
  __shared__ float h[DH];
  __shared__ float sc[DOUT];
  __shared__ float red[4096];
  __shared__ int lsh[256];

  const int b = blockIdx.x, tid = threadIdx.x;

  if (tid < DIN) {
    const float* p = part + ((size_t)b * DIN + tid) * SLOTS;
    float s = 0.f;
#pragma unroll
    for (int i = 0; i < SLOTS; ++i) s += p[i];
    xm[tid] = s * (1.f / (float)NTOK);
  }
  __syncthreads();

  {
    constexpr int RPS = DIN / 4;
    const int j4 = tid % C4, sl = tid / C4;
    if (sl < 4) {
      const float* wp = Wt + (size_t)(sl * RPS) * DOUT + j4 * 4;
      f32x4 acc = {0.f, 0.f, 0.f, 0.f};
#pragma unroll
      for (int r = 0; r < RPS; ++r) {
        f32x4 wv = *(const f32x4*)(wp + (size_t)r * DOUT);
        float xv = xm[sl * RPS + r];
        acc[0] = fmaf(xv, wv[0], acc[0]);
        acc[1] = fmaf(xv, wv[1], acc[1]);
        acc[2] = fmaf(xv, wv[2], acc[2]);
        acc[3] = fmaf(xv, wv[3], acc[3]);
      }
      *(f32x4*)&red[sl * DOUT + j4 * 4] = acc;
    }
  }
  __syncthreads();
  if (tid < DOUT)
    st[tid] = ((red[0 * DOUT + tid] + red[1 * DOUT + tid]) +
               (red[2 * DOUT + tid] + red[3 * DOUT + tid])) + bias[tid];
  __syncthreads();

  {
    const int j4 = tid % DH4, sl = tid / DH4;
    if (sl < NSLC) {
      f32x4 acc = {0.f, 0.f, 0.f, 0.f};
#pragma unroll
      for (int rr = 0; rr < RPSC; ++rr) {
        int r = sl * RPSC + rr;
        if (r < DOUT) {
          f32x4 wv = *(const f32x4*)(W1 + (size_t)r * DH + j4 * 4);
          float sv = st[r];
          acc[0] = fmaf(sv, wv[0], acc[0]);
          acc[1] = fmaf(sv, wv[1], acc[1]);
          acc[2] = fmaf(sv, wv[2], acc[2]);
          acc[3] = fmaf(sv, wv[3], acc[3]);
        }
      }
      *(f32x4*)&red[(size_t)sl * DH + j4 * 4] = acc;
    }
  }
  __syncthreads();
  if (tid < DH) {
    float a = 0.f;
#pragma unroll 4
    for (int sl = 0; sl < NSLC; ++sl) a += red[(size_t)sl * DH + tid];
    h[tid] = fmaxf(b1[tid] + a, 0.f);
  }
  __syncthreads();

  {
    const int c4 = tid % C4, sl = tid / C4;
    if (sl < NSLD) {
      f32x4 acc = {0.f, 0.f, 0.f, 0.f};
#pragma unroll
      for (int rr = 0; rr < RPSD; ++rr) {
        int r = sl * RPSD + rr;
        if (r < DH) {
          f32x4 wv = *(const f32x4*)(W2 + (size_t)r * DOUT + c4 * 4);
          float hv = h[r];
          acc[0] = fmaf(hv, wv[0], acc[0]);
          acc[1] = fmaf(hv, wv[1], acc[1]);
          acc[2] = fmaf(hv, wv[2], acc[2]);
          acc[3] = fmaf(hv, wv[3], acc[3]);
        }
      }
      *(f32x4*)&red[(size_t)sl * DOUT + c4 * 4] = acc;
    }
  }
  __syncthreads();
  for (int c = tid; c < DOUT; c += 1024) {
    float a = 0.f;
#pragma unroll 4
    for (int sl = 0; sl < NSLD; ++sl) a += red[(size_t)sl * DOUT + c];
    sc[c] = b2[c] + a;
  }
  __syncthreads();

  for (int c = tid; c < DOUT; c += 1024) {
    float v = sc[c];
    int rank = 0;
#pragma unroll 8
    for (int j = 0; j < DOUT; ++j) {
      float u = sc[j];
      rank += (u > v) || (u == v && j < c);
    }
    mask[(size_t)b * DOUT + c] = (rank < k) ? 1.f : 0.f;
    if (CMP && rank < k) lsh[rank] = c;
  }
  if constexpr (CMP) {
    if (tid >= k && tid < CMPN) lsh[tid] = -1;
    __syncthreads();
    if (tid < CMPN) {
      int c = lsh[tid];
      list_g[b * 256 + tid] = c;
      biasc[b * 256 + tid] = (c >= 0) ? bias[c] : 0.f;
    }
  }
}

// ---------------------------------------------------------------------------
// All 4 stages' W [K][N] fp32 -> hi/lo bf16 [Npad][K].
// ---------------------------------------------------------------------------
__global__ __launch_bounds__(256)
void convW_all_k(const float* __restrict__ W0, const float* __restrict__ W1,
                 const float* __restrict__ W2, const float* __restrict__ W3,
                 ushort* __restrict__ hi, ushort* __restrict__ lo)
{
  const int Kd[4]   = { 96, 96, 192, 384 };
  const int Nd[4]   = { 96, 192, 384, 768 };
  const int off[5]  = { 0, 12288, 36864, 110592, 405504 };
  const float* Wp[4] = { W0, W1, W2, W3 };

  int idx = blockIdx.x * 256 + threadIdx.x;
  if (idx >= 405504) return;
  int s = (idx >= off[1]) + (idx >= off[2]) + (idx >= off[3]);
  int local = idx - off[s];
  int K = Kd[s], N = Nd[s];
  int n = local / K, kk = local - n * K;
  float v = (n < N) ? Wp[s][(size_t)kk * N + n] : 0.f;
  ushort h = f2bf(v);
  hi[idx] = h;
  lo[idx] = f2bf(v - bf2f(h));
}

#define ASYNC16(GP, LP) __builtin_amdgcn_global_load_lds( \
    (const __attribute__((address_space(1))) void*)(GP),  \
    (__attribute__((address_space(3))) void*)(LP), 16, 0, 0)

// ---------------------------------------------------------------------------
// FUSED-SEGMENT GEMM + bias + mask + LN-for-next-stage + colsum epilogue.
// SINGLE-buffered K-loop (KS=3). Round-16, known good. Stages 1-2.
// ---------------------------------------------------------------------------
template<int K, int BNL, int N, int NWN, bool WLO>
__global__ __launch_bounds__(128 * NWN)
void gemm_ln_k(const ushort* __restrict__ ahi, const ushort* __restrict__ alo,
               const ushort* __restrict__ bhi, const ushort* __restrict__ blo,
               const float* __restrict__ bias, const float* __restrict__ msk,
               const float* __restrict__ gnext, const float* __restrict__ bnext,
               ushort* __restrict__ oh, ushort* __restrict__ ol,
               float* __restrict__ part)
{
  constexpr int T   = 128 * NWN;
  constexpr int R   = T / 4;
  constexpr int AI  = 128 / R;
  constexpr int BI  = BNL / R;
  constexpr int KS  = K / 32;
  constexpr int WN  = N / NWN;
  constexpr int NFR = WN / 16;
  __shared__ __align__(16) ushort ldsAh[128 * 32];
  __shared__ __align__(16) ushort ldsAl[128 * 32];
  __shared__ __align__(16) ushort ldsBh[BNL * 32];
  __shared__ __align__(16) ushort ldsBl[BNL * 32];

  const int tid  = threadIdx.x;
  const int lane = tid & 63;
  const int wid  = tid >> 6;
  const int wm = wid & 1, wn = wid >> 1;

  const int q8  = gridDim.x >> 3;
  const int bid = blockIdx.x;
  const int mt  = (bid & 7) * q8 + (bid >> 3);
  const size_t row0 = (size_t)mt * 128;

  f32x4 acc[4][NFR];
#pragma unroll
  for (int i = 0; i < 4; ++i)
#pragma unroll
    for (int j = 0; j < NFR; ++j) acc[i][j] = { 0.f, 0.f, 0.f, 0.f };

  const int c_row  = tid >> 2;
  const int c_phys = tid & 3;

#define STG(KK)                                                                \
  {                                                                            \
    const int k0_ = (KK) * 32;                                                 \
    _Pragma("unroll")                                                          \
    for (int r_ = 0; r_ < AI; ++r_) {                                          \
      int row_  = c_row + r_ * R;                                              \
      int slot_ = c_phys ^ ((row_ >> 1) & 3);                                  \
      ASYNC16(ahi + (row0 + row_) * (size_t)K + (k0_ + slot_ * 8),             \
              &ldsAh[(row_ * 4 + c_phys) * 8]);                                \
      ASYNC16(alo + (row0 + row_) * (size_t)K + (k0_ + slot_ * 8),             \
              &ldsAl[(row_ * 4 + c_phys) * 8]);                                \
    }                                                                          \
    _Pragma("unroll")                                                          \
    for (int r_ = 0; r_ < BI; ++r_) {                                          \
      int row_  = c_row + r_ * R;                                              \
      int slot_ = c_phys ^ ((row_ >> 1) & 3);                                  \
      ASYNC16(bhi + (size_t)row_ * K + (k0_ + slot_ * 8),                      \
              &ldsBh[(row_ * 4 + c_phys) * 8]);                                \
      ASYNC16(blo + (size_t)row_ * K + (k0_ + slot_ * 8),                      \
              &ldsBl[(row_ * 4 + c_phys) * 8]);                                \
    }                                                                          \
  }

#pragma unroll
  for (int t = 0; t < KS; ++t) {
    STG(t);
    asm volatile("s_waitcnt vmcnt(0)" ::: "memory");
    __builtin_amdgcn_s_barrier();
    const int slot = lane >> 4;
    const int r16  = lane & 15;
    bf16x8 ah[4], al[4], bh[NFR], bl[NFR];
#pragma unroll
    for (int mi = 0; mi < 4; ++mi) {
      int r = wm * 64 + mi * 16 + r16;
      int off = (r * 4 + (slot ^ ((r >> 1) & 3))) * 8;
      ah[mi] = *(const bf16x8*)&ldsAh[off];
      al[mi] = *(const bf16x8*)&ldsAl[off];
    }
#pragma unroll
    for (int ni = 0; ni < NFR; ++ni) {
      int r = wn * WN + ni * 16 + r16;
      int off = (r * 4 + (slot ^ ((r >> 1) & 3))) * 8;
      bh[ni] = *(const bf16x8*)&ldsBh[off];
      bl[ni] = *(const bf16x8*)&ldsBl[off];
    }
#pragma unroll
    for (int mi = 0; mi < 4; ++mi)
#pragma unroll
      for (int ni = 0; ni < NFR; ++ni)
        acc[mi][ni] = __builtin_amdgcn_mfma_f32_16x16x32_bf16(ah[mi], bh[ni],
                                                              acc[mi][ni], 0, 0, 0);
#pragma unroll
    for (int mi = 0; mi < 4; ++mi)
#pragma unroll
      for (int ni = 0; ni < NFR; ++ni)
        acc[mi][ni] = __builtin_amdgcn_mfma_f32_16x16x32_bf16(ah[mi], bl[ni],
                                                              acc[mi][ni], 0, 0, 0);
#pragma unroll
    for (int mi = 0; mi < 4; ++mi)
#pragma unroll
      for (int ni = 0; ni < NFR; ++ni)
        acc[mi][ni] = __builtin_amdgcn_mfma_f32_16x16x32_bf16(al[mi], bh[ni],
                                                              acc[mi][ni], 0, 0, 0);
    if (t + 1 < KS) __builtin_amdgcn_s_barrier();
  }
#undef STG

  // ---------------- fused epilogue (round-16, known good) ------------------
  __syncthreads();

  float* rowred = (float*)&ldsAh[0];
  float* colred = (float*)&ldsAl[0];
  ushort* xsh = (ushort*)&ldsBh[0];
  ushort* xsl = (ushort*)&ldsBl[0];

  const int l15 = lane & 15, l4 = lane >> 4;
  const int b0i = (int)(row0 / NTOK);
  const size_t rowB = (size_t)(b0i + 1) * NTOK;
  const bool strad = rowB < row0 + 128;

  float biasv[NFR], mk0a[NFR], mk1a[NFR], gvn[NFR], bvn[NFR];
#pragma unroll
  for (int ni = 0; ni < NFR; ++ni) {
    int n = wn * WN + ni * 16 + l15;
    biasv[ni] = bias[n];
    mk0a[ni] = msk[(size_t)b0i * N + n];
    mk1a[ni] = strad ? msk[(size_t)(b0i + 1) * N + n] : mk0a[ni];
    gvn[ni] = gnext[n];
    bvn[ni] = bnext[n];
  }

  float rs[16], rq[16];
#pragma unroll
  for (int i = 0; i < 16; ++i) { rs[i] = 0.f; rq[i] = 0.f; }
#pragma unroll
  for (int mi = 0; mi < 4; ++mi)
#pragma unroll
    for (int q = 0; q < 4; ++q) {
      size_t row = row0 + wm * 64 + mi * 16 + l4 * 4 + q;
      bool loB = row < rowB;
#pragma unroll
      for (int ni = 0; ni < NFR; ++ni) {
        float v = (acc[mi][ni][q] + biasv[ni]) * (loB ? mk0a[ni] : mk1a[ni]);
        acc[mi][ni][q] = v;
        rs[mi * 4 + q] += v;
        rq[mi * 4 + q] += v * v;
      }
    }
#pragma unroll
  for (int off = 1; off < 16; off <<= 1)
#pragma unroll
    for (int i = 0; i < 16; ++i) {
      rs[i] += __shfl_xor(rs[i], off);
      rq[i] += __shfl_xor(rq[i], off);
    }
  if (l15 == 0) {
#pragma unroll
    for (int mi = 0; mi < 4; ++mi)
#pragma unroll
      for (int q = 0; q < 4; ++q) {
        int r = wm * 64 + mi * 16 + l4 * 4 + q;
        rowred[(wn * 128 + r) * 2 + 0] = rs[mi * 4 + q];
        rowred[(wn * 128 + r) * 2 + 1] = rq[mi * 4 + q];
      }
  }
  __syncthreads();

  float mean[16], rstd[16];
#pragma unroll
  for (int mi = 0; mi < 4; ++mi)
#pragma unroll
    for (int q = 0; q < 4; ++q) {
      int r = wm * 64 + mi * 16 + l4 * 4 + q;
      float S = 0.f, Q = 0.f;
#pragma unroll
      for (int w = 0; w < NWN; ++w) {
        S += rowred[(w * 128 + r) * 2 + 0];
        Q += rowred[(w * 128 + r) * 2 + 1];
      }
      float mn  = S / (float)N;
      float var = Q / (float)N - mn * mn;
      mean[mi * 4 + q] = mn;
      rstd[mi * 4 + q] = 1.f / sqrtf(var + 1e-5f);
    }

  float cs0[NFR], cs1[NFR];
#pragma unroll
  for (int ni = 0; ni < NFR; ++ni) { cs0[ni] = 0.f; cs1[ni] = 0.f; }
#pragma unroll
  for (int mi = 0; mi < 4; ++mi) {
    __syncthreads();
#pragma unroll
    for (int q = 0; q < 4; ++q) {
      const int rl = l4 * 4 + q;
      const size_t row = row0 + wm * 64 + mi * 16 + rl;
      const bool loB = row < rowB;
      const float mn = mean[mi * 4 + q], rv = rstd[mi * 4 + q];
#pragma unroll
      for (int ni = 0; ni < NFR; ++ni) {
        const int n = wn * WN + ni * 16 + l15;
        float xn = (acc[mi][ni][q] - mn) * rv * gvn[ni] + bvn[ni];
        ushort hh = f2bf(xn);
        xsh[(wm * 16 + rl) * N + n] = hh;
        if constexpr (WLO) xsl[(wm * 16 + rl) * N + n] = f2bf(xn - bf2f(hh));
        if (loB) cs0[ni] += xn; else cs1[ni] += xn;
      }
    }
    __syncthreads();
    constexpr int U4R = N / 8;
    for (int idx = tid; idx < 32 * U4R; idx += T) {
      const int grp = idx / U4R, c = idx - grp * U4R;
      const size_t row = row0 + (grp >> 4) * 64 + mi * 16 + (grp & 15);
      *(uint4*)(oh + row * (size_t)N + c * 8) =
          *(const uint4*)(xsh + grp * N + c * 8);
      if constexpr (WLO)
        *(uint4*)(ol + row * (size_t)N + c * 8) =
            *(const uint4*)(xsl + grp * N + c * 8);
    }
  }

#pragma unroll
  for (int ni = 0; ni < NFR; ++ni) {
    cs0[ni] += __shfl_xor(cs0[ni], 16);
    cs0[ni] += __shfl_xor(cs0[ni], 32);
    cs1[ni] += __shfl_xor(cs1[ni], 16);
    cs1[ni] += __shfl_xor(cs1[ni], 32);
  }
  __syncthreads();
  if (l4 == 0) {
#pragma unroll
    for (int ni = 0; ni < NFR; ++ni) {
      int n = wn * WN + ni * 16 + l15;
      colred[(0 * 2 + wm) * N + n] = cs0[ni];
      colred[(1 * 2 + wm) * N + n] = cs1[ni];
    }
  }
  __syncthreads();
  if (wm == 0 && l4 == 0) {
    const int mt_lo = (b0i * NTOK) >> 7;
    const int slot0 = mt - mt_lo;
#pragma unroll
    for (int ni = 0; ni < NFR; ++ni) {
      int n = wn * WN + ni * 16 + l15;
      float t0 = colred[0 * N + n] + colred[1 * N + n];
      part[((size_t)b0i * N + n) * 25 + slot0] = t0;
      if (strad) {
        float t1 = colred[2 * N + n] + colred[3 * N + n];
        part[((size_t)(b0i + 1) * N + n) * 25 + 0] = t1;
      }
    }
  }
}

// ---------------------------------------------------------------------------
// Stage-3 COMPACT GEMM + LN epilogue. SINGLE-buffered K-loop (KS=6); manual
// LDS carve (40 KB -> 4 blocks/CU); B rows staged via list[] indirection.
// Epilogue = round-16 logic.
// ---------------------------------------------------------------------------
template<int K, int NC, int N>
__global__ __launch_bounds__(256)
void gemm_lnc_k(const ushort* __restrict__ ahi, const ushort* __restrict__ alo,
                const ushort* __restrict__ whi, const ushort* __restrict__ wlo,
                const int* __restrict__ list, const float* __restrict__ biasc,
                const float* __restrict__ gnext, const float* __restrict__ bnext,
                ushort* __restrict__ oh, float* __restrict__ part)
{
  constexpr int KS  = K / 32;          // 6
  constexpr int WN  = NC / 2;          // 96
  constexpr int NFR = WN / 16;         // 6
  __shared__ __align__(16) ushort lds[2 * 128 * 32 + 2 * NC * 32];  // 40 KB
  ushort* ldsAh = lds;
  ushort* ldsAl = lds + 128 * 32;
  ushort* ldsBh = lds + 2 * 128 * 32;
  ushort* ldsBl = lds + 2 * 128 * 32 + NC * 32;

  const int tid  = threadIdx.x;
  const int lane = tid & 63;
  const int wid  = tid >> 6;
  const int wm = wid & 1, wn = wid >> 1;

  const int q8  = gridDim.x >> 3;
  const int bid = blockIdx.x;
  const int wg  = (bid & 7) * q8 + (bid >> 3);
  const int b   = wg / 25;
  const int mt  = wg - b * 25;
  const size_t row0 = (size_t)b * NTOK + (size_t)mt * 128;
  const size_t rowEnd = (size_t)(b + 1) * NTOK;
  const int rows_valid = (mt == 24) ? 64 : 128;

  const int c_row  = tid >> 2;     // 0..63
  const int c_phys = tid & 3;

  int bsrc[3];
#pragma unroll
  for (int r_ = 0; r_ < 3; ++r_) {
    int s = list[b * 256 + c_row + r_ * 64];
    bsrc[r_] = (s < 0) ? 0 : s;
  }

  f32x4 acc[4][NFR];
#pragma unroll
  for (int i = 0; i < 4; ++i)
#pragma unroll
    for (int j = 0; j < NFR; ++j) acc[i][j] = { 0.f, 0.f, 0.f, 0.f };

#define STGL(KK)                                                               \
  {                                                                            \
    const int k0_ = (KK) * 32;                                                 \
    _Pragma("unroll")                                                          \
    for (int r_ = 0; r_ < 2; ++r_) {                                           \
      int row_  = c_row + r_ * 64;                                             \
      int slot_ = c_phys ^ ((row_ >> 1) & 3);                                  \
      size_t ar_ = row0 + row_;                                                \
      if (ar_ >= rowEnd) ar_ = rowEnd - 1;                                     \
      ASYNC16(ahi + ar_ * (size_t)K + (k0_ + slot_ * 8),                       \
              &ldsAh[(row_ * 4 + c_phys) * 8]);                                \
      ASYNC16(alo + ar_ * (size_t)K + (k0_ + slot_ * 8),                       \
              &ldsAl[(row_ * 4 + c_phys) * 8]);                                \
    }                                                                          \
    _Pragma("unroll")                                                          \
    for (int r_ = 0; r_ < 3; ++r_) {                                           \
      int row_  = c_row + r_ * 64;                                             \
      int slot_ = c_phys ^ ((row_ >> 1) & 3);                                  \
      ASYNC16(whi + (size_t)bsrc[r_] * K + (k0_ + slot_ * 8),                  \
              &ldsBh[(row_ * 4 + c_phys) * 8]);                                \
      ASYNC16(wlo + (size_t)bsrc[r_] * K + (k0_ + slot_ * 8),                  \
              &ldsBl[(row_ * 4 + c_phys) * 8]);                                \
    }                                                                          \
  }

#pragma unroll
  for (int t = 0; t < KS; ++t) {
    STGL(t);
    asm volatile("s_waitcnt vmcnt(0)" ::: "memory");
    __builtin_amdgcn_s_barrier();
    const int slot = lane >> 4;
    const int r16  = lane & 15;
    bf16x8 ah[4], al[4], bh[NFR], bl[NFR];
#pragma unroll
    for (int mi = 0; mi < 4; ++mi) {
      int r = wm * 64 + mi * 16 + r16;
      int off = (r * 4 + (slot ^ ((r >> 1) & 3))) * 8;
      ah[mi] = *(const bf16x8*)&ldsAh[off];
      al[mi] = *(const bf16x8*)&ldsAl[off];
    }
#pragma unroll
    for (int ni = 0; ni < NFR; ++ni) {
      int r = wn * WN + ni * 16 + r16;
      int off = (r * 4 + (slot ^ ((r >> 1) & 3))) * 8;
      bh[ni] = *(const bf16x8*)&ldsBh[off];
      bl[ni] = *(const bf16x8*)&ldsBl[off];
    }
#pragma unroll
    for (int mi = 0; mi < 4; ++mi)
#pragma unroll
      for (int ni = 0; ni < NFR; ++ni)
        acc[mi][ni] = __builtin_amdgcn_mfma_f32_16x16x32_bf16(ah[mi], bh[ni],
                                                              acc[mi][ni], 0, 0, 0);
#pragma unroll
    for (int mi = 0; mi < 4; ++mi)
#pragma unroll
      for (int ni = 0; ni < NFR; ++ni)
        acc[mi][ni] = __builtin_amdgcn_mfma_f32_16x16x32_bf16(ah[mi], bl[ni],
                                                              acc[mi][ni], 0, 0, 0);
#pragma unroll
    for (int mi = 0; mi < 4; ++mi)
#pragma unroll
      for (int ni = 0; ni < NFR; ++ni)
        acc[mi][ni] = __builtin_amdgcn_mfma_f32_16x16x32_bf16(al[mi], bh[ni],
                                                              acc[mi][ni], 0, 0, 0);
    if (t + 1 < KS) __builtin_amdgcn_s_barrier();
  }
#undef STGL

  // ---------------- compact-LN epilogue (round-16, known good) -------------
  __syncthreads();

  float* rr      = (float*)ldsAh;
  float* rowredp = rr;                   // [2][128][2] = 512 floats
  float* rowmnrv = rr + 512;             // [128]
  float* rowrv   = rr + 640;             // [128]
  float* sbuf    = (float*)ldsBh;        // [16][N] fp32 = 24 KB (Bh+Bl)

  const int l15 = lane & 15, l4 = lane >> 4;

  int   nj[NFR];
  float biasv[NFR];
#pragma unroll
  for (int ni = 0; ni < NFR; ++ni) {
    int j = wn * WN + ni * 16 + l15;
    nj[ni]    = list[b * 256 + j];
    biasv[ni] = biasc[b * 256 + j];
  }

  float rs[16], rq[16];
#pragma unroll
  for (int i = 0; i < 16; ++i) { rs[i] = 0.f; rq[i] = 0.f; }
#pragma unroll
  for (int mi = 0; mi < 4; ++mi)
#pragma unroll
    for (int q = 0; q < 4; ++q) {
#pragma unroll
      for (int ni = 0; ni < NFR; ++ni) {
        float v = acc[mi][ni][q] + biasv[ni];
        acc[mi][ni][q] = v;
        rs[mi * 4 + q] += v;
        rq[mi * 4 + q] += v * v;
      }
    }
#pragma unroll
  for (int off = 1; off < 16; off <<= 1)
#pragma unroll
    for (int i = 0; i < 16; ++i) {
      rs[i] += __shfl_xor(rs[i], off);
      rq[i] += __shfl_xor(rq[i], off);
    }
  if (l15 == 0) {
#pragma unroll
    for (int mi = 0; mi < 4; ++mi)
#pragma unroll
      for (int q = 0; q < 4; ++q) {
        int r = wm * 64 + mi * 16 + l4 * 4 + q;
        rowredp[(wn * 128 + r) * 2 + 0] = rs[mi * 4 + q];
        rowredp[(wn * 128 + r) * 2 + 1] = rq[mi * 4 + q];
      }
  }
  __syncthreads();
  if (tid < 128) {
    float S = rowredp[(0 * 128 + tid) * 2 + 0] + rowredp[(1 * 128 + tid) * 2 + 0];
    float Q = rowredp[(0 * 128 + tid) * 2 + 1] + rowredp[(1 * 128 + tid) * 2 + 1];
    float mn = S / (float)N;
    float rv = 1.f / sqrtf(Q / (float)N - mn * mn + 1e-5f);
    rowmnrv[tid] = mn * rv;
    rowrv[tid]   = rv;
  }
  __syncthreads();

  float colS = 0.f, colS2 = 0.f;

#pragma unroll
  for (int h = 0; h < 8; ++h) {
    if (h * 16 >= rows_valid) break;
    __syncthreads();
    for (int idx = tid; idx < 16 * N / 4; idx += 256)
      ((f32x4*)sbuf)[idx] = f32x4{0.f, 0.f, 0.f, 0.f};
    __syncthreads();
    if ((h >> 2) == wm) {
      const int mi = h & 3;
#pragma unroll
      for (int q = 0; q < 4; ++q) {
        const int rl = l4 * 4 + q;
        const float rv = rowrv[h * 16 + rl];
#pragma unroll
        for (int ni = 0; ni < NFR; ++ni)
          sbuf[rl * N + nj[ni]] = acc[mi][ni][q] * rv;
      }
    }
    __syncthreads();
    {
      float a = 0.f;
#pragma unroll
      for (int rl = 0; rl < 16; ++rl) a += sbuf[rl * N + tid];
      colS += a;
      if (tid < N - 256) {
        float a2 = 0.f;
        const int c2 = 256 + tid;
#pragma unroll
        for (int rl = 0; rl < 16; ++rl) a2 += sbuf[rl * N + c2];
        colS2 += a2;
      }
    }
    for (int idx = tid; idx < 16 * (N / 8); idx += 256) {
      const int rl = idx / (N / 8), cg = idx - rl * (N / 8);
      const float mnrv = rowmnrv[h * 16 + rl];
      const float* sp = sbuf + rl * N + cg * 8;
      f32x4 s0 = *(const f32x4*)(sp);
      f32x4 s1 = *(const f32x4*)(sp + 4);
      f32x4 g0 = *(const f32x4*)(gnext + cg * 8);
      f32x4 g1 = *(const f32x4*)(gnext + cg * 8 + 4);
      f32x4 e0 = *(const f32x4*)(bnext + cg * 8);
      f32x4 e1 = *(const f32x4*)(bnext + cg * 8 + 4);
      uint32_t w[4];
#pragma unroll
      for (int j = 0; j < 2; ++j) {
        ushort ha = f2bf(g0[2*j]   * (s0[2*j]   - mnrv) + e0[2*j]);
        ushort hb = f2bf(g0[2*j+1] * (s0[2*j+1] - mnrv) + e0[2*j+1]);
        w[j] = (uint32_t)ha | ((uint32_t)hb << 16);
      }
#pragma unroll
      for (int j = 0; j < 2; ++j) {
        ushort ha = f2bf(g1[2*j]   * (s1[2*j]   - mnrv) + e1[2*j]);
        ushort hb = f2bf(g1[2*j+1] * (s1[2*j+1] - mnrv) + e1[2*j+1]);
        w[2 + j] = (uint32_t)ha | ((uint32_t)hb << 16);
      }
      *(uint4*)(oh + (row0 + h * 16 + rl) * (size_t)N + cg * 8) =
          make_uint4(w[0], w[1], w[2], w[3]);
    }
  }

  float msum = 0.f;
  for (int r = 0; r < rows_valid; ++r) msum += rowmnrv[r];
  {
    const int c = tid;
    part[((size_t)b * N + c) * 25 + mt] =
        gnext[c] * (colS - msum) + (float)rows_valid * bnext[c];
    if (tid < N - 256) {
      const int c2 = 256 + tid;
      part[((size_t)b * N + c2) * 25 + mt] =
          gnext[c2] * (colS2 - msum) + (float)rows_valid * bnext[c2];
    }
  }
}

// ---------------------------------------------------------------------------
// Stage-4 COMPACTED GEMM (round-16, known good): per-batch m-tiles, 128 rows
// x 256 compacted cols, 512 thr, vmcnt(3), indirect B, scatter epilogue.
// ---------------------------------------------------------------------------
template<int K>
__global__ __launch_bounds__(512)
void gemm_c4_k(const ushort* __restrict__ A, const ushort* __restrict__ whi,
               const int* __restrict__ list, const float* __restrict__ biasc,
               float* __restrict__ C)
{
  constexpr int NT = K / 32;       // 12
  __shared__ __align__(16) ushort ldsA[3][128 * 32];
  __shared__ __align__(16) ushort ldsB[3][256 * 32];

  const int tid  = threadIdx.x;
  const int lane = tid & 63;
  const int wid  = tid >> 6;
  const int wm = wid & 1, wn = wid >> 1;

  const int q8  = gridDim.x >> 3;
  const int bid = blockIdx.x;
  const int wg  = (bid & 7) * q8 + (bid >> 3);
  const int b   = wg / 25;
  const int mt  = wg - b * 25;
  const size_t row0 = (size_t)b * NTOK + (size_t)mt * 128;
  const int rows_valid = (mt == 24) ? 64 : 128;

  const int c_row  = tid >> 2;     // 0..127
  const int c_phys = tid & 3;

  size_t arow = row0 + c_row;
  const size_t rowEnd = (size_t)(b + 1) * NTOK;
  if (arow >= rowEnd) arow = rowEnd - 1;
  const ushort* apr = A + arow * (size_t)K;

  int bsrc[2];
#pragma unroll
  for (int r_ = 0; r_ < 2; ++r_) {
    int s = list[b * 256 + c_row + r_ * 128];
    bsrc[r_] = (s < 0) ? 0 : s;
  }

  f32x4 acc[4][4];
#pragma unroll
  for (int i = 0; i < 4; ++i)
#pragma unroll
    for (int j = 0; j < 4; ++j) acc[i][j] = { 0.f, 0.f, 0.f, 0.f };

#define STAGEC(BUF, TT)                                                        \
  {                                                                            \
    const int k0_ = (TT) * 32;                                                 \
    {                                                                          \
      int slot_ = c_phys ^ ((c_row >> 1) & 3);                                 \
      ASYNC16(apr + (k0_ + slot_ * 8),                                         \
              &ldsA[BUF][(c_row * 4 + c_phys) * 8]);                           \
    }                                                                          \
    _Pragma("unroll")                                                          \
    for (int r_ = 0; r_ < 2; ++r_) {                                           \
      int row_  = c_row + r_ * 128;                                            \
      int slot_ = c_phys ^ ((row_ >> 1) & 3);                                  \
      ASYNC16(whi + (size_t)bsrc[r_] * K + (k0_ + slot_ * 8),                  \
              &ldsB[BUF][(row_ * 4 + c_phys) * 8]);                            \
    }                                                                          \
  }

  STAGEC(0, 0);
  STAGEC(1, 1);
#pragma unroll
  for (int t = 0; t < NT; ++t) {
    if (t == NT - 1) { asm volatile("s_waitcnt vmcnt(0)" ::: "memory"); }
    else             { asm volatile("s_waitcnt vmcnt(3)" ::: "memory"); }
    __builtin_amdgcn_s_barrier();
    if (t + 2 < NT) STAGEC((t + 2) % 3, t + 2);
    const int buf = t % 3;
    const int slot = lane >> 4;
    const int r16  = lane & 15;
    bf16x8 af[4], bfr[4];
#pragma unroll
    for (int mi = 0; mi < 4; ++mi) {
      int r = wm * 64 + mi * 16 + r16;
      af[mi] = *(const bf16x8*)&ldsA[buf][(r * 4 + (slot ^ ((r >> 1) & 3))) * 8];
    }
#pragma unroll
    for (int ni = 0; ni < 4; ++ni) {
      int r = wn * 64 + ni * 16 + r16;
      bfr[ni] = *(const bf16x8*)&ldsB[buf][(r * 4 + (slot ^ ((r >> 1) & 3))) * 8];
    }
#pragma unroll
    for (int mi = 0; mi < 4; ++mi)
#pragma unroll
      for (int ni = 0; ni < 4; ++ni)
        acc[mi][ni] = __builtin_amdgcn_mfma_f32_16x16x32_bf16(af[mi], bfr[ni],
                                                              acc[mi][ni], 0, 0, 0);
  }
#undef STAGEC

  float* cst = (float*)&ldsB[0][0];      // [16][768] fp32

  const int l15 = lane & 15, l4 = lane >> 4;
  int   nj[4];
  float biasv[4];
#pragma unroll
  for (int ni = 0; ni < 4; ++ni) {
    int j = wn * 64 + ni * 16 + l15;
    nj[ni]    = list[b * 256 + j];
    biasv[ni] = biasc[b * 256 + j];
  }

#pragma unroll
  for (int hh = 0; hh < 8; ++hh) {
    const int hrows = rows_valid - hh * 16;
    if (hrows <= 0) break;
    __syncthreads();
    for (int idx = tid; idx < 16 * 192; idx += 512)
      ((f32x4*)cst)[idx] = f32x4{0.f, 0.f, 0.f, 0.f};
    __syncthreads();
    if ((hh >> 2) == wm) {
      const int mi = hh & 3;
#pragma unroll
      for (int q = 0; q < 4; ++q) {
        const int rl = l4 * 4 + q;
#pragma unroll
        for (int ni = 0; ni < 4; ++ni)
          if (nj[ni] >= 0)
            cst[rl * 768 + nj[ni]] = acc[mi][ni][q] + biasv[ni];
      }
    }
    __syncthreads();
    const int nst = (hrows >= 16 ? 16 : hrows) * 192;
    for (int idx = tid; idx < nst; idx += 512) {
      const int grp = idx / 192, c = idx - grp * 192;
      const size_t row = row0 + hh * 16 + grp;
      *(f32x4*)(C + row * 768 + c * 4) = ((const f32x4*)cst)[grp * 192 + c];
    }
  }
}

// ---------------------------------------------------------------------------
extern "C" void kernel_launch(void* const* d_in, const int* in_sizes, int n_in,
                              void* d_out, int out_size, void* d_ws, size_t ws_size,
                              hipStream_t stream)
{
  (void)in_sizes; (void)n_in; (void)out_size; (void)ws_size;
  const float* x = (const float*)d_in[0];
  const float *sg[4], *sb[4], *sW[4], *sbias[4], *pW1[4], *pb1[4], *pW2[4], *pb2[4];
  for (int s = 0; s < 4; ++s) {
    int base = 1 + s * 8;
    sg[s]    = (const float*)d_in[base + 0];
    sb[s]    = (const float*)d_in[base + 1];
    sW[s]    = (const float*)d_in[base + 2];
    sbias[s] = (const float*)d_in[base + 3];
    pW1[s]   = (const float*)d_in[base + 4];
    pb1[s]   = (const float*)d_in[base + 5];
    pW2[s]   = (const float*)d_in[base + 6];
    pb2[s]   = (const float*)d_in[base + 7];
  }

  float* out = (float*)d_out;
  ushort* hiA = (ushort*)out;                    // x̃1 (M*96) then x̃3 (M*192)
  ushort* loA = (ushort*)(out + 19267584);       // lo1 then lo3
  ushort* loB = (ushort*)(out + 38535168);       // lo2 (M*192)

  char* ws = (char*)d_ws;
  ushort* hiB  = (ushort*)(ws);                  // x̃2 (M*192) then x̃4 (M*384)
  float*  part = (float*) (ws + 77070336);
  float*  mk   = (float*) (ws + 79822848);
  ushort* w_hi = (ushort*)(ws + 79921152);       // 811,008
  ushort* w_lo = (ushort*)(ws + 80732160);       // 811,008
  int*    lst  = (int*)   (ws + 87834624);       // 32,768
  float*  bsc  = (float*) (ws + 87867392);       // 32,768 -> end 87,900,160

  const int woff[4] = { 0, 12288, 36864, 110592 };

  convW_all_k<<<(405504 + 255) / 256, 256, 0, stream>>>(
      sW[0], sW[1], sW[2], sW[3], w_hi, w_lo);

  // ---- stage 1: LN1 (lane-dense), scores1 (SLOTS=49), fused gemm1+LN2
  ln1_k<<<32 * 49, 256, 0, stream>>>(x, sg[0], sb[0], hiA, loA, part);
  scores_k<96, 96, 49, false, 256><<<32, 1024, 0, stream>>>(
      part, sW[0], sbias[0], pW1[0], pb1[0], pW2[0], pb2[0], mk, 86,
      nullptr, nullptr);
  gemm_ln_k<96, 128, 96, 2, true><<<784, 256, 0, stream>>>(
      hiA, loA, w_hi + woff[0], w_lo + woff[0],
      sbias[0], mk, sg[1], sb[1], hiB, loB, part);

  // ---- stage 2: scores2, fused gemm2+LN3
  scores_k<96, 192, 25, false, 256><<<32, 1024, 0, stream>>>(
      part, sW[1], sbias[1], pW1[1], pb1[1], pW2[1], pb2[1], mk, 134,
      nullptr, nullptr);
  gemm_ln_k<96, 192, 192, 2, true><<<784, 256, 0, stream>>>(
      hiB, loB, w_hi + woff[1], w_lo + woff[1],
      sbias[1], mk, sg[2], sb[2], hiA, loA, part);

  // ---- stage 3: scores3 (list+biasc), single-buffer compact gemm3+LN4
  scores_k<192, 384, 25, true, 192><<<32, 1024, 0, stream>>>(
      part, sW[2], sbias[2], pW1[2], pb1[2], pW2[2], pb2[2], mk, 192,
      lst, bsc);
  gemm_lnc_k<192, 192, 384><<<800, 256, 0, stream>>>(
      hiA, loA, w_hi + woff[2], w_lo + woff[2], lst, bsc, sg[3], sb[3],
      hiB, part);

  // ---- stage 4: scores4 (list+biasc), compacted GEMM (indirect B)
  scores_k<384, 768, 25, true, 256><<<32, 1024, 0, stream>>>(
      part, sW[3], sbias[3], pW1[3], pb1[3], pW2[3], pb2[3], mk, 230,
      lst, bsc);
  gemm_c4_k<384><<<800, 512, 0, stream>>>(hiB, w_hi + woff[3], lst, bsc, out);
}